// Round 1
// baseline (1047.073 us; speedup 1.0000x reference)
//
#include <hip/hip_runtime.h>
#include <math.h>

// Problem constants
#define S_LEN 2048
#define BATCH 2
#define NH 16
#define DH 64
#define DM 1024
#define FEAT 384          // 2*DH*N_ROLL = 384
#define SB 4096           // S_LEN * BATCH

static constexpr float SCALE = 0.125f;  // 1/sqrt(64)
static constexpr float EPS = 1e-5f;

// ---------------------------------------------------------------------------
// Generic f32 GEMM: C[M,N] = A[M,K] @ B[K,N], all row-major.
// 64x64 tile, 256 threads, 4x4 micro-tile per thread, BK=16.
// ---------------------------------------------------------------------------
__global__ __launch_bounds__(256) void gemm_f32(const float* __restrict__ A,
                                                const float* __restrict__ B,
                                                float* __restrict__ C,
                                                int M, int N, int K) {
    __shared__ float As[16][65];
    __shared__ float Bs[16][65];
    int t = threadIdx.x;
    int tx = t & 15, ty = t >> 4;
    int row0 = blockIdx.y * 64, col0 = blockIdx.x * 64;
    float acc[4][4] = {};
    for (int k0 = 0; k0 < K; k0 += 16) {
        #pragma unroll
        for (int i = 0; i < 4; ++i) {
            int idx = t + i * 256;            // 0..1023
            int r = idx >> 4, c = idx & 15;   // 64 rows x 16 cols
            As[c][r] = A[(size_t)(row0 + r) * K + (k0 + c)];
        }
        #pragma unroll
        for (int i = 0; i < 4; ++i) {
            int idx = t + i * 256;
            int r = idx >> 6, c = idx & 63;   // 16 rows x 64 cols
            Bs[r][c] = B[(size_t)(k0 + r) * N + (col0 + c)];
        }
        __syncthreads();
        #pragma unroll
        for (int kk = 0; kk < 16; ++kk) {
            float a[4], b[4];
            #pragma unroll
            for (int i = 0; i < 4; ++i) a[i] = As[kk][ty * 4 + i];
            #pragma unroll
            for (int j = 0; j < 4; ++j) b[j] = Bs[kk][tx * 4 + j];
            #pragma unroll
            for (int i = 0; i < 4; ++i)
                #pragma unroll
                for (int j = 0; j < 4; ++j)
                    acc[i][j] = fmaf(a[i], b[j], acc[i][j]);
        }
        __syncthreads();
    }
    #pragma unroll
    for (int i = 0; i < 4; ++i)
        #pragma unroll
        for (int j = 0; j < 4; ++j)
            C[(size_t)(row0 + ty * 4 + i) * N + col0 + tx * 4 + j] = acc[i][j];
}

// ---------------------------------------------------------------------------
// kv_agg partials: for each (b,n) and j-chunk, accumulate
//   kvagg[f][d] += pk[j,f] * v[j,d],  z[f] += pk[j,f]
// pk computed on the fly from k row via DPFP.
// Grid: (16 chunks, 32 bn), 256 threads.
// Thread t: d = t&63, fgrp = t>>6; owns f = fgrp + 4*m for m=0..95.
// ---------------------------------------------------------------------------
__global__ __launch_bounds__(256) void kvagg_kernel(const float* __restrict__ kv,
                                                    float* __restrict__ kvagg_part,
                                                    float* __restrict__ z_part) {
    __shared__ float x2[128];
    __shared__ float vs[64];
    __shared__ float pk[FEAT];
    int t = threadIdx.x;
    int chunk = blockIdx.x;   // 0..15 (j-chunks of 128)
    int bn = blockIdx.y;      // 0..31
    int b = bn >> 4, n = bn & 15;
    int fgrp = t >> 6, d = t & 63;
    float acc[96];
    #pragma unroll
    for (int m = 0; m < 96; ++m) acc[m] = 0.f;
    float zacc[3] = {0.f, 0.f, 0.f};
    int j0 = chunk * 128;
    for (int jj = 0; jj < 128; ++jj) {
        int j = j0 + jj;
        const float* krow = kv + (size_t)(j * BATCH + b) * 2048 + n * 64;
        if (t < 64) {
            float kvv = krow[t];
            x2[t] = fmaxf(kvv, 0.f);
            x2[t + 64] = fmaxf(-kvv, 0.f);
        } else if (t < 128) {
            vs[t - 64] = krow[1024 + (t - 64)];
        }
        __syncthreads();
        if (t < 128) {
            #pragma unroll
            for (int m = 0; m < 3; ++m)
                pk[t + 128 * m] = x2[t] * x2[(t - m - 1) & 127];
        }
        __syncthreads();
        float vval = vs[d];
        #pragma unroll
        for (int m = 0; m < 96; ++m)
            acc[m] = fmaf(pk[fgrp + 4 * m], vval, acc[m]);
        if (t < 128) {
            #pragma unroll
            for (int m = 0; m < 3; ++m) zacc[m] += pk[t + 128 * m];
        }
        __syncthreads();
    }
    float* outp = kvagg_part + (size_t)(chunk * 32 + bn) * FEAT * 64;
    #pragma unroll
    for (int m = 0; m < 96; ++m)
        outp[(fgrp + 4 * m) * 64 + d] = acc[m];
    if (t < 128) {
        float* zp = z_part + (size_t)(chunk * 32 + bn) * FEAT;
        #pragma unroll
        for (int m = 0; m < 3; ++m) zp[t + 128 * m] = zacc[m];
    }
}

// ---------------------------------------------------------------------------
// Reduce 16 partial chunks -> kv_agg [32][384][64] and z [32][384]
// ---------------------------------------------------------------------------
__global__ __launch_bounds__(256) void reduce_parts(const float* __restrict__ kvagg_part,
                                                    const float* __restrict__ z_part,
                                                    float* __restrict__ kv_agg,
                                                    float* __restrict__ z) {
    const int KVN = 32 * FEAT * 64;  // 786432
    int idx = blockIdx.x * 256 + threadIdx.x;
    if (idx < KVN) {
        float s = 0.f;
        #pragma unroll
        for (int c = 0; c < 16; ++c) s += kvagg_part[(size_t)c * KVN + idx];
        kv_agg[idx] = s;
    } else if (idx < KVN + 32 * FEAT) {
        int e = idx - KVN;
        float s = 0.f;
        #pragma unroll
        for (int c = 0; c < 16; ++c) s += z_part[c * 32 * FEAT + e];
        z[e] = s;
    }
}

// ---------------------------------------------------------------------------
// attn_vec: per (i,b,n) one wave. num = pq . kv_agg[:,d], den = pq . z.
// pq computed on the fly from q row.
// Grid: 16384 blocks x 256 threads (4 waves/block).
// Wave id gw: i = gw & 2047, bn = gw >> 11 (contiguous i per bn for L2 reuse).
// ---------------------------------------------------------------------------
__global__ __launch_bounds__(256) void attnvec_kernel(const float* __restrict__ q,
                                                      const float* __restrict__ kv_agg,
                                                      const float* __restrict__ z,
                                                      float* __restrict__ attn_vec) {
    __shared__ float x2s[4][128];
    __shared__ float pqs[4][FEAT];
    int t = threadIdx.x;
    int wl = t >> 6, lane = t & 63;
    int gw = blockIdx.x * 4 + wl;
    int i = gw & 2047;
    int bn = gw >> 11;
    int b = bn >> 4, n = bn & 15;
    float qv = q[(size_t)(i * BATCH + b) * 1024 + n * 64 + lane];
    x2s[wl][lane] = fmaxf(qv, 0.f);
    x2s[wl][64 + lane] = fmaxf(-qv, 0.f);
    __syncthreads();
    #pragma unroll
    for (int s6 = 0; s6 < 6; ++s6) {
        int f = lane + 64 * s6;
        int ir = (f >> 7) + 1;
        int jj = f & 127;
        pqs[wl][f] = x2s[wl][jj] * x2s[wl][(jj - ir) & 127];
    }
    __syncthreads();
    const float* kvp = kv_agg + (size_t)bn * FEAT * 64 + lane;
    float acc = 0.f;
    #pragma unroll 8
    for (int f = 0; f < FEAT; ++f)
        acc = fmaf(pqs[wl][f], kvp[(size_t)f * 64], acc);
    float dpart = 0.f;
    const float* zp = z + bn * FEAT;
    #pragma unroll
    for (int s6 = 0; s6 < 6; ++s6) {
        int f = lane + 64 * s6;
        dpart += pqs[wl][f] * zp[f];
    }
    #pragma unroll
    for (int off = 32; off >= 1; off >>= 1)
        dpart += __shfl_xor(dpart, off, 64);
    float den = dpart * SCALE + EPS;
    attn_vec[(size_t)(i * BATCH + b) * 1024 + n * 64 + lane] = acc * SCALE / den;
}

// ---------------------------------------------------------------------------
// Residual + LayerNorm over last dim (1024). One block per row.
// ---------------------------------------------------------------------------
__global__ __launch_bounds__(256) void ln_kernel(const float* __restrict__ h,
                                                 const float* __restrict__ attn_out,
                                                 const float* __restrict__ gamma,
                                                 const float* __restrict__ beta,
                                                 float* __restrict__ out) {
    int r = blockIdx.x;
    int t = threadIdx.x;
    float xs[4];
    float sum = 0.f, sq = 0.f;
    const float* hp = h + (size_t)r * 1024;
    const float* ap = attn_out + (size_t)r * 1024;
    #pragma unroll
    for (int j = 0; j < 4; ++j) {
        int c = t + 256 * j;
        float x = hp[c] + ap[c];
        xs[j] = x;
        sum += x;
        sq += x * x;
    }
    #pragma unroll
    for (int off = 32; off >= 1; off >>= 1) {
        sum += __shfl_xor(sum, off, 64);
        sq += __shfl_xor(sq, off, 64);
    }
    __shared__ float ssum[4], ssq[4];
    int wl = t >> 6, lane = t & 63;
    if (lane == 0) { ssum[wl] = sum; ssq[wl] = sq; }
    __syncthreads();
    sum = ssum[0] + ssum[1] + ssum[2] + ssum[3];
    sq = ssq[0] + ssq[1] + ssq[2] + ssq[3];
    float mu = sum * (1.f / 1024.f);
    float var = sq * (1.f / 1024.f) - mu * mu;
    float rs = rsqrtf(var + 1e-5f);
    float* op = out + (size_t)r * 1024;
    #pragma unroll
    for (int j = 0; j < 4; ++j) {
        int c = t + 256 * j;
        op[c] = (xs[j] - mu) * rs * gamma[c] + beta[c];
    }
}

// ---------------------------------------------------------------------------
extern "C" void kernel_launch(void* const* d_in, const int* in_sizes, int n_in,
                              void* d_out, int out_size, void* d_ws, size_t ws_size,
                              hipStream_t stream) {
    const float* h     = (const float*)d_in[0];
    const float* Wq    = (const float*)d_in[1];
    const float* Wkv   = (const float*)d_in[2];
    const float* Wo    = (const float*)d_in[3];
    const float* gamma = (const float*)d_in[4];
    const float* beta  = (const float*)d_in[5];
    float* out = (float*)d_out;
    float* ws  = (float*)d_ws;

    // Workspace layout (floats):
    float* q          = ws;               // 4,194,304  (reused as attn_out)
    float* kvbuf      = ws + 4194304;     // 8,388,608  (reused as attn_vec)
    float* kvagg_part = ws + 12582912;    // 12,582,912 (16 chunks x 786432)
    float* z_part     = ws + 25165824;    // 196,608
    float* kv_agg     = ws + 25362432;    // 786,432
    float* z          = ws + 26148864;    // 12,288
    float* attn_vec   = kvbuf;            // kv no longer needed after kvagg
    float* attn_out   = q;                // q no longer needed after attnvec

    dim3 blk(256);
    // 1) q = h @ Wq   [4096,1024] x [1024,1024]
    gemm_f32<<<dim3(16, 64), blk, 0, stream>>>(h, Wq, q, SB, 1024, DM);
    // 2) kv = h @ Wkv [4096,1024] x [1024,2048]
    gemm_f32<<<dim3(32, 64), blk, 0, stream>>>(h, Wkv, kvbuf, SB, 2048, DM);
    // 3) kv_agg partials + z partials
    kvagg_kernel<<<dim3(16, 32), blk, 0, stream>>>(kvbuf, kvagg_part, z_part);
    // 4) reduce partials
    reduce_parts<<<dim3((32 * FEAT * 64 + 32 * FEAT + 255) / 256), blk, 0, stream>>>(
        kvagg_part, z_part, kv_agg, z);
    // 5) attn_vec = (pq @ kv_agg) * scale / (pq . z * scale + eps)
    attnvec_kernel<<<dim3(16384), blk, 0, stream>>>(q, kv_agg, z, attn_vec);
    // 6) attn_out = attn_vec @ Wo
    gemm_f32<<<dim3(16, 64), blk, 0, stream>>>(attn_vec, Wo, attn_out, SB, 1024, DM);
    // 7) out = LayerNorm(h + attn_out)
    ln_kernel<<<dim3(SB), blk, 0, stream>>>(h, attn_out, gamma, beta, out);
}

// Round 2
// 576.344 us; speedup vs baseline: 1.8167x; 1.8167x over previous
//
#include <hip/hip_runtime.h>
#include <math.h>

// Problem constants
#define S_LEN 2048
#define BATCH 2
#define NH 16
#define DH 64
#define DM 1024
#define FEAT 384          // 2*DH*N_ROLL = 384
#define SB 4096           // S_LEN * BATCH

static constexpr float SCALE = 0.125f;  // 1/sqrt(64)
static constexpr float EPS = 1e-5f;

typedef __attribute__((ext_vector_type(8))) short short8;
typedef __attribute__((ext_vector_type(4))) float f32x4;

#define AS1 __attribute__((address_space(1)))
#define AS3 __attribute__((address_space(3)))

// f32 -> bf16 (RNE) as raw ushort
__device__ __forceinline__ unsigned short f2bf(float x) {
    unsigned int u = __float_as_uint(x);
    u += 0x7FFFu + ((u >> 16) & 1u);
    return (unsigned short)(u >> 16);
}

// ---------------------------------------------------------------------------
// f32 -> bf16 straight conversion, vectorized (float4 in, ushort4 out)
// ---------------------------------------------------------------------------
__global__ __launch_bounds__(256) void conv_bf16(const float* __restrict__ src,
                                                 unsigned short* __restrict__ dst,
                                                 int n4) {
    int i = blockIdx.x * 256 + threadIdx.x;
    if (i >= n4) return;
    const float4 v = ((const float4*)src)[i];
    ushort4 o;
    o.x = f2bf(v.x); o.y = f2bf(v.y); o.z = f2bf(v.z); o.w = f2bf(v.w);
    ((ushort4*)dst)[i] = o;
}

// ---------------------------------------------------------------------------
// Transpose-convert: src f32 [K][N] -> dst bf16 [N][K]
// 32x32 tiles, 256 threads.
// ---------------------------------------------------------------------------
__global__ __launch_bounds__(256) void transpose_bf16(const float* __restrict__ src,
                                                      unsigned short* __restrict__ dst,
                                                      int K, int N) {
    __shared__ unsigned short tile[32][33];
    int n0 = blockIdx.x * 32, k0 = blockIdx.y * 32;
    int tx = threadIdx.x & 31, ty = threadIdx.x >> 5;  // ty 0..7
    #pragma unroll
    for (int i = 0; i < 4; ++i) {
        int k = k0 + ty + i * 8;
        tile[ty + i * 8][tx] = f2bf(src[(size_t)k * N + n0 + tx]);
    }
    __syncthreads();
    #pragma unroll
    for (int i = 0; i < 4; ++i) {
        int n = n0 + ty + i * 8;
        dst[(size_t)n * K + k0 + tx] = tile[tx][ty + i * 8];
    }
}

// ---------------------------------------------------------------------------
// bf16 MFMA GEMM: C_f32[M,N] = A_bf16[M,K] @ (BT_bf16[N,K])^T
// 128x128 tile, 256 threads (4 waves, 2x2 of 64x64), BK=32.
// m97 structure: global_load_lds(16B) staging, 2 barriers/K-step,
// 16x16x32 bf16 MFMA, 4x4 frags per wave.
// ---------------------------------------------------------------------------
__global__ __launch_bounds__(256) void gemm_bf16(const unsigned short* __restrict__ A,
                                                 const unsigned short* __restrict__ BT,
                                                 float* __restrict__ C,
                                                 int M, int N, int K) {
    __shared__ unsigned short Asb[128 * 32];
    __shared__ unsigned short Bsb[128 * 32];
    int t = threadIdx.x;
    int w = t >> 6, l = t & 63;
    int wr = w >> 1, wc = w & 1;
    int row0 = blockIdx.y * 128, col0 = blockIdx.x * 128;

    f32x4 acc[4][4];
    #pragma unroll
    for (int m = 0; m < 4; ++m)
        #pragma unroll
        for (int n = 0; n < 4; ++n)
            acc[m][n] = (f32x4){0.f, 0.f, 0.f, 0.f};

    // per-lane global src coordinates for staging (row = chunk*16 + l/4, col = (l&3)*8)
    int srow = l >> 2;
    int scol = (l & 3) * 8;

    for (int k0 = 0; k0 < K; k0 += 32) {
        // stage A and B tiles: 8 chunks each of 1024B; wave w does chunks w*2, w*2+1
        #pragma unroll
        for (int i = 0; i < 2; ++i) {
            int chunk = w * 2 + i;
            const unsigned short* asrc =
                A + (size_t)(row0 + chunk * 16 + srow) * K + k0 + scol;
            __builtin_amdgcn_global_load_lds((const AS1 void*)asrc,
                                             (AS3 void*)(Asb + chunk * 512), 16, 0, 0);
            const unsigned short* bsrc =
                BT + (size_t)(col0 + chunk * 16 + srow) * K + k0 + scol;
            __builtin_amdgcn_global_load_lds((const AS1 void*)bsrc,
                                             (AS3 void*)(Bsb + chunk * 512), 16, 0, 0);
        }
        __syncthreads();

        // fragment loads: lane l reads row (base + (l&15)), k-cols (l>>4)*8 .. +8
        int rsel = l & 15, csel = (l >> 4) * 8;
        short8 a[4], b[4];
        #pragma unroll
        for (int m = 0; m < 4; ++m)
            a[m] = *(const short8*)&Asb[(wr * 64 + m * 16 + rsel) * 32 + csel];
        #pragma unroll
        for (int n = 0; n < 4; ++n)
            b[n] = *(const short8*)&Bsb[(wc * 64 + n * 16 + rsel) * 32 + csel];
        #pragma unroll
        for (int m = 0; m < 4; ++m)
            #pragma unroll
            for (int n = 0; n < 4; ++n)
                acc[m][n] = __builtin_amdgcn_mfma_f32_16x16x32_bf16(a[m], b[n], acc[m][n], 0, 0, 0);
        __syncthreads();
    }

    // epilogue: D mapping col=lane&15, row=(lane>>4)*4+reg
    int ocol = l & 15, orow = (l >> 4) * 4;
    #pragma unroll
    for (int m = 0; m < 4; ++m)
        #pragma unroll
        for (int n = 0; n < 4; ++n) {
            size_t base = (size_t)(row0 + wr * 64 + m * 16 + orow) * N
                        + col0 + wc * 64 + n * 16 + ocol;
            #pragma unroll
            for (int j = 0; j < 4; ++j)
                C[base + (size_t)j * N] = acc[m][n][j];
        }
}

// ---------------------------------------------------------------------------
// kv_agg partials: for each (b,n) and j-chunk (256 j's), accumulate
//   kvagg[f][d] += pk[j,f] * v[j,d],  z[f] += pk[j,f]
// Grid: (8 chunks, 32 bn), 256 threads.
// ---------------------------------------------------------------------------
__global__ __launch_bounds__(256) void kvagg_kernel(const float* __restrict__ kv,
                                                    float* __restrict__ kvagg_part,
                                                    float* __restrict__ z_part) {
    __shared__ float x2[128];
    __shared__ float vs[64];
    __shared__ float pk[FEAT];
    int t = threadIdx.x;
    int chunk = blockIdx.x;   // 0..7 (j-chunks of 256)
    int bn = blockIdx.y;      // 0..31
    int b = bn >> 4, n = bn & 15;
    int fgrp = t >> 6, d = t & 63;
    float acc[96];
    #pragma unroll
    for (int m = 0; m < 96; ++m) acc[m] = 0.f;
    float zacc[3] = {0.f, 0.f, 0.f};
    int j0 = chunk * 256;
    for (int jj = 0; jj < 256; ++jj) {
        int j = j0 + jj;
        const float* krow = kv + (size_t)(j * BATCH + b) * 2048 + n * 64;
        if (t < 64) {
            float kvv = krow[t];
            x2[t] = fmaxf(kvv, 0.f);
            x2[t + 64] = fmaxf(-kvv, 0.f);
        } else if (t < 128) {
            vs[t - 64] = krow[1024 + (t - 64)];
        }
        __syncthreads();
        if (t < 128) {
            #pragma unroll
            for (int m = 0; m < 3; ++m)
                pk[t + 128 * m] = x2[t] * x2[(t - m - 1) & 127];
        }
        __syncthreads();
        float vval = vs[d];
        #pragma unroll
        for (int m = 0; m < 96; ++m)
            acc[m] = fmaf(pk[fgrp + 4 * m], vval, acc[m]);
        if (t < 128) {
            #pragma unroll
            for (int m = 0; m < 3; ++m) zacc[m] += pk[t + 128 * m];
        }
        __syncthreads();
    }
    float* outp = kvagg_part + (size_t)(chunk * 32 + bn) * FEAT * 64;
    #pragma unroll
    for (int m = 0; m < 96; ++m)
        outp[(fgrp + 4 * m) * 64 + d] = acc[m];
    if (t < 128) {
        float* zp = z_part + (size_t)(chunk * 32 + bn) * FEAT;
        #pragma unroll
        for (int m = 0; m < 3; ++m) zp[t + 128 * m] = zacc[m];
    }
}

// ---------------------------------------------------------------------------
// Reduce 8 partial chunks -> kv_agg [32][384][64] and z [32][384]
// ---------------------------------------------------------------------------
__global__ __launch_bounds__(256) void reduce_parts(const float* __restrict__ kvagg_part,
                                                    const float* __restrict__ z_part,
                                                    float* __restrict__ kv_agg,
                                                    float* __restrict__ z) {
    const int KVN = 32 * FEAT * 64;  // 786432
    int idx = blockIdx.x * 256 + threadIdx.x;
    if (idx < KVN) {
        float s = 0.f;
        #pragma unroll
        for (int c = 0; c < 8; ++c) s += kvagg_part[(size_t)c * KVN + idx];
        kv_agg[idx] = s;
    } else if (idx < KVN + 32 * FEAT) {
        int e = idx - KVN;
        float s = 0.f;
        #pragma unroll
        for (int c = 0; c < 8; ++c) s += z_part[c * 32 * FEAT + e];
        z[e] = s;
    }
}

// ---------------------------------------------------------------------------
// attn_vec: per (i,b,n) one wave. num = pq . kv_agg[:,d], den = pq . z.
// ---------------------------------------------------------------------------
__global__ __launch_bounds__(256) void attnvec_kernel(const float* __restrict__ q,
                                                      const float* __restrict__ kv_agg,
                                                      const float* __restrict__ z,
                                                      float* __restrict__ attn_vec) {
    __shared__ float x2s[4][128];
    __shared__ float pqs[4][FEAT];
    int t = threadIdx.x;
    int wl = t >> 6, lane = t & 63;
    int gw = blockIdx.x * 4 + wl;
    int i = gw & 2047;
    int bn = gw >> 11;
    int b = bn >> 4, n = bn & 15;
    float qv = q[(size_t)(i * BATCH + b) * 1024 + n * 64 + lane];
    x2s[wl][lane] = fmaxf(qv, 0.f);
    x2s[wl][64 + lane] = fmaxf(-qv, 0.f);
    __syncthreads();
    #pragma unroll
    for (int s6 = 0; s6 < 6; ++s6) {
        int f = lane + 64 * s6;
        int ir = (f >> 7) + 1;
        int jj = f & 127;
        pqs[wl][f] = x2s[wl][jj] * x2s[wl][(jj - ir) & 127];
    }
    __syncthreads();
    const float* kvp = kv_agg + (size_t)bn * FEAT * 64 + lane;
    float acc = 0.f;
    #pragma unroll 8
    for (int f = 0; f < FEAT; ++f)
        acc = fmaf(pqs[wl][f], kvp[(size_t)f * 64], acc);
    float dpart = 0.f;
    const float* zp = z + bn * FEAT;
    #pragma unroll
    for (int s6 = 0; s6 < 6; ++s6) {
        int f = lane + 64 * s6;
        dpart += pqs[wl][f] * zp[f];
    }
    #pragma unroll
    for (int off = 32; off >= 1; off >>= 1)
        dpart += __shfl_xor(dpart, off, 64);
    float den = dpart * SCALE + EPS;
    attn_vec[(size_t)(i * BATCH + b) * 1024 + n * 64 + lane] = acc * SCALE / den;
}

// ---------------------------------------------------------------------------
// Residual + LayerNorm over last dim (1024). One block per row.
// ---------------------------------------------------------------------------
__global__ __launch_bounds__(256) void ln_kernel(const float* __restrict__ h,
                                                 const float* __restrict__ attn_out,
                                                 const float* __restrict__ gamma,
                                                 const float* __restrict__ beta,
                                                 float* __restrict__ out) {
    int r = blockIdx.x;
    int t = threadIdx.x;
    float xs[4];
    float sum = 0.f, sq = 0.f;
    const float* hp = h + (size_t)r * 1024;
    const float* ap = attn_out + (size_t)r * 1024;
    #pragma unroll
    for (int j = 0; j < 4; ++j) {
        int c = t + 256 * j;
        float x = hp[c] + ap[c];
        xs[j] = x;
        sum += x;
        sq += x * x;
    }
    #pragma unroll
    for (int off = 32; off >= 1; off >>= 1) {
        sum += __shfl_xor(sum, off, 64);
        sq += __shfl_xor(sq, off, 64);
    }
    __shared__ float ssum[4], ssq[4];
    int wl = t >> 6, lane = t & 63;
    if (lane == 0) { ssum[wl] = sum; ssq[wl] = sq; }
    __syncthreads();
    sum = ssum[0] + ssum[1] + ssum[2] + ssum[3];
    sq = ssq[0] + ssq[1] + ssq[2] + ssq[3];
    float mu = sum * (1.f / 1024.f);
    float var = sq * (1.f / 1024.f) - mu * mu;
    float rs = rsqrtf(var + 1e-5f);
    float* op = out + (size_t)r * 1024;
    #pragma unroll
    for (int j = 0; j < 4; ++j) {
        int c = t + 256 * j;
        op[c] = (xs[j] - mu) * rs * gamma[c] + beta[c];
    }
}

// ---------------------------------------------------------------------------
extern "C" void kernel_launch(void* const* d_in, const int* in_sizes, int n_in,
                              void* d_out, int out_size, void* d_ws, size_t ws_size,
                              hipStream_t stream) {
    const float* h     = (const float*)d_in[0];
    const float* Wq    = (const float*)d_in[1];
    const float* Wkv   = (const float*)d_in[2];
    const float* Wo    = (const float*)d_in[3];
    const float* gamma = (const float*)d_in[4];
    const float* beta  = (const float*)d_in[5];
    float* out = (float*)d_out;
    float* ws  = (float*)d_ws;

    // f32 region (floats)
    float* q          = ws;               // 4,194,304 (reused as attn_out)
    float* kvbuf      = ws + 4194304;     // 8,388,608 (reused as attn_vec)
    float* kvagg_part = ws + 12582912;    // 8 x 786,432 = 6,291,456
    float* z_part     = ws + 18874368;    // 98,304
    float* kv_agg     = ws + 18972672;    // 786,432
    float* z          = ws + 19759104;    // 12,288
    // bf16 region (ushorts), starts at float offset 19,771,392
    unsigned short* bfbase = (unsigned short*)(ws + 19771392);
    unsigned short* h_bf   = bfbase;              // 4,194,304
    unsigned short* WqT    = bfbase + 4194304;    // 1,048,576
    unsigned short* WkvT   = bfbase + 5242880;    // 2,097,152
    unsigned short* WoT    = bfbase + 7340032;    // 1,048,576
    unsigned short* av_bf  = h_bf;                // reuse after projections done

    float* attn_vec = kvbuf;
    float* attn_out = q;

    dim3 blk(256);
    // 0) conversions
    conv_bf16<<<dim3(4096), blk, 0, stream>>>(h, h_bf, 1048576);
    transpose_bf16<<<dim3(32, 32), blk, 0, stream>>>(Wq, WqT, 1024, 1024);
    transpose_bf16<<<dim3(64, 32), blk, 0, stream>>>(Wkv, WkvT, 1024, 2048);
    transpose_bf16<<<dim3(32, 32), blk, 0, stream>>>(Wo, WoT, 1024, 1024);
    // 1) q = h @ Wq   [4096,1024] = [4096,1024]x[1024,1024]
    gemm_bf16<<<dim3(8, 32), blk, 0, stream>>>(h_bf, WqT, q, SB, 1024, DM);
    // 2) kv = h @ Wkv [4096,2048]
    gemm_bf16<<<dim3(16, 32), blk, 0, stream>>>(h_bf, WkvT, kvbuf, SB, 2048, DM);
    // 3) kv_agg partials + z partials (8 chunks x 256 j)
    kvagg_kernel<<<dim3(8, 32), blk, 0, stream>>>(kvbuf, kvagg_part, z_part);
    // 4) reduce partials
    reduce_parts<<<dim3((32 * FEAT * 64 + 32 * FEAT + 255) / 256), blk, 0, stream>>>(
        kvagg_part, z_part, kv_agg, z);
    // 5) attn_vec
    attnvec_kernel<<<dim3(16384), blk, 0, stream>>>(q, kv_agg, z, attn_vec);
    // 6) attn_out = attn_vec @ Wo
    conv_bf16<<<dim3(4096), blk, 0, stream>>>(attn_vec, av_bf, 1048576);
    gemm_bf16<<<dim3(8, 32), blk, 0, stream>>>(av_bf, WoT, attn_out, SB, 1024, DM);
    // 7) out = LayerNorm(h + attn_out)
    ln_kernel<<<dim3(SB), blk, 0, stream>>>(h, attn_out, gamma, beta, out);
}

// Round 3
// 290.669 us; speedup vs baseline: 3.6023x; 1.9828x over previous
//
#include <hip/hip_runtime.h>
#include <math.h>

// Problem constants
#define NH 16
#define DM 1024
#define FEAT 384          // 2*64*3
#define SB 4096           // S*B
#define SEQ 2048

static constexpr float SCALE = 0.125f;  // 1/sqrt(64)
static constexpr float EPS = 1e-5f;

typedef __attribute__((ext_vector_type(8))) short short8;
typedef __attribute__((ext_vector_type(4))) float f32x4;

#define AS1 __attribute__((address_space(1)))
#define AS3 __attribute__((address_space(3)))

// f32 -> bf16 (RNE) as raw ushort
__device__ __forceinline__ unsigned short f2bf(float x) {
    unsigned int u = __float_as_uint(x);
    u += 0x7FFFu + ((u >> 16) & 1u);
    return (unsigned short)(u >> 16);
}
__device__ __forceinline__ float bf2f(short s) {
    return __uint_as_float(((unsigned int)(unsigned short)s) << 16);
}

// ---------------------------------------------------------------------------
// f32 -> bf16 straight conversion (float4 in, ushort4 out)
// ---------------------------------------------------------------------------
__global__ __launch_bounds__(256) void conv_bf16(const float* __restrict__ src,
                                                 unsigned short* __restrict__ dst,
                                                 int n4) {
    int i = blockIdx.x * 256 + threadIdx.x;
    if (i >= n4) return;
    const float4 v = ((const float4*)src)[i];
    ushort4 o;
    o.x = f2bf(v.x); o.y = f2bf(v.y); o.z = f2bf(v.z); o.w = f2bf(v.w);
    ((ushort4*)dst)[i] = o;
}

// ---------------------------------------------------------------------------
// Transpose-convert: src f32 [K][N] -> dst bf16 [N][K]
// ---------------------------------------------------------------------------
__global__ __launch_bounds__(256) void transpose_bf16(const float* __restrict__ src,
                                                      unsigned short* __restrict__ dst,
                                                      int K, int N) {
    __shared__ unsigned short tile[32][33];
    int n0 = blockIdx.x * 32, k0 = blockIdx.y * 32;
    int tx = threadIdx.x & 31, ty = threadIdx.x >> 5;
    #pragma unroll
    for (int i = 0; i < 4; ++i) {
        int k = k0 + ty + i * 8;
        tile[ty + i * 8][tx] = f2bf(src[(size_t)k * N + n0 + tx]);
    }
    __syncthreads();
    #pragma unroll
    for (int i = 0; i < 4; ++i) {
        int n = n0 + ty + i * 8;
        dst[(size_t)n * K + k0 + tx] = tile[tx][ty + i * 8];
    }
}

// ---------------------------------------------------------------------------
// bf16 MFMA GEMM: C_f32[M,N] = A_bf16[M,K] @ (BT_bf16[N,K])^T
// 128x128 tile, 4 waves 2x2, BK=32, m97 structure.
// ---------------------------------------------------------------------------
__global__ __launch_bounds__(256) void gemm_bf16(const unsigned short* __restrict__ A,
                                                 const unsigned short* __restrict__ BT,
                                                 float* __restrict__ C,
                                                 int M, int N, int K) {
    __shared__ unsigned short Asb[128 * 32];
    __shared__ unsigned short Bsb[128 * 32];
    int t = threadIdx.x;
    int w = t >> 6, l = t & 63;
    int wr = w >> 1, wc = w & 1;
    int row0 = blockIdx.y * 128, col0 = blockIdx.x * 128;

    f32x4 acc[4][4];
    #pragma unroll
    for (int m = 0; m < 4; ++m)
        #pragma unroll
        for (int n = 0; n < 4; ++n)
            acc[m][n] = (f32x4){0.f, 0.f, 0.f, 0.f};

    int srow = l >> 2;
    int scol = (l & 3) * 8;

    for (int k0 = 0; k0 < K; k0 += 32) {
        #pragma unroll
        for (int i = 0; i < 2; ++i) {
            int chunk = w * 2 + i;
            const unsigned short* asrc =
                A + (size_t)(row0 + chunk * 16 + srow) * K + k0 + scol;
            __builtin_amdgcn_global_load_lds((const AS1 void*)asrc,
                                             (AS3 void*)(Asb + chunk * 512), 16, 0, 0);
            const unsigned short* bsrc =
                BT + (size_t)(col0 + chunk * 16 + srow) * K + k0 + scol;
            __builtin_amdgcn_global_load_lds((const AS1 void*)bsrc,
                                             (AS3 void*)(Bsb + chunk * 512), 16, 0, 0);
        }
        __syncthreads();
        int rsel = l & 15, csel = (l >> 4) * 8;
        short8 a[4], b[4];
        #pragma unroll
        for (int m = 0; m < 4; ++m)
            a[m] = *(const short8*)&Asb[(wr * 64 + m * 16 + rsel) * 32 + csel];
        #pragma unroll
        for (int n = 0; n < 4; ++n)
            b[n] = *(const short8*)&Bsb[(wc * 64 + n * 16 + rsel) * 32 + csel];
        #pragma unroll
        for (int m = 0; m < 4; ++m)
            #pragma unroll
            for (int n = 0; n < 4; ++n)
                acc[m][n] = __builtin_amdgcn_mfma_f32_16x16x32_bf16(a[m], b[n], acc[m][n], 0, 0, 0);
        __syncthreads();
    }

    int ocol = l & 15, orow = (l >> 4) * 4;
    #pragma unroll
    for (int m = 0; m < 4; ++m)
        #pragma unroll
        for (int n = 0; n < 4; ++n) {
            size_t base = (size_t)(row0 + wr * 64 + m * 16 + orow) * N
                        + col0 + wc * 64 + n * 16 + ocol;
            #pragma unroll
            for (int j = 0; j < 4; ++j)
                C[base + (size_t)j * N] = acc[m][n][j];
        }
}

// ---------------------------------------------------------------------------
// featk: from kv f32, produce pkT bf16 [bnl][384][2048] and vT bf16 [bnl][64][2048]
// Grid: (8 bnl, 64 j-tiles of 32), 256 threads.
// ---------------------------------------------------------------------------
__global__ __launch_bounds__(256) void featk_kernel(const float* __restrict__ kv,
                                                    unsigned short* __restrict__ pkT,
                                                    unsigned short* __restrict__ vT,
                                                    int bn0) {
    __shared__ float x2[128][33];
    __shared__ unsigned short vls[64][40];
    int t = threadIdx.x;
    int bnl = blockIdx.x;
    int bn = bn0 + bnl;
    int b = bn >> 4, nh = bn & 15;
    int j0 = blockIdx.y * 32;
    int c = t & 63;
    #pragma unroll
    for (int ii = 0; ii < 8; ++ii) {
        int jl = ii * 4 + (t >> 6);
        const float* row = kv + (size_t)((j0 + jl) * 2 + b) * 2048 + nh * 64;
        float kd = row[c];
        float vd = row[1024 + c];
        x2[c][jl] = fmaxf(kd, 0.f);
        x2[c + 64][jl] = fmaxf(-kd, 0.f);
        vls[c][jl] = f2bf(vd);
    }
    __syncthreads();
    // vT write: d = t>>2, jj0 = (t&3)*8 -> one short8
    {
        int d = t >> 2, jj0 = (t & 3) * 8;
        short8 o;
        #pragma unroll
        for (int e = 0; e < 8; ++e) o[e] = (short)vls[d][jj0 + e];
        *(short8*)&vT[((size_t)bnl * 64 + d) * 2048 + j0 + jj0] = o;
    }
    // pkT write: 6 f-blocks of 64
    int fr = t >> 2, jj0 = (t & 3) * 8;
    #pragma unroll
    for (int fb = 0; fb < 6; ++fb) {
        int f = fb * 64 + fr;
        int fm = f & 127;
        int r = (f >> 7) + 1;
        int fm2 = (fm - r) & 127;
        short8 o;
        #pragma unroll
        for (int e = 0; e < 8; ++e)
            o[e] = (short)f2bf(x2[fm][jj0 + e] * x2[fm2][jj0 + e]);
        *(short8*)&pkT[((size_t)bnl * FEAT + f) * 2048 + j0 + jj0] = o;
    }
}

// ---------------------------------------------------------------------------
// featq: from q f32, produce pq bf16 [bnl][2048][384]
// Grid: (8 bnl, 64 i-tiles of 32), 256 threads.
// ---------------------------------------------------------------------------
__global__ __launch_bounds__(256) void featq_kernel(const float* __restrict__ q,
                                                    unsigned short* __restrict__ pq,
                                                    int bn0) {
    __shared__ float y2[32][130];
    int t = threadIdx.x;
    int bnl = blockIdx.x;
    int bn = bn0 + bnl;
    int b = bn >> 4, nh = bn & 15;
    int i0 = blockIdx.y * 32;
    int d = t & 63;
    #pragma unroll
    for (int ii = 0; ii < 8; ++ii) {
        int il = ii * 4 + (t >> 6);
        float qv = q[(size_t)((i0 + il) * 2 + b) * 1024 + nh * 64 + d];
        y2[il][d] = fmaxf(qv, 0.f);
        y2[il][64 + d] = fmaxf(-qv, 0.f);
    }
    __syncthreads();
    int i = t >> 3, f0 = (t & 7) * 48;
    unsigned short obuf[48];
    #pragma unroll
    for (int ff = 0; ff < 48; ++ff) {
        int f = f0 + ff;
        int fm = f & 127;
        int r = (f >> 7) + 1;
        int fm2 = (fm - r) & 127;
        obuf[ff] = f2bf(y2[i][fm] * y2[i][fm2]);
    }
    unsigned short* dst = &pq[((size_t)bnl * SEQ + i0 + i) * FEAT + f0];
    #pragma unroll
    for (int s = 0; s < 6; ++s)
        *(short8*)&dst[s * 8] = *(short8*)&obuf[s * 8];
}

// ---------------------------------------------------------------------------
// kvagg GEMM (batched, K-split): per (bnl, kseg):
//   kvp[kseg][bnl][d=64][f=384] = vT[d][kseg-slice] @ pkT[f][kseg-slice]^T
//   zp[kseg][bnl][f] = sum_j pkT[f][j]  (wr==0 waves)
// Block: BM=64(d) x BN=128(f), 4 waves 2x2 (WM=32,WN=64). Grid (3, 8, 4).
// ---------------------------------------------------------------------------
__global__ __launch_bounds__(256) void kvagg_gemm(const unsigned short* __restrict__ vT,
                                                  const unsigned short* __restrict__ pkT,
                                                  float* __restrict__ kvp,
                                                  float* __restrict__ zp) {
    __shared__ unsigned short Asb[64 * 32];
    __shared__ unsigned short Bsb[128 * 32];
    int t = threadIdx.x;
    int w = t >> 6, l = t & 63;
    int wr = w >> 1, wc = w & 1;
    int fblk = blockIdx.x;   // 0..2
    int bnl = blockIdx.y;    // 0..7
    int kseg = blockIdx.z;   // 0..3
    const unsigned short* Abase = vT + (size_t)bnl * 64 * 2048;
    const unsigned short* Bbase = pkT + ((size_t)bnl * FEAT + fblk * 128) * 2048;

    f32x4 acc[2][4];
    #pragma unroll
    for (int m = 0; m < 2; ++m)
        #pragma unroll
        for (int n = 0; n < 4; ++n)
            acc[m][n] = (f32x4){0.f, 0.f, 0.f, 0.f};
    float zacc[4] = {0.f, 0.f, 0.f, 0.f};

    int srow = l >> 2, scol = (l & 3) * 8;
    int rsel = l & 15, csel = (l >> 4) * 8;

    for (int k0 = kseg * 512; k0 < kseg * 512 + 512; k0 += 32) {
        #pragma unroll
        for (int i = 0; i < 3; ++i) {
            int idx = w * 3 + i;
            if (idx < 4) {
                const unsigned short* src = Abase + (size_t)(idx * 16 + srow) * 2048 + k0 + scol;
                __builtin_amdgcn_global_load_lds((const AS1 void*)src,
                                                 (AS3 void*)(Asb + idx * 512), 16, 0, 0);
            } else {
                int cB = idx - 4;
                const unsigned short* src = Bbase + (size_t)(cB * 16 + srow) * 2048 + k0 + scol;
                __builtin_amdgcn_global_load_lds((const AS1 void*)src,
                                                 (AS3 void*)(Bsb + cB * 512), 16, 0, 0);
            }
        }
        __syncthreads();
        short8 a[2], bfr[4];
        #pragma unroll
        for (int m = 0; m < 2; ++m)
            a[m] = *(const short8*)&Asb[(wr * 32 + m * 16 + rsel) * 32 + csel];
        #pragma unroll
        for (int n = 0; n < 4; ++n)
            bfr[n] = *(const short8*)&Bsb[(wc * 64 + n * 16 + rsel) * 32 + csel];
        if (wr == 0) {
            #pragma unroll
            for (int n = 0; n < 4; ++n)
                #pragma unroll
                for (int e = 0; e < 8; ++e)
                    zacc[n] += bf2f(bfr[n][e]);
        }
        #pragma unroll
        for (int m = 0; m < 2; ++m)
            #pragma unroll
            for (int n = 0; n < 4; ++n)
                acc[m][n] = __builtin_amdgcn_mfma_f32_16x16x32_bf16(a[m], bfr[n], acc[m][n], 0, 0, 0);
        __syncthreads();
    }

    // z partial: reduce across k-groups, lanes 0..15 of wr==0 waves write
    #pragma unroll
    for (int n = 0; n < 4; ++n) {
        float v = zacc[n];
        v += __shfl_xor(v, 16, 64);
        v += __shfl_xor(v, 32, 64);
        if (wr == 0 && l < 16)
            zp[(size_t)(kseg * 8 + bnl) * FEAT + fblk * 128 + wc * 64 + n * 16 + l] = v;
    }
    // partial C write (f32)
    int orow = (l >> 4) * 4, ocol = l & 15;
    float* outp = kvp + (size_t)(kseg * 8 + bnl) * 64 * FEAT;
    #pragma unroll
    for (int m = 0; m < 2; ++m)
        #pragma unroll
        for (int n = 0; n < 4; ++n) {
            int fcol = fblk * 128 + wc * 64 + n * 16 + ocol;
            #pragma unroll
            for (int j = 0; j < 4; ++j)
                outp[(size_t)(wr * 32 + m * 16 + orow + j) * FEAT + fcol] = acc[m][n][j];
        }
}

// ---------------------------------------------------------------------------
// Reduce 4 k-segments -> kvaggT bf16 [bn][64][384], z f32 [bn][384]
// ---------------------------------------------------------------------------
__global__ __launch_bounds__(256) void reduceA(const float* __restrict__ kvp,
                                               const float* __restrict__ zp,
                                               unsigned short* __restrict__ kvaggT,
                                               float* __restrict__ z,
                                               int bn0) {
    const int NKV = 8 * 64 * FEAT;  // 196608
    int idx = blockIdx.x * 256 + threadIdx.x;
    if (idx < NKV) {
        float s = 0.f;
        #pragma unroll
        for (int c = 0; c < 4; ++c) s += kvp[(size_t)c * NKV + idx];
        int bnl = idx / (64 * FEAT);
        int rem = idx - bnl * (64 * FEAT);
        kvaggT[(size_t)(bn0 + bnl) * 64 * FEAT + rem] = f2bf(s);
    } else if (idx < NKV + 8 * FEAT) {
        int e = idx - NKV;
        float s = 0.f;
        #pragma unroll
        for (int c = 0; c < 4; ++c) s += zp[c * 8 * FEAT + e];
        int bnl = e / FEAT;
        z[(size_t)(bn0 + bnl) * FEAT + (e - bnl * FEAT)] = s;
    }
}

// ---------------------------------------------------------------------------
// attn GEMM (batched): per bnl: C[i=2048][d=64] = pq[i][f] @ kvaggT[d][f]^T
// plus fused den = pq . z, divide, bf16 output into av.
// Block BM=128 x BN=64, 4 waves 4x1 (WM=32,WN=64). Grid (16, 8).
// ---------------------------------------------------------------------------
__global__ __launch_bounds__(256) void attn_gemm(const unsigned short* __restrict__ pq,
                                                 const unsigned short* __restrict__ kvaggT,
                                                 const float* __restrict__ z,
                                                 unsigned short* __restrict__ av,
                                                 int bn0) {
    __shared__ unsigned short Asb[128 * 32];
    __shared__ unsigned short Bsb[64 * 32];
    __shared__ float z_lds[FEAT];
    __shared__ float den_lds[128];
    int t = threadIdx.x;
    int w = t >> 6, l = t & 63;
    int iblk = blockIdx.x;   // 0..15
    int bnl = blockIdx.y;
    int bn = bn0 + bnl;
    int b = bn >> 4, nh = bn & 15;
    const unsigned short* Abase = pq + ((size_t)bnl * SEQ + iblk * 128) * FEAT;
    const unsigned short* Bbase = kvaggT + (size_t)bn * 64 * FEAT;

    for (int e = t; e < FEAT; e += 256) z_lds[e] = z[(size_t)bn * FEAT + e];

    f32x4 acc[2][4];
    #pragma unroll
    for (int m = 0; m < 2; ++m)
        #pragma unroll
        for (int n = 0; n < 4; ++n)
            acc[m][n] = (f32x4){0.f, 0.f, 0.f, 0.f};
    float denacc[2] = {0.f, 0.f};

    int srow = l >> 2, scol = (l & 3) * 8;
    int rsel = l & 15, csel = (l >> 4) * 8;

    for (int k0 = 0; k0 < FEAT; k0 += 32) {
        #pragma unroll
        for (int i = 0; i < 3; ++i) {
            int idx = w * 3 + i;
            if (idx < 8) {
                const unsigned short* src = Abase + (size_t)(idx * 16 + srow) * FEAT + k0 + scol;
                __builtin_amdgcn_global_load_lds((const AS1 void*)src,
                                                 (AS3 void*)(Asb + idx * 512), 16, 0, 0);
            } else {
                int cB = idx - 8;
                const unsigned short* src = Bbase + (size_t)(cB * 16 + srow) * FEAT + k0 + scol;
                __builtin_amdgcn_global_load_lds((const AS1 void*)src,
                                                 (AS3 void*)(Bsb + cB * 512), 16, 0, 0);
            }
        }
        __syncthreads();
        short8 a[2], bfr[4];
        #pragma unroll
        for (int m = 0; m < 2; ++m)
            a[m] = *(const short8*)&Asb[(w * 32 + m * 16 + rsel) * 32 + csel];
        #pragma unroll
        for (int n = 0; n < 4; ++n)
            bfr[n] = *(const short8*)&Bsb[(n * 16 + rsel) * 32 + csel];
        #pragma unroll
        for (int m = 0; m < 2; ++m)
            #pragma unroll
            for (int e = 0; e < 8; ++e)
                denacc[m] += bf2f(a[m][e]) * z_lds[k0 + csel + e];
        #pragma unroll
        for (int m = 0; m < 2; ++m)
            #pragma unroll
            for (int n = 0; n < 4; ++n)
                acc[m][n] = __builtin_amdgcn_mfma_f32_16x16x32_bf16(a[m], bfr[n], acc[m][n], 0, 0, 0);
        __syncthreads();
    }

    #pragma unroll
    for (int m = 0; m < 2; ++m) {
        float v = denacc[m];
        v += __shfl_xor(v, 16, 64);
        v += __shfl_xor(v, 32, 64);
        if (l < 16) den_lds[w * 32 + m * 16 + l] = v;
    }
    __syncthreads();

    int orow = (l >> 4) * 4, ocol = l & 15;
    #pragma unroll
    for (int m = 0; m < 2; ++m)
        #pragma unroll
        for (int n = 0; n < 4; ++n)
            #pragma unroll
            for (int j = 0; j < 4; ++j) {
                int row = w * 32 + m * 16 + orow + j;
                float den = den_lds[row] * SCALE + EPS;
                float val = acc[m][n][j] * SCALE / den;
                int i = iblk * 128 + row;
                av[((size_t)i * 2 + b) * 1024 + nh * 64 + n * 16 + ocol] = f2bf(val);
            }
}

// ---------------------------------------------------------------------------
// Residual + LayerNorm over last dim (1024). One block per row.
// ---------------------------------------------------------------------------
__global__ __launch_bounds__(256) void ln_kernel(const float* __restrict__ h,
                                                 const float* __restrict__ attn_out,
                                                 const float* __restrict__ gamma,
                                                 const float* __restrict__ beta,
                                                 float* __restrict__ out) {
    int r = blockIdx.x;
    int t = threadIdx.x;
    float xs[4];
    float sum = 0.f, sq = 0.f;
    const float* hp = h + (size_t)r * 1024;
    const float* ap = attn_out + (size_t)r * 1024;
    #pragma unroll
    for (int j = 0; j < 4; ++j) {
        int c = t + 256 * j;
        float x = hp[c] + ap[c];
        xs[j] = x;
        sum += x;
        sq += x * x;
    }
    #pragma unroll
    for (int off = 32; off >= 1; off >>= 1) {
        sum += __shfl_xor(sum, off, 64);
        sq += __shfl_xor(sq, off, 64);
    }
    __shared__ float ssum[4], ssq[4];
    int wl = t >> 6, lane = t & 63;
    if (lane == 0) { ssum[wl] = sum; ssq[wl] = sq; }
    __syncthreads();
    sum = ssum[0] + ssum[1] + ssum[2] + ssum[3];
    sq = ssq[0] + ssq[1] + ssq[2] + ssq[3];
    float mu = sum * (1.f / 1024.f);
    float var = sq * (1.f / 1024.f) - mu * mu;
    float rs = rsqrtf(var + 1e-5f);
    float* op = out + (size_t)r * 1024;
    #pragma unroll
    for (int j = 0; j < 4; ++j) {
        int c = t + 256 * j;
        op[c] = (xs[j] - mu) * rs * gamma[c] + beta[c];
    }
}

// ---------------------------------------------------------------------------
extern "C" void kernel_launch(void* const* d_in, const int* in_sizes, int n_in,
                              void* d_out, int out_size, void* d_ws, size_t ws_size,
                              hipStream_t stream) {
    const float* h     = (const float*)d_in[0];
    const float* Wq    = (const float*)d_in[1];
    const float* Wkv   = (const float*)d_in[2];
    const float* Wo    = (const float*)d_in[3];
    const float* gamma = (const float*)d_in[4];
    const float* beta  = (const float*)d_in[5];
    float* out = (float*)d_out;
    unsigned short* u = (unsigned short*)d_ws;

    // Workspace layout (ushort offsets) — total 49,594,368 u = 99.2 MB
    unsigned short* h_bf   = u;                 // 4,194,304 (reused as av)
    unsigned short* WqT    = u + 4194304;       // 1,048,576
    unsigned short* WkvT   = u + 5242880;       // 2,097,152
    unsigned short* WoT    = u + 7340032;       // 1,048,576
    float* q               = (float*)(u + 8388608);    // 4,194,304 f (reused attn_out)
    float* kvbuf           = (float*)(u + 16777216);   // 8,388,608 f
    unsigned short* pkT_g  = u + 33554432;      // 6,291,456
    unsigned short* vT_g   = u + 39845888;      // 1,048,576
    unsigned short* pq_g   = u + 40894464;      // 6,291,456
    unsigned short* kvaggT = u + 47185920;      // 786,432
    float* z               = (float*)(u + 47972352);   // 12,288 f
    float* kvp_g           = (float*)(u + 47996928);   // 786,432 f
    float* zp_g            = (float*)(u + 49569792);   // 12,288 f
    unsigned short* av     = h_bf;              // reuse after gemm kv
    float* attn_out        = q;                 // reuse after featq

    dim3 blk(256);
    // 0) conversions
    conv_bf16<<<dim3(4096), blk, 0, stream>>>(h, h_bf, 1048576);
    transpose_bf16<<<dim3(32, 32), blk, 0, stream>>>(Wq, WqT, 1024, 1024);
    transpose_bf16<<<dim3(64, 32), blk, 0, stream>>>(Wkv, WkvT, 1024, 2048);
    transpose_bf16<<<dim3(32, 32), blk, 0, stream>>>(Wo, WoT, 1024, 1024);
    // 1) projections
    gemm_bf16<<<dim3(8, 32), blk, 0, stream>>>(h_bf, WqT, q, SB, 1024, DM);
    gemm_bf16<<<dim3(16, 32), blk, 0, stream>>>(h_bf, WkvT, kvbuf, SB, 2048, DM);
    // 2) kv_agg + z per group of 8 (b,n)
    for (int g = 0; g < 4; ++g) {
        featk_kernel<<<dim3(8, 64), blk, 0, stream>>>(kvbuf, pkT_g, vT_g, g * 8);
        kvagg_gemm<<<dim3(3, 8, 4), blk, 0, stream>>>(vT_g, pkT_g, kvp_g, zp_g);
        reduceA<<<dim3(780), blk, 0, stream>>>(kvp_g, zp_g, kvaggT, z, g * 8);
    }
    // 3) attn_vec per group
    for (int g = 0; g < 4; ++g) {
        featq_kernel<<<dim3(8, 64), blk, 0, stream>>>(q, pq_g, g * 8);
        attn_gemm<<<dim3(16, 8), blk, 0, stream>>>(pq_g, kvaggT, z, av, g * 8);
    }
    // 4) output projection + LN
    gemm_bf16<<<dim3(8, 32), blk, 0, stream>>>(av, WoT, attn_out, SB, 1024, DM);
    ln_kernel<<<dim3(SB), blk, 0, stream>>>(h, attn_out, gamma, beta, out);
}

// Round 4
// 184.513 us; speedup vs baseline: 5.6748x; 1.5753x over previous
//
#include <hip/hip_runtime.h>
#include <math.h>

// Problem constants
#define NH 16
#define DM 1024
#define FEAT 384          // 2*64*3
#define SB 4096           // S*B
#define SEQ 2048

static constexpr float SCALE = 0.125f;  // 1/sqrt(64)
static constexpr float EPS = 1e-5f;

typedef __attribute__((ext_vector_type(8))) _Float16 half8;
typedef __attribute__((ext_vector_type(4))) _Float16 half4;
typedef __attribute__((ext_vector_type(4))) float f32x4;

#define AS1 __attribute__((address_space(1)))
#define AS3 __attribute__((address_space(3)))

// ---------------------------------------------------------------------------
// f32 -> f16 straight conversion (float4 in, half4 out)
// ---------------------------------------------------------------------------
__global__ __launch_bounds__(256) void conv_h16(const float* __restrict__ src,
                                                _Float16* __restrict__ dst,
                                                int n4) {
    int i = blockIdx.x * 256 + threadIdx.x;
    if (i >= n4) return;
    const float4 v = ((const float4*)src)[i];
    half4 o = {(_Float16)v.x, (_Float16)v.y, (_Float16)v.z, (_Float16)v.w};
    ((half4*)dst)[i] = o;
}

// ---------------------------------------------------------------------------
// Transpose-convert into dst f16 [Ntot][1024].
// Row n of dst: n<1024 -> srcA col n; else srcB col n-1024.
// srcA is [1024][1024], srcB is [1024][2048]. Grid (Ntot/32, 32).
// ---------------------------------------------------------------------------
__global__ __launch_bounds__(256) void transpose_h16(const float* __restrict__ srcA,
                                                     const float* __restrict__ srcB,
                                                     _Float16* __restrict__ dst) {
    __shared__ _Float16 tile[32][33];
    int n0 = blockIdx.x * 32, k0 = blockIdx.y * 32;
    const float* src;
    int N, col0;
    if (n0 < 1024) { src = srcA; N = 1024; col0 = n0; }
    else           { src = srcB; N = 2048; col0 = n0 - 1024; }
    int tx = threadIdx.x & 31, ty = threadIdx.x >> 5;
    #pragma unroll
    for (int i = 0; i < 4; ++i) {
        int k = k0 + ty + i * 8;
        tile[ty + i * 8][tx] = (_Float16)src[(size_t)k * N + col0 + tx];
    }
    __syncthreads();
    #pragma unroll
    for (int i = 0; i < 4; ++i) {
        int n = n0 + ty + i * 8;
        dst[(size_t)n * 1024 + k0 + tx] = tile[tx][ty + i * 8];
    }
}

// ---------------------------------------------------------------------------
// f16 MFMA GEMM: C[M,N] = A_f16[M,K] @ (BT_f16[N,K])^T
// 128x128 tile, 4 waves 2x2, BK=32, m97 structure. OUT_HALF: f16 vs f32 C.
// ---------------------------------------------------------------------------
template <bool OUT_HALF>
__global__ __launch_bounds__(256) void gemm_f16(const _Float16* __restrict__ A,
                                                const _Float16* __restrict__ BT,
                                                void* __restrict__ Cv,
                                                int M, int N, int K) {
    __shared__ _Float16 Asb[128 * 32];
    __shared__ _Float16 Bsb[128 * 32];
    int t = threadIdx.x;
    int w = t >> 6, l = t & 63;
    int wr = w >> 1, wc = w & 1;
    int row0 = blockIdx.y * 128, col0 = blockIdx.x * 128;

    f32x4 acc[4][4];
    #pragma unroll
    for (int m = 0; m < 4; ++m)
        #pragma unroll
        for (int n = 0; n < 4; ++n)
            acc[m][n] = (f32x4){0.f, 0.f, 0.f, 0.f};

    int srow = l >> 2;
    int scol = (l & 3) * 8;

    for (int k0 = 0; k0 < K; k0 += 32) {
        #pragma unroll
        for (int i = 0; i < 2; ++i) {
            int chunk = w * 2 + i;
            const _Float16* asrc =
                A + (size_t)(row0 + chunk * 16 + srow) * K + k0 + scol;
            __builtin_amdgcn_global_load_lds((const AS1 void*)asrc,
                                             (AS3 void*)(Asb + chunk * 512), 16, 0, 0);
            const _Float16* bsrc =
                BT + (size_t)(col0 + chunk * 16 + srow) * K + k0 + scol;
            __builtin_amdgcn_global_load_lds((const AS1 void*)bsrc,
                                             (AS3 void*)(Bsb + chunk * 512), 16, 0, 0);
        }
        __syncthreads();
        int rsel = l & 15, csel = (l >> 4) * 8;
        half8 a[4], b[4];
        #pragma unroll
        for (int m = 0; m < 4; ++m)
            a[m] = *(const half8*)&Asb[(wr * 64 + m * 16 + rsel) * 32 + csel];
        #pragma unroll
        for (int n = 0; n < 4; ++n)
            b[n] = *(const half8*)&Bsb[(wc * 64 + n * 16 + rsel) * 32 + csel];
        #pragma unroll
        for (int m = 0; m < 4; ++m)
            #pragma unroll
            for (int n = 0; n < 4; ++n)
                acc[m][n] = __builtin_amdgcn_mfma_f32_16x16x32_f16(a[m], b[n], acc[m][n], 0, 0, 0);
        __syncthreads();
    }

    int ocol = l & 15, orow = (l >> 4) * 4;
    #pragma unroll
    for (int m = 0; m < 4; ++m)
        #pragma unroll
        for (int n = 0; n < 4; ++n) {
            size_t base = (size_t)(row0 + wr * 64 + m * 16 + orow) * N
                        + col0 + wc * 64 + n * 16 + ocol;
            #pragma unroll
            for (int j = 0; j < 4; ++j) {
                if constexpr (OUT_HALF)
                    ((_Float16*)Cv)[base + (size_t)j * N] = (_Float16)acc[m][n][j];
                else
                    ((float*)Cv)[base + (size_t)j * N] = acc[m][n][j];
            }
        }
}

// ---------------------------------------------------------------------------
// featk: from qkv f16, produce pkT f16 [bnl][384][2048], vT f16 [bnl][64][2048]
// for 16 (b,n) per group. Grid: (16, 64 j-tiles of 32), 256 threads.
// ---------------------------------------------------------------------------
__global__ __launch_bounds__(256) void featk_kernel(const _Float16* __restrict__ qkv,
                                                    _Float16* __restrict__ pkT,
                                                    _Float16* __restrict__ vT,
                                                    int bn0) {
    __shared__ float x2[128][33];
    __shared__ _Float16 vls[64][40];
    int t = threadIdx.x;
    int bnl = blockIdx.x;
    int bn = bn0 + bnl;
    int b = bn >> 4, nh = bn & 15;
    int j0 = blockIdx.y * 32;
    int c = t & 63;
    #pragma unroll
    for (int ii = 0; ii < 8; ++ii) {
        int jl = ii * 4 + (t >> 6);
        const _Float16* row = qkv + (size_t)((j0 + jl) * 2 + b) * 3072 + nh * 64;
        float kd = (float)row[1024 + c];
        vls[c][jl] = row[2048 + c];
        x2[c][jl] = fmaxf(kd, 0.f);
        x2[c + 64][jl] = fmaxf(-kd, 0.f);
    }
    __syncthreads();
    {
        int d = t >> 2, jj0 = (t & 3) * 8;
        half8 o;
        #pragma unroll
        for (int e = 0; e < 8; ++e) o[e] = vls[d][jj0 + e];
        *(half8*)&vT[((size_t)bnl * 64 + d) * 2048 + j0 + jj0] = o;
    }
    int fr = t >> 2, jj0 = (t & 3) * 8;
    #pragma unroll
    for (int fb = 0; fb < 6; ++fb) {
        int f = fb * 64 + fr;
        int fm = f & 127;
        int r = (f >> 7) + 1;
        int fm2 = (fm - r) & 127;
        half8 o;
        #pragma unroll
        for (int e = 0; e < 8; ++e)
            o[e] = (_Float16)(x2[fm][jj0 + e] * x2[fm2][jj0 + e]);
        *(half8*)&pkT[((size_t)bnl * FEAT + f) * 2048 + j0 + jj0] = o;
    }
}

// ---------------------------------------------------------------------------
// featq: from qkv f16 (q part), produce pq f16 [bn][2048][384] for ALL 32 bn.
// Grid: (32, 64 i-tiles of 32), 256 threads.
// ---------------------------------------------------------------------------
__global__ __launch_bounds__(256) void featq_kernel(const _Float16* __restrict__ qkv,
                                                    _Float16* __restrict__ pq) {
    __shared__ float y2[32][130];
    int t = threadIdx.x;
    int bn = blockIdx.x;
    int b = bn >> 4, nh = bn & 15;
    int i0 = blockIdx.y * 32;
    int d = t & 63;
    #pragma unroll
    for (int ii = 0; ii < 8; ++ii) {
        int il = ii * 4 + (t >> 6);
        float qv = (float)qkv[(size_t)((i0 + il) * 2 + b) * 3072 + nh * 64 + d];
        y2[il][d] = fmaxf(qv, 0.f);
        y2[il][64 + d] = fmaxf(-qv, 0.f);
    }
    __syncthreads();
    int i = t >> 3, f0 = (t & 7) * 48;
    _Float16 obuf[48];
    #pragma unroll
    for (int ff = 0; ff < 48; ++ff) {
        int f = f0 + ff;
        int fm = f & 127;
        int r = (f >> 7) + 1;
        int fm2 = (fm - r) & 127;
        obuf[ff] = (_Float16)(y2[i][fm] * y2[i][fm2]);
    }
    _Float16* dst = &pq[((size_t)bn * SEQ + i0 + i) * FEAT + f0];
    #pragma unroll
    for (int s = 0; s < 6; ++s)
        *(half8*)&dst[s * 8] = *(half8*)&obuf[s * 8];
}

// ---------------------------------------------------------------------------
// kvagg GEMM (16 bn per group, K-split 4): per (fblk, bnl, kseg):
//   kvp[kseg][bnl][64][384-slice] = vT @ pkT^T over 512 j
//   zp[kseg][bnl][f] = sum_j pk[f][j]   (wr==0 waves)
// Block: BM=64(d) x BN=128(f), 4 waves 2x2. Grid (3, 16, 4).
// ---------------------------------------------------------------------------
__global__ __launch_bounds__(256) void kvagg_gemm(const _Float16* __restrict__ vT,
                                                  const _Float16* __restrict__ pkT,
                                                  float* __restrict__ kvp,
                                                  float* __restrict__ zp) {
    __shared__ _Float16 Asb[64 * 32];
    __shared__ _Float16 Bsb[128 * 32];
    int t = threadIdx.x;
    int w = t >> 6, l = t & 63;
    int wr = w >> 1, wc = w & 1;
    int fblk = blockIdx.x;   // 0..2
    int bnl = blockIdx.y;    // 0..15
    int kseg = blockIdx.z;   // 0..3
    const _Float16* Abase = vT + (size_t)bnl * 64 * 2048;
    const _Float16* Bbase = pkT + ((size_t)bnl * FEAT + fblk * 128) * 2048;

    f32x4 acc[2][4];
    #pragma unroll
    for (int m = 0; m < 2; ++m)
        #pragma unroll
        for (int n = 0; n < 4; ++n)
            acc[m][n] = (f32x4){0.f, 0.f, 0.f, 0.f};
    float zacc[4] = {0.f, 0.f, 0.f, 0.f};

    int srow = l >> 2, scol = (l & 3) * 8;
    int rsel = l & 15, csel = (l >> 4) * 8;

    for (int k0 = kseg * 512; k0 < kseg * 512 + 512; k0 += 32) {
        #pragma unroll
        for (int i = 0; i < 3; ++i) {
            int idx = w * 3 + i;
            if (idx < 4) {
                const _Float16* src = Abase + (size_t)(idx * 16 + srow) * 2048 + k0 + scol;
                __builtin_amdgcn_global_load_lds((const AS1 void*)src,
                                                 (AS3 void*)(Asb + idx * 512), 16, 0, 0);
            } else {
                int cB = idx - 4;
                const _Float16* src = Bbase + (size_t)(cB * 16 + srow) * 2048 + k0 + scol;
                __builtin_amdgcn_global_load_lds((const AS1 void*)src,
                                                 (AS3 void*)(Bsb + cB * 512), 16, 0, 0);
            }
        }
        __syncthreads();
        half8 a[2], bfr[4];
        #pragma unroll
        for (int m = 0; m < 2; ++m)
            a[m] = *(const half8*)&Asb[(wr * 32 + m * 16 + rsel) * 32 + csel];
        #pragma unroll
        for (int n = 0; n < 4; ++n)
            bfr[n] = *(const half8*)&Bsb[(wc * 64 + n * 16 + rsel) * 32 + csel];
        if (wr == 0) {
            #pragma unroll
            for (int n = 0; n < 4; ++n)
                #pragma unroll
                for (int e = 0; e < 8; ++e)
                    zacc[n] += (float)bfr[n][e];
        }
        #pragma unroll
        for (int m = 0; m < 2; ++m)
            #pragma unroll
            for (int n = 0; n < 4; ++n)
                acc[m][n] = __builtin_amdgcn_mfma_f32_16x16x32_f16(a[m], bfr[n], acc[m][n], 0, 0, 0);
        __syncthreads();
    }

    #pragma unroll
    for (int n = 0; n < 4; ++n) {
        float v = zacc[n];
        v += __shfl_xor(v, 16, 64);
        v += __shfl_xor(v, 32, 64);
        if (wr == 0 && l < 16)
            zp[(size_t)(kseg * 16 + bnl) * FEAT + fblk * 128 + wc * 64 + n * 16 + l] = v;
    }
    int orow = (l >> 4) * 4, ocol = l & 15;
    float* outp = kvp + (size_t)(kseg * 16 + bnl) * 64 * FEAT;
    #pragma unroll
    for (int m = 0; m < 2; ++m)
        #pragma unroll
        for (int n = 0; n < 4; ++n) {
            int fcol = fblk * 128 + wc * 64 + n * 16 + ocol;
            #pragma unroll
            for (int j = 0; j < 4; ++j)
                outp[(size_t)(wr * 32 + m * 16 + orow + j) * FEAT + fcol] = acc[m][n][j];
        }
}

// ---------------------------------------------------------------------------
// Reduce 4 k-segments -> kvaggT f16 [bn][64][384], z f32 [bn][384] (16 bn group)
// ---------------------------------------------------------------------------
__global__ __launch_bounds__(256) void reduceA(const float* __restrict__ kvp,
                                               const float* __restrict__ zp,
                                               _Float16* __restrict__ kvaggT,
                                               float* __restrict__ z,
                                               int bn0) {
    const int NKV = 16 * 64 * FEAT;  // 393216
    int idx = blockIdx.x * 256 + threadIdx.x;
    if (idx < NKV) {
        float s = 0.f;
        #pragma unroll
        for (int c = 0; c < 4; ++c) s += kvp[(size_t)c * NKV + idx];
        int bnl = idx / (64 * FEAT);
        int rem = idx - bnl * (64 * FEAT);
        kvaggT[(size_t)(bn0 + bnl) * 64 * FEAT + rem] = (_Float16)s;
    } else if (idx < NKV + 16 * FEAT) {
        int e = idx - NKV;
        float s = 0.f;
        #pragma unroll
        for (int c = 0; c < 4; ++c) s += zp[c * 16 * FEAT + e];
        int bnl = e / FEAT;
        z[(size_t)(bn0 + bnl) * FEAT + (e - bnl * FEAT)] = s;
    }
}

// ---------------------------------------------------------------------------
// attn GEMM (all 32 bn): C[i=2048][d=64] = pq[i][f] @ kvaggT[d][f]^T
// fused den = pq.z, divide, f16 out into av. Grid (16, 32), 4 waves 4x1.
// ---------------------------------------------------------------------------
__global__ __launch_bounds__(256) void attn_gemm(const _Float16* __restrict__ pq,
                                                 const _Float16* __restrict__ kvaggT,
                                                 const float* __restrict__ z,
                                                 _Float16* __restrict__ av) {
    __shared__ _Float16 Asb[128 * 32];
    __shared__ _Float16 Bsb[64 * 32];
    __shared__ float z_lds[FEAT];
    __shared__ float den_lds[128];
    int t = threadIdx.x;
    int w = t >> 6, l = t & 63;
    int iblk = blockIdx.x;   // 0..15
    int bn = blockIdx.y;     // 0..31
    int b = bn >> 4, nh = bn & 15;
    const _Float16* Abase = pq + ((size_t)bn * SEQ + iblk * 128) * FEAT;
    const _Float16* Bbase = kvaggT + (size_t)bn * 64 * FEAT;

    for (int e = t; e < FEAT; e += 256) z_lds[e] = z[(size_t)bn * FEAT + e];

    f32x4 acc[2][4];
    #pragma unroll
    for (int m = 0; m < 2; ++m)
        #pragma unroll
        for (int n = 0; n < 4; ++n)
            acc[m][n] = (f32x4){0.f, 0.f, 0.f, 0.f};
    float denacc[2] = {0.f, 0.f};

    int srow = l >> 2, scol = (l & 3) * 8;
    int rsel = l & 15, csel = (l >> 4) * 8;

    for (int k0 = 0; k0 < FEAT; k0 += 32) {
        #pragma unroll
        for (int i = 0; i < 3; ++i) {
            int idx = w * 3 + i;
            if (idx < 8) {
                const _Float16* src = Abase + (size_t)(idx * 16 + srow) * FEAT + k0 + scol;
                __builtin_amdgcn_global_load_lds((const AS1 void*)src,
                                                 (AS3 void*)(Asb + idx * 512), 16, 0, 0);
            } else {
                int cB = idx - 8;
                const _Float16* src = Bbase + (size_t)(cB * 16 + srow) * FEAT + k0 + scol;
                __builtin_amdgcn_global_load_lds((const AS1 void*)src,
                                                 (AS3 void*)(Bsb + cB * 512), 16, 0, 0);
            }
        }
        __syncthreads();
        half8 a[2], bfr[4];
        #pragma unroll
        for (int m = 0; m < 2; ++m)
            a[m] = *(const half8*)&Asb[(w * 32 + m * 16 + rsel) * 32 + csel];
        #pragma unroll
        for (int n = 0; n < 4; ++n)
            bfr[n] = *(const half8*)&Bsb[(n * 16 + rsel) * 32 + csel];
        #pragma unroll
        for (int m = 0; m < 2; ++m)
            #pragma unroll
            for (int e = 0; e < 8; ++e)
                denacc[m] += (float)a[m][e] * z_lds[k0 + csel + e];
        #pragma unroll
        for (int m = 0; m < 2; ++m)
            #pragma unroll
            for (int n = 0; n < 4; ++n)
                acc[m][n] = __builtin_amdgcn_mfma_f32_16x16x32_f16(a[m], bfr[n], acc[m][n], 0, 0, 0);
        __syncthreads();
    }

    #pragma unroll
    for (int m = 0; m < 2; ++m) {
        float v = denacc[m];
        v += __shfl_xor(v, 16, 64);
        v += __shfl_xor(v, 32, 64);
        if (l < 16) den_lds[w * 32 + m * 16 + l] = v;
    }
    __syncthreads();

    int orow = (l >> 4) * 4, ocol = l & 15;
    #pragma unroll
    for (int m = 0; m < 2; ++m)
        #pragma unroll
        for (int n = 0; n < 4; ++n)
            #pragma unroll
            for (int j = 0; j < 4; ++j) {
                int row = w * 32 + m * 16 + orow + j;
                float den = den_lds[row] * SCALE + EPS;
                float val = acc[m][n][j] * SCALE / den;
                int i = iblk * 128 + row;
                av[((size_t)i * 2 + b) * 1024 + nh * 64 + n * 16 + ocol] = (_Float16)val;
            }
}

// ---------------------------------------------------------------------------
// Residual + LayerNorm over last dim (1024). One block per row.
// ---------------------------------------------------------------------------
__global__ __launch_bounds__(256) void ln_kernel(const float* __restrict__ h,
                                                 const float* __restrict__ attn_out,
                                                 const float* __restrict__ gamma,
                                                 const float* __restrict__ beta,
                                                 float* __restrict__ out) {
    int r = blockIdx.x;
    int t = threadIdx.x;
    float xs[4];
    float sum = 0.f, sq = 0.f;
    const float* hp = h + (size_t)r * 1024;
    const float* ap = attn_out + (size_t)r * 1024;
    #pragma unroll
    for (int j = 0; j < 4; ++j) {
        int c = t + 256 * j;
        float x = hp[c] + ap[c];
        xs[j] = x;
        sum += x;
        sq += x * x;
    }
    #pragma unroll
    for (int off = 32; off >= 1; off >>= 1) {
        sum += __shfl_xor(sum, off, 64);
        sq += __shfl_xor(sq, off, 64);
    }
    __shared__ float ssum[4], ssq[4];
    int wl = t >> 6, lane = t & 63;
    if (lane == 0) { ssum[wl] = sum; ssq[wl] = sq; }
    __syncthreads();
    sum = ssum[0] + ssum[1] + ssum[2] + ssum[3];
    sq = ssq[0] + ssq[1] + ssq[2] + ssq[3];
    float mu = sum * (1.f / 1024.f);
    float var = sq * (1.f / 1024.f) - mu * mu;
    float rs = rsqrtf(var + 1e-5f);
    float* op = out + (size_t)r * 1024;
    #pragma unroll
    for (int j = 0; j < 4; ++j) {
        int c = t + 256 * j;
        op[c] = (xs[j] - mu) * rs * gamma[c] + beta[c];
    }
}

// ---------------------------------------------------------------------------
extern "C" void kernel_launch(void* const* d_in, const int* in_sizes, int n_in,
                              void* d_out, int out_size, void* d_ws, size_t ws_size,
                              hipStream_t stream) {
    const float* h     = (const float*)d_in[0];
    const float* Wq    = (const float*)d_in[1];
    const float* Wkv   = (const float*)d_in[2];
    const float* Wo    = (const float*)d_in[3];
    const float* gamma = (const float*)d_in[4];
    const float* beta  = (const float*)d_in[5];
    float* out = (float*)d_out;
    _Float16* u = (_Float16*)d_ws;

    // Workspace layout (2-byte units), total ~94 MB:
    _Float16* h_h    = u;                       // 4,194,304 u (8 MB); later kvp(f32) / av(f16)
    _Float16* WqkvT  = u + 4194304;             // 3,145,728 u (6 MB)
    _Float16* WoT    = u + 7340032;             // 1,048,576 u (2 MB)
    _Float16* qkv    = u + 8388608;             // 12,582,912 u (24 MB); later attn_out f32 (16 MB)
    _Float16* region = u + 20971520;            // 25,165,824 u (50.3 MB): pkT+vT, later pq
    _Float16* kvaggT = u + 46137344;            // 786,432 u (1.5 MB)
    float*    z      = (float*)(u + 46923776);  // 12,288 f
    float*    zp     = (float*)(u + 46948352);  // 24,576 f
    // aliases
    _Float16* pkT_g  = region;                  // 12,582,912 u (16 bn)
    _Float16* vT_g   = region + 12582912;       // 2,097,152 u
    _Float16* pq     = region;                  // 25,165,824 u (all 32 bn)
    float*    kvp    = (float*)h_h;             // 1,572,864 f (6.3 MB)
    _Float16* av     = h_h;                     // 8 MB (after kvp dead)
    float*    attn_out = (float*)qkv;           // 16 MB (after featq)

    dim3 blk(256);
    // 0) conversions
    conv_h16<<<dim3(4096), blk, 0, stream>>>(h, h_h, 1048576);
    transpose_h16<<<dim3(96, 32), blk, 0, stream>>>(Wq, Wkv, WqkvT);
    transpose_h16<<<dim3(32, 32), blk, 0, stream>>>(Wo, Wo, WoT);
    // 1) fused qkv projection: [4096,3072] f16
    gemm_f16<true><<<dim3(24, 32), blk, 0, stream>>>(h_h, WqkvT, qkv, SB, 3072, DM);
    // 2) kv_agg + z in 2 groups of 16 (b,n)
    for (int g = 0; g < 2; ++g) {
        featk_kernel<<<dim3(16, 64), blk, 0, stream>>>(qkv, pkT_g, vT_g, g * 16);
        kvagg_gemm<<<dim3(3, 16, 4), blk, 0, stream>>>(vT_g, pkT_g, kvp, zp);
        reduceA<<<dim3(1560), blk, 0, stream>>>(kvp, zp, kvaggT, z, g * 16);
    }
    // 3) attn_vec: all 32 bn
    featq_kernel<<<dim3(32, 64), blk, 0, stream>>>(qkv, pq);
    attn_gemm<<<dim3(16, 32), blk, 0, stream>>>(pq, kvaggT, z, av);
    // 4) output projection + LN
    gemm_f16<false><<<dim3(8, 32), blk, 0, stream>>>(av, WoT, attn_out, SB, 1024, DM);
    ln_kernel<<<dim3(SB), blk, 0, stream>>>(h, attn_out, gamma, beta, out);
}

// Round 5
// 159.260 us; speedup vs baseline: 6.5746x; 1.1586x over previous
//
#include <hip/hip_runtime.h>
#include <math.h>

// Problem constants
#define NH 16
#define DM 1024
#define FEAT 384          // 2*64*3
#define SB 4096           // S*B
#define SEQ 2048

static constexpr float SCALE = 0.125f;  // 1/sqrt(64)
static constexpr float EPS = 1e-5f;

typedef __attribute__((ext_vector_type(8))) _Float16 half8;
typedef __attribute__((ext_vector_type(4))) _Float16 half4;
typedef __attribute__((ext_vector_type(4))) float f32x4;

#define AS1 __attribute__((address_space(1)))
#define AS3 __attribute__((address_space(3)))

// ---------------------------------------------------------------------------
// f32 -> f16 straight conversion (float4 in, half4 out)
// ---------------------------------------------------------------------------
__global__ __launch_bounds__(256) void conv_h16(const float* __restrict__ src,
                                                _Float16* __restrict__ dst,
                                                int n4) {
    int i = blockIdx.x * 256 + threadIdx.x;
    if (i >= n4) return;
    const float4 v = ((const float4*)src)[i];
    half4 o = {(_Float16)v.x, (_Float16)v.y, (_Float16)v.z, (_Float16)v.w};
    ((half4*)dst)[i] = o;
}

// ---------------------------------------------------------------------------
// Transpose-convert into dst f16 [Ntot][1024].
// Row n of dst: n<1024 -> srcA col n; else srcB col n-1024.
// ---------------------------------------------------------------------------
__global__ __launch_bounds__(256) void transpose_h16(const float* __restrict__ srcA,
                                                     const float* __restrict__ srcB,
                                                     _Float16* __restrict__ dst) {
    __shared__ _Float16 tile[32][33];
    int n0 = blockIdx.x * 32, k0 = blockIdx.y * 32;
    const float* src;
    int N, col0;
    if (n0 < 1024) { src = srcA; N = 1024; col0 = n0; }
    else           { src = srcB; N = 2048; col0 = n0 - 1024; }
    int tx = threadIdx.x & 31, ty = threadIdx.x >> 5;
    #pragma unroll
    for (int i = 0; i < 4; ++i) {
        int k = k0 + ty + i * 8;
        tile[ty + i * 8][tx] = (_Float16)src[(size_t)k * N + col0 + tx];
    }
    __syncthreads();
    #pragma unroll
    for (int i = 0; i < 4; ++i) {
        int n = n0 + ty + i * 8;
        dst[(size_t)n * 1024 + k0 + tx] = tile[tx][ty + i * 8];
    }
}

// ---------------------------------------------------------------------------
// f16 MFMA GEMM: C[M,N] = A_f16[M,K] @ (BT_f16[N,K])^T
// 128x128 tile, 4 waves 2x2, BK=32, m97 structure. OUT_HALF: f16 vs f32 C.
// ---------------------------------------------------------------------------
template <bool OUT_HALF>
__global__ __launch_bounds__(256) void gemm_f16(const _Float16* __restrict__ A,
                                                const _Float16* __restrict__ BT,
                                                void* __restrict__ Cv,
                                                int M, int N, int K) {
    __shared__ _Float16 Asb[128 * 32];
    __shared__ _Float16 Bsb[128 * 32];
    int t = threadIdx.x;
    int w = t >> 6, l = t & 63;
    int wr = w >> 1, wc = w & 1;
    int row0 = blockIdx.y * 128, col0 = blockIdx.x * 128;

    f32x4 acc[4][4];
    #pragma unroll
    for (int m = 0; m < 4; ++m)
        #pragma unroll
        for (int n = 0; n < 4; ++n)
            acc[m][n] = (f32x4){0.f, 0.f, 0.f, 0.f};

    int srow = l >> 2;
    int scol = (l & 3) * 8;

    for (int k0 = 0; k0 < K; k0 += 32) {
        #pragma unroll
        for (int i = 0; i < 2; ++i) {
            int chunk = w * 2 + i;
            const _Float16* asrc =
                A + (size_t)(row0 + chunk * 16 + srow) * K + k0 + scol;
            __builtin_amdgcn_global_load_lds((const AS1 void*)asrc,
                                             (AS3 void*)(Asb + chunk * 512), 16, 0, 0);
            const _Float16* bsrc =
                BT + (size_t)(col0 + chunk * 16 + srow) * K + k0 + scol;
            __builtin_amdgcn_global_load_lds((const AS1 void*)bsrc,
                                             (AS3 void*)(Bsb + chunk * 512), 16, 0, 0);
        }
        __syncthreads();
        int rsel = l & 15, csel = (l >> 4) * 8;
        half8 a[4], b[4];
        #pragma unroll
        for (int m = 0; m < 4; ++m)
            a[m] = *(const half8*)&Asb[(wr * 64 + m * 16 + rsel) * 32 + csel];
        #pragma unroll
        for (int n = 0; n < 4; ++n)
            b[n] = *(const half8*)&Bsb[(wc * 64 + n * 16 + rsel) * 32 + csel];
        #pragma unroll
        for (int m = 0; m < 4; ++m)
            #pragma unroll
            for (int n = 0; n < 4; ++n)
                acc[m][n] = __builtin_amdgcn_mfma_f32_16x16x32_f16(a[m], b[n], acc[m][n], 0, 0, 0);
        __syncthreads();
    }

    int ocol = l & 15, orow = (l >> 4) * 4;
    #pragma unroll
    for (int m = 0; m < 4; ++m)
        #pragma unroll
        for (int n = 0; n < 4; ++n) {
            size_t base = (size_t)(row0 + wr * 64 + m * 16 + orow) * N
                        + col0 + wc * 64 + n * 16 + ocol;
            #pragma unroll
            for (int j = 0; j < 4; ++j) {
                if constexpr (OUT_HALF)
                    ((_Float16*)Cv)[base + (size_t)j * N] = (_Float16)acc[m][n][j];
                else
                    ((float*)Cv)[base + (size_t)j * N] = acc[m][n][j];
            }
        }
}

// ---------------------------------------------------------------------------
// featk: from qkv f16, produce pkT f16 [bnl][384][2048], vT f16 [bnl][64][2048]
// for 16 (b,n) per group. Grid: (16, 64 j-tiles of 32), 256 threads.
// ---------------------------------------------------------------------------
__global__ __launch_bounds__(256) void featk_kernel(const _Float16* __restrict__ qkv,
                                                    _Float16* __restrict__ pkT,
                                                    _Float16* __restrict__ vT,
                                                    int bn0) {
    __shared__ float x2[128][33];
    __shared__ _Float16 vls[64][40];
    int t = threadIdx.x;
    int bnl = blockIdx.x;
    int bn = bn0 + bnl;
    int b = bn >> 4, nh = bn & 15;
    int j0 = blockIdx.y * 32;
    int c = t & 63;
    #pragma unroll
    for (int ii = 0; ii < 8; ++ii) {
        int jl = ii * 4 + (t >> 6);
        const _Float16* row = qkv + (size_t)((j0 + jl) * 2 + b) * 3072 + nh * 64;
        float kd = (float)row[1024 + c];
        vls[c][jl] = row[2048 + c];
        x2[c][jl] = fmaxf(kd, 0.f);
        x2[c + 64][jl] = fmaxf(-kd, 0.f);
    }
    __syncthreads();
    {
        int d = t >> 2, jj0 = (t & 3) * 8;
        half8 o;
        #pragma unroll
        for (int e = 0; e < 8; ++e) o[e] = vls[d][jj0 + e];
        *(half8*)&vT[((size_t)bnl * 64 + d) * 2048 + j0 + jj0] = o;
    }
    int fr = t >> 2, jj0 = (t & 3) * 8;
    #pragma unroll
    for (int fb = 0; fb < 6; ++fb) {
        int f = fb * 64 + fr;
        int fm = f & 127;
        int r = (f >> 7) + 1;
        int fm2 = (fm - r) & 127;
        half8 o;
        #pragma unroll
        for (int e = 0; e < 8; ++e)
            o[e] = (_Float16)(x2[fm][jj0 + e] * x2[fm2][jj0 + e]);
        *(half8*)&pkT[((size_t)bnl * FEAT + f) * 2048 + j0 + jj0] = o;
    }
}

// ---------------------------------------------------------------------------
// kvagg GEMM (16 bn per group, K-split 4): per (fblk, bnl, kseg):
//   kvp[kseg][bnl][64][384-slice] = vT @ pkT^T over 512 j
//   zp[kseg][bnl][f] = sum_j pk[f][j]   (wr==0 waves)
// Block: BM=64(d) x BN=128(f), 4 waves 2x2. Grid (3, 16, 4).
// ---------------------------------------------------------------------------
__global__ __launch_bounds__(256) void kvagg_gemm(const _Float16* __restrict__ vT,
                                                  const _Float16* __restrict__ pkT,
                                                  float* __restrict__ kvp,
                                                  float* __restrict__ zp) {
    __shared__ _Float16 Asb[64 * 32];
    __shared__ _Float16 Bsb[128 * 32];
    int t = threadIdx.x;
    int w = t >> 6, l = t & 63;
    int wr = w >> 1, wc = w & 1;
    int fblk = blockIdx.x;   // 0..2
    int bnl = blockIdx.y;    // 0..15
    int kseg = blockIdx.z;   // 0..3
    const _Float16* Abase = vT + (size_t)bnl * 64 * 2048;
    const _Float16* Bbase = pkT + ((size_t)bnl * FEAT + fblk * 128) * 2048;

    f32x4 acc[2][4];
    #pragma unroll
    for (int m = 0; m < 2; ++m)
        #pragma unroll
        for (int n = 0; n < 4; ++n)
            acc[m][n] = (f32x4){0.f, 0.f, 0.f, 0.f};
    float zacc[4] = {0.f, 0.f, 0.f, 0.f};

    int srow = l >> 2, scol = (l & 3) * 8;
    int rsel = l & 15, csel = (l >> 4) * 8;

    for (int k0 = kseg * 512; k0 < kseg * 512 + 512; k0 += 32) {
        #pragma unroll
        for (int i = 0; i < 3; ++i) {
            int idx = w * 3 + i;
            if (idx < 4) {
                const _Float16* src = Abase + (size_t)(idx * 16 + srow) * 2048 + k0 + scol;
                __builtin_amdgcn_global_load_lds((const AS1 void*)src,
                                                 (AS3 void*)(Asb + idx * 512), 16, 0, 0);
            } else {
                int cB = idx - 4;
                const _Float16* src = Bbase + (size_t)(cB * 16 + srow) * 2048 + k0 + scol;
                __builtin_amdgcn_global_load_lds((const AS1 void*)src,
                                                 (AS3 void*)(Bsb + cB * 512), 16, 0, 0);
            }
        }
        __syncthreads();
        half8 a[2], bfr[4];
        #pragma unroll
        for (int m = 0; m < 2; ++m)
            a[m] = *(const half8*)&Asb[(wr * 32 + m * 16 + rsel) * 32 + csel];
        #pragma unroll
        for (int n = 0; n < 4; ++n)
            bfr[n] = *(const half8*)&Bsb[(wc * 64 + n * 16 + rsel) * 32 + csel];
        if (wr == 0) {
            #pragma unroll
            for (int n = 0; n < 4; ++n)
                #pragma unroll
                for (int e = 0; e < 8; ++e)
                    zacc[n] += (float)bfr[n][e];
        }
        #pragma unroll
        for (int m = 0; m < 2; ++m)
            #pragma unroll
            for (int n = 0; n < 4; ++n)
                acc[m][n] = __builtin_amdgcn_mfma_f32_16x16x32_f16(a[m], bfr[n], acc[m][n], 0, 0, 0);
        __syncthreads();
    }

    #pragma unroll
    for (int n = 0; n < 4; ++n) {
        float v = zacc[n];
        v += __shfl_xor(v, 16, 64);
        v += __shfl_xor(v, 32, 64);
        if (wr == 0 && l < 16)
            zp[(size_t)(kseg * 16 + bnl) * FEAT + fblk * 128 + wc * 64 + n * 16 + l] = v;
    }
    int orow = (l >> 4) * 4, ocol = l & 15;
    float* outp = kvp + (size_t)(kseg * 16 + bnl) * 64 * FEAT;
    #pragma unroll
    for (int m = 0; m < 2; ++m)
        #pragma unroll
        for (int n = 0; n < 4; ++n) {
            int fcol = fblk * 128 + wc * 64 + n * 16 + ocol;
            #pragma unroll
            for (int j = 0; j < 4; ++j)
                outp[(size_t)(wr * 32 + m * 16 + orow + j) * FEAT + fcol] = acc[m][n][j];
        }
}

// ---------------------------------------------------------------------------
// Reduce 4 k-segments -> kvaggT f16 [bn][64][384], z f32 [bn][384] (16 bn group)
// ---------------------------------------------------------------------------
__global__ __launch_bounds__(256) void reduceA(const float* __restrict__ kvp,
                                               const float* __restrict__ zp,
                                               _Float16* __restrict__ kvaggT,
                                               float* __restrict__ z,
                                               int bn0) {
    const int NKV = 16 * 64 * FEAT;  // 393216
    int idx = blockIdx.x * 256 + threadIdx.x;
    if (idx < NKV) {
        float s = 0.f;
        #pragma unroll
        for (int c = 0; c < 4; ++c) s += kvp[(size_t)c * NKV + idx];
        int bnl = idx / (64 * FEAT);
        int rem = idx - bnl * (64 * FEAT);
        kvaggT[(size_t)(bn0 + bnl) * 64 * FEAT + rem] = (_Float16)s;
    } else if (idx < NKV + 16 * FEAT) {
        int e = idx - NKV;
        float s = 0.f;
        #pragma unroll
        for (int c = 0; c < 4; ++c) s += zp[c * 16 * FEAT + e];
        int bnl = e / FEAT;
        z[(size_t)(bn0 + bnl) * FEAT + (e - bnl * FEAT)] = s;
    }
}

// ---------------------------------------------------------------------------
// pq compute helper: static-index feature map for one 192-wide f-half.
// Fully unrolled so qr[] indices are compile-time (no scratch spill).
// ---------------------------------------------------------------------------
template <int F0>
__device__ __forceinline__ void pq_half(const float (&qr)[64], _Float16* prow) {
    #pragma unroll
    for (int g8 = 0; g8 < 24; ++g8) {
        half8 o;
        #pragma unroll
        for (int e = 0; e < 8; ++e) {
            const int f = F0 + g8 * 8 + e;
            const int fm = f & 127;
            const int r = (f >> 7) + 1;
            const int fm2 = (fm - r) & 127;
            float a = (fm < 64) ? fmaxf(qr[fm], 0.f) : fmaxf(-qr[fm - 64], 0.f);
            float bb = (fm2 < 64) ? fmaxf(qr[fm2], 0.f) : fmaxf(-qr[fm2 - 64], 0.f);
            o[e] = (_Float16)(a * bb);
        }
        *(half8*)&prow[F0 + g8 * 8] = o;
    }
}

// ---------------------------------------------------------------------------
// Fused attn: per block (iblk 128 rows, one bn):
//   pq (128x384) computed from qkv q-part into padded LDS,
//   B = kvaggT[bn] (64x384) staged into padded LDS,
//   then barrier-free 12-step MFMA K-loop; fused den = pq.z; f16 out to av.
// Grid (16, 32), 256 threads (4 waves, 4x1 over rows).
// ---------------------------------------------------------------------------
#define PQ_STR 392   // 384 + 8 pad (16B-aligned rows, 2-way-free bank pattern)
__global__ __launch_bounds__(256) void attn_fused(const _Float16* __restrict__ qkv,
                                                  const _Float16* __restrict__ kvaggT,
                                                  const float* __restrict__ z,
                                                  _Float16* __restrict__ av) {
    __shared__ _Float16 pq_lds[128 * PQ_STR];   // 100,352 B
    __shared__ _Float16 B_lds[64 * PQ_STR];     //  50,176 B
    __shared__ float z_lds[FEAT];
    __shared__ float den_lds[128];
    int t = threadIdx.x;
    int w = t >> 6, l = t & 63;
    int iblk = blockIdx.x;   // 0..15
    int bn = blockIdx.y;     // 0..31
    int b = bn >> 4, nh = bn & 15;

    // stage B (64x384) into padded LDS via regs
    {
        const _Float16* Bg = kvaggT + (size_t)bn * 64 * FEAT;
        #pragma unroll
        for (int s = 0; s < 12; ++s) {
            int idx8 = t + 256 * s;          // 0..3071
            half8 vv = *(const half8*)&Bg[idx8 * 8];
            int row = idx8 / 48, col8 = idx8 - row * 48;
            *(half8*)&B_lds[row * PQ_STR + col8 * 8] = vv;
        }
    }
    for (int e = t; e < FEAT; e += 256) z_lds[e] = z[(size_t)bn * FEAT + e];

    // load q row into regs, compute pq into LDS (wave-uniform f-half split)
    {
        int il = t & 127;
        int ig = iblk * 128 + il;
        const _Float16* qrow = qkv + ((size_t)ig * 2 + b) * 3072 + nh * 64;
        float qr[64];
        #pragma unroll
        for (int e2 = 0; e2 < 8; ++e2) {
            half8 vv = *(const half8*)&qrow[e2 * 8];
            #pragma unroll
            for (int e = 0; e < 8; ++e) qr[e2 * 8 + e] = (float)vv[e];
        }
        _Float16* prow = &pq_lds[il * PQ_STR];
        if (t < 128) pq_half<0>(qr, prow);
        else         pq_half<192>(qr, prow);
    }
    __syncthreads();

    f32x4 acc[2][4];
    #pragma unroll
    for (int m = 0; m < 2; ++m)
        #pragma unroll
        for (int n = 0; n < 4; ++n)
            acc[m][n] = (f32x4){0.f, 0.f, 0.f, 0.f};
    float denacc[2] = {0.f, 0.f};
    int rsel = l & 15, csel = (l >> 4) * 8;

    #pragma unroll
    for (int k0 = 0; k0 < FEAT; k0 += 32) {
        half8 a[2], bfr[4];
        #pragma unroll
        for (int m = 0; m < 2; ++m)
            a[m] = *(const half8*)&pq_lds[(w * 32 + m * 16 + rsel) * PQ_STR + k0 + csel];
        #pragma unroll
        for (int n = 0; n < 4; ++n)
            bfr[n] = *(const half8*)&B_lds[(n * 16 + rsel) * PQ_STR + k0 + csel];
        #pragma unroll
        for (int m = 0; m < 2; ++m)
            #pragma unroll
            for (int e = 0; e < 8; ++e)
                denacc[m] += (float)a[m][e] * z_lds[k0 + csel + e];
        #pragma unroll
        for (int m = 0; m < 2; ++m)
            #pragma unroll
            for (int n = 0; n < 4; ++n)
                acc[m][n] = __builtin_amdgcn_mfma_f32_16x16x32_f16(a[m], bfr[n], acc[m][n], 0, 0, 0);
    }

    #pragma unroll
    for (int m = 0; m < 2; ++m) {
        float v = denacc[m];
        v += __shfl_xor(v, 16, 64);
        v += __shfl_xor(v, 32, 64);
        if (l < 16) den_lds[w * 32 + m * 16 + l] = v;
    }
    __syncthreads();

    int orow = (l >> 4) * 4, ocol = l & 15;
    #pragma unroll
    for (int m = 0; m < 2; ++m)
        #pragma unroll
        for (int n = 0; n < 4; ++n)
            #pragma unroll
            for (int j = 0; j < 4; ++j) {
                int row = w * 32 + m * 16 + orow + j;
                float den = den_lds[row] * SCALE + EPS;
                float val = acc[m][n][j] * SCALE / den;
                int i = iblk * 128 + row;
                av[((size_t)i * 2 + b) * 1024 + nh * 64 + n * 16 + ocol] = (_Float16)val;
            }
}

// ---------------------------------------------------------------------------
// Residual + LayerNorm over last dim (1024). One block per row. attn_out f16.
// ---------------------------------------------------------------------------
__global__ __launch_bounds__(256) void ln_kernel(const float* __restrict__ h,
                                                 const _Float16* __restrict__ attn_out,
                                                 const float* __restrict__ gamma,
                                                 const float* __restrict__ beta,
                                                 float* __restrict__ out) {
    int r = blockIdx.x;
    int t = threadIdx.x;
    float xs[4];
    float sum = 0.f, sq = 0.f;
    const float* hp = h + (size_t)r * 1024;
    const _Float16* ap = attn_out + (size_t)r * 1024;
    #pragma unroll
    for (int j = 0; j < 4; ++j) {
        int c = t + 256 * j;
        float x = hp[c] + (float)ap[c];
        xs[j] = x;
        sum += x;
        sq += x * x;
    }
    #pragma unroll
    for (int off = 32; off >= 1; off >>= 1) {
        sum += __shfl_xor(sum, off, 64);
        sq += __shfl_xor(sq, off, 64);
    }
    __shared__ float ssum[4], ssq[4];
    int wl = t >> 6, lane = t & 63;
    if (lane == 0) { ssum[wl] = sum; ssq[wl] = sq; }
    __syncthreads();
    sum = ssum[0] + ssum[1] + ssum[2] + ssum[3];
    sq = ssq[0] + ssq[1] + ssq[2] + ssq[3];
    float mu = sum * (1.f / 1024.f);
    float var = sq * (1.f / 1024.f) - mu * mu;
    float rs = rsqrtf(var + 1e-5f);
    float* op = out + (size_t)r * 1024;
    #pragma unroll
    for (int j = 0; j < 4; ++j) {
        int c = t + 256 * j;
        op[c] = (xs[j] - mu) * rs * gamma[c] + beta[c];
    }
}

// ---------------------------------------------------------------------------
extern "C" void kernel_launch(void* const* d_in, const int* in_sizes, int n_in,
                              void* d_out, int out_size, void* d_ws, size_t ws_size,
                              hipStream_t stream) {
    const float* h     = (const float*)d_in[0];
    const float* Wq    = (const float*)d_in[1];
    const float* Wkv   = (const float*)d_in[2];
    const float* Wo    = (const float*)d_in[3];
    const float* gamma = (const float*)d_in[4];
    const float* beta  = (const float*)d_in[5];
    float* out = (float*)d_out;
    _Float16* u = (_Float16*)d_ws;

    // Workspace layout (2-byte units), total ~73 MB:
    _Float16* h_h    = u;                       // 4,194,304 u (8 MB); later kvp(f32 6.3MB) then av(f16 8MB)
    _Float16* WqkvT  = u + 4194304;             // 3,145,728 u (6 MB)
    _Float16* WoT    = u + 7340032;             // 1,048,576 u (2 MB)
    _Float16* qkv    = u + 8388608;             // 12,582,912 u (24 MB); later attn_out f16 (8 MB)
    _Float16* pkT_g  = u + 20971520;            // 12,582,912 u (25.2 MB)
    _Float16* vT_g   = u + 33554432;            // 2,097,152 u (4.2 MB)
    _Float16* kvaggT = u + 35651584;            // 786,432 u (1.5 MB)
    float*    z      = (float*)(u + 36438016);  // 12,288 f
    float*    zp     = (float*)(u + 36462592);  // 24,576 f
    // aliases
    float*    kvp        = (float*)h_h;         // 1,572,864 f (6.3 MB), during kvagg
    _Float16* av         = h_h;                 // after kvp dead
    _Float16* attn_out_h = qkv;                 // after attn_fused

    dim3 blk(256);
    // 0) conversions
    conv_h16<<<dim3(4096), blk, 0, stream>>>(h, h_h, 1048576);
    transpose_h16<<<dim3(96, 32), blk, 0, stream>>>(Wq, Wkv, WqkvT);
    transpose_h16<<<dim3(32, 32), blk, 0, stream>>>(Wo, Wo, WoT);
    // 1) fused qkv projection: [4096,3072] f16
    gemm_f16<true><<<dim3(24, 32), blk, 0, stream>>>(h_h, WqkvT, qkv, SB, 3072, DM);
    // 2) kv_agg + z in 2 groups of 16 (b,n)
    for (int g = 0; g < 2; ++g) {
        featk_kernel<<<dim3(16, 64), blk, 0, stream>>>(qkv, pkT_g, vT_g, g * 16);
        kvagg_gemm<<<dim3(3, 16, 4), blk, 0, stream>>>(vT_g, pkT_g, kvp, zp);
        reduceA<<<dim3(1560), blk, 0, stream>>>(kvp, zp, kvaggT, z, g * 16);
    }
    // 3) fused featq + attn GEMM (all 32 bn)
    attn_fused<<<dim3(16, 32), blk, 0, stream>>>(qkv, kvaggT, z, av);
    // 4) output projection (f16 out) + LN
    gemm_f16<true><<<dim3(8, 32), blk, 0, stream>>>(av, WoT, attn_out_h, SB, 1024, DM);
    ln_kernel<<<dim3(SB), blk, 0, stream>>>(h, attn_out_h, gamma, beta, out);
}

// Round 6
// 154.362 us; speedup vs baseline: 6.7832x; 1.0317x over previous
//
#include <hip/hip_runtime.h>
#include <math.h>

// Problem constants
#define NH 16
#define DM 1024
#define FEAT 384          // 2*64*3
#define SB 4096           // S*B
#define SEQ 2048

static constexpr float SCALE = 0.125f;  // 1/sqrt(64)
static constexpr float EPS = 1e-5f;

typedef __attribute__((ext_vector_type(8))) _Float16 half8;
typedef __attribute__((ext_vector_type(4))) _Float16 half4;
typedef __attribute__((ext_vector_type(4))) float f32x4;

#define AS1 __attribute__((address_space(1)))
#define AS3 __attribute__((address_space(3)))

// ---------------------------------------------------------------------------
// f32 -> f16 straight conversion (float4 in, half4 out)
// ---------------------------------------------------------------------------
__global__ __launch_bounds__(256) void conv_h16(const float* __restrict__ src,
                                                _Float16* __restrict__ dst,
                                                int n4) {
    int i = blockIdx.x * 256 + threadIdx.x;
    if (i >= n4) return;
    const float4 v = ((const float4*)src)[i];
    half4 o = {(_Float16)v.x, (_Float16)v.y, (_Float16)v.z, (_Float16)v.w};
    ((half4*)dst)[i] = o;
}

// ---------------------------------------------------------------------------
// Transpose-convert into dst f16 [Ntot][1024].
// ---------------------------------------------------------------------------
__global__ __launch_bounds__(256) void transpose_h16(const float* __restrict__ srcA,
                                                     const float* __restrict__ srcB,
                                                     _Float16* __restrict__ dst) {
    __shared__ _Float16 tile[32][33];
    int n0 = blockIdx.x * 32, k0 = blockIdx.y * 32;
    const float* src;
    int N, col0;
    if (n0 < 1024) { src = srcA; N = 1024; col0 = n0; }
    else           { src = srcB; N = 2048; col0 = n0 - 1024; }
    int tx = threadIdx.x & 31, ty = threadIdx.x >> 5;
    #pragma unroll
    for (int i = 0; i < 4; ++i) {
        int k = k0 + ty + i * 8;
        tile[ty + i * 8][tx] = (_Float16)src[(size_t)k * N + col0 + tx];
    }
    __syncthreads();
    #pragma unroll
    for (int i = 0; i < 4; ++i) {
        int n = n0 + ty + i * 8;
        dst[(size_t)n * 1024 + k0 + tx] = tile[tx][ty + i * 8];
    }
}

// ---------------------------------------------------------------------------
// 256x256 8-phase f16 MFMA GEMM (T1+T2+T3+T4+T5), C f16.
// 512 threads = 8 waves (2 M x 4 N), BK=64, double-buffered 128 KiB LDS.
// LDS swizzle: LDS(row, c16) holds global(row, c16 ^ (row&7)); reads apply
// the same XOR. Staged with inverse-swizzled global source (linear LDS dest).
// Requires: M%256==0, N%256==0, K%64==0, K/64 >= 3, grid = (M/256)*(N/256), %8==0.
// ---------------------------------------------------------------------------
template <int MH, int NB>
__device__ __forceinline__ void mfma_quad(f32x4 (&acc)[8][4], half8 (&a)[4][2],
                                          half8 (&bv)[4][2]) {
    #pragma unroll
    for (int mf = 0; mf < 4; ++mf)
        #pragma unroll
        for (int nf = 0; nf < 2; ++nf)
            #pragma unroll
            for (int ks = 0; ks < 2; ++ks)
                acc[MH * 4 + mf][NB * 2 + nf] = __builtin_amdgcn_mfma_f32_16x16x32_f16(
                    a[mf][ks], bv[NB * 2 + nf][ks], acc[MH * 4 + mf][NB * 2 + nf], 0, 0, 0);
}

__global__ __launch_bounds__(512) void gemm_f16_8ph(const _Float16* __restrict__ A,
                                                    const _Float16* __restrict__ BT,
                                                    _Float16* __restrict__ C,
                                                    int M, int N, int K) {
    __shared__ _Float16 smem[65536];   // 2 buf x (A 256x64 + B 256x64) = 128 KiB
    const int t = threadIdx.x;
    const int w = t >> 6, l = t & 63;
    const int wr = w >> 2, wc = w & 3;
    const int NT = K >> 6;          // K-tiles
    const int NHT = K >> 4;         // half-tiles total = 4*NT

    // XCD-aware bijective swizzle (gridDim.x % 8 == 0)
    int nwg = gridDim.x;
    int cpx = nwg >> 3;
    int bid = blockIdx.x;
    int swz = (bid & 7) * cpx + (bid >> 3);
    int ntile = N >> 8;
    int row0 = (swz / ntile) << 8;
    int col0 = (swz % ntile) << 8;

    f32x4 acc[8][4];
    #pragma unroll
    for (int m = 0; m < 8; ++m)
        #pragma unroll
        for (int n = 0; n < 4; ++n)
            acc[m][n] = (f32x4){0.f, 0.f, 0.f, 0.f};

    const int lr = l >> 3;                 // source row within 8-row chunk
    const int lc8 = ((l & 7) ^ lr) * 8;    // inverse-swizzled source col (halfs)

    // stage half-tile s of global sequence; in-tile order [Bh0,Bh1,Ah0,Ah1]
    auto STAGE = [&](int s) {
        if (s >= NHT) return;
        int tau = s >> 2, hh = s & 3;
        int kk = tau << 6;
        int hf = hh & 1;
        int ldsbase = ((tau & 1) << 15) + ((hh >= 2) ? 0 : 16384) + (hf << 13)
                    + ((w * 2) << 9);
        const _Float16* gbase = (hh >= 2)
            ? A + (size_t)(row0 + hf * 128) * K
            : BT + (size_t)(col0 + hf * 128) * K;
        #pragma unroll
        for (int i = 0; i < 2; ++i) {
            const _Float16* src = gbase + (size_t)((w * 2 + i) * 8 + lr) * K + kk + lc8;
            __builtin_amdgcn_global_load_lds((const AS1 void*)src,
                                             (AS3 void*)(smem + ldsbase + (i << 9)), 16, 0, 0);
        }
    };

    half8 a[4][2], bv[4][2];
    auto LDA = [&](int mh, int bufb) {
        #pragma unroll
        for (int mf = 0; mf < 4; ++mf) {
            int r = wr * 128 + (mh * 4 + mf) * 16 + (l & 15);
            #pragma unroll
            for (int ks = 0; ks < 2; ++ks) {
                int c16 = (ks * 4 + (l >> 4)) ^ (r & 7);
                a[mf][ks] = *(const half8*)&smem[bufb + r * 64 + c16 * 8];
            }
        }
    };
    auto LDB = [&](int bufb) {
        #pragma unroll
        for (int nf = 0; nf < 4; ++nf) {
            int r = wc * 64 + nf * 16 + (l & 15);
            #pragma unroll
            for (int ks = 0; ks < 2; ++ks) {
                int c16 = (ks * 4 + (l >> 4)) ^ (r & 7);
                bv[nf][ks] = *(const half8*)&smem[bufb + 16384 + r * 64 + c16 * 8];
            }
        }
    };

    // Prologue: tile0 fully (s=0..3) + 3 half-tiles of tile1 (s=4..6)
    #pragma unroll 1
    for (int s = 0; s < 7; ++s) STAGE(s);
    asm volatile("s_waitcnt vmcnt(6)" ::: "memory");
    __builtin_amdgcn_s_barrier();

    #pragma unroll 1
    for (int ti = 0; ti < NT; ++ti) {
        const int bufb = (ti & 1) << 15;
        const int sb = 7 + (ti << 2);
        // ---- phase 0: reads a[m0] + all b; stage t+1:Ah1; MFMA (m0, n01)
        LDA(0, bufb); LDB(bufb);
        STAGE(sb);
        __builtin_amdgcn_sched_barrier(0);
        __builtin_amdgcn_s_barrier();
        asm volatile("s_waitcnt lgkmcnt(0)" ::: "memory");
        __builtin_amdgcn_sched_barrier(0);
        __builtin_amdgcn_s_setprio(1);
        mfma_quad<0, 0>(acc, a, bv);
        __builtin_amdgcn_s_setprio(0);
        __builtin_amdgcn_sched_barrier(0);
        __builtin_amdgcn_s_barrier();
        // ---- phase 1: stage t+2:Bh0; MFMA (m0, n23)
        STAGE(sb + 1);
        __builtin_amdgcn_sched_barrier(0);
        __builtin_amdgcn_s_barrier();
        __builtin_amdgcn_s_setprio(1);
        mfma_quad<0, 1>(acc, a, bv);
        __builtin_amdgcn_s_setprio(0);
        __builtin_amdgcn_sched_barrier(0);
        __builtin_amdgcn_s_barrier();
        // ---- phase 2: reads a[m1]; stage t+2:Bh1; MFMA (m1, n01)
        LDA(1, bufb);
        STAGE(sb + 2);
        __builtin_amdgcn_sched_barrier(0);
        __builtin_amdgcn_s_barrier();
        asm volatile("s_waitcnt lgkmcnt(0)" ::: "memory");
        __builtin_amdgcn_sched_barrier(0);
        __builtin_amdgcn_s_setprio(1);
        mfma_quad<1, 0>(acc, a, bv);
        __builtin_amdgcn_s_setprio(0);
        __builtin_amdgcn_sched_barrier(0);
        __builtin_amdgcn_s_barrier();
        // ---- phase 3: stage t+2:Ah0; MFMA (m1, n23); boundary vmcnt
        STAGE(sb + 3);
        __builtin_amdgcn_sched_barrier(0);
        __builtin_amdgcn_s_barrier();
        __builtin_amdgcn_s_setprio(1);
        mfma_quad<1, 1>(acc, a, bv);
        __builtin_amdgcn_s_setprio(0);
        __builtin_amdgcn_sched_barrier(0);
        if (ti < NT - 2) asm volatile("s_waitcnt vmcnt(6)" ::: "memory");
        else             asm volatile("s_waitcnt vmcnt(0)" ::: "memory");
        __builtin_amdgcn_s_barrier();
    }

    // Epilogue: f16 C write
    int ocol = l & 15, orow4 = (l >> 4) * 4;
    #pragma unroll
    for (int mf = 0; mf < 8; ++mf)
        #pragma unroll
        for (int nf = 0; nf < 4; ++nf) {
            size_t base = (size_t)(row0 + wr * 128 + mf * 16 + orow4) * N
                        + col0 + wc * 64 + nf * 16 + ocol;
            #pragma unroll
            for (int j = 0; j < 4; ++j)
                C[base + (size_t)j * N] = (_Float16)acc[mf][nf][j];
        }
}

// ---------------------------------------------------------------------------
// f16 MFMA GEMM: 128x128 tile, 4 waves 2x2, BK=32, m97 structure (Wo proj).
// ---------------------------------------------------------------------------
template <bool OUT_HALF>
__global__ __launch_bounds__(256) void gemm_f16(const _Float16* __restrict__ A,
                                                const _Float16* __restrict__ BT,
                                                void* __restrict__ Cv,
                                                int M, int N, int K) {
    __shared__ _Float16 Asb[128 * 32];
    __shared__ _Float16 Bsb[128 * 32];
    int t = threadIdx.x;
    int w = t >> 6, l = t & 63;
    int wr = w >> 1, wc = w & 1;
    int row0 = blockIdx.y * 128, col0 = blockIdx.x * 128;

    f32x4 acc[4][4];
    #pragma unroll
    for (int m = 0; m < 4; ++m)
        #pragma unroll
        for (int n = 0; n < 4; ++n)
            acc[m][n] = (f32x4){0.f, 0.f, 0.f, 0.f};

    int srow = l >> 2;
    int scol = (l & 3) * 8;

    for (int k0 = 0; k0 < K; k0 += 32) {
        #pragma unroll
        for (int i = 0; i < 2; ++i) {
            int chunk = w * 2 + i;
            const _Float16* asrc =
                A + (size_t)(row0 + chunk * 16 + srow) * K + k0 + scol;
            __builtin_amdgcn_global_load_lds((const AS1 void*)asrc,
                                             (AS3 void*)(Asb + chunk * 512), 16, 0, 0);
            const _Float16* bsrc =
                BT + (size_t)(col0 + chunk * 16 + srow) * K + k0 + scol;
            __builtin_amdgcn_global_load_lds((const AS1 void*)bsrc,
                                             (AS3 void*)(Bsb + chunk * 512), 16, 0, 0);
        }
        __syncthreads();
        int rsel = l & 15, csel = (l >> 4) * 8;
        half8 a[4], b[4];
        #pragma unroll
        for (int m = 0; m < 4; ++m)
            a[m] = *(const half8*)&Asb[(wr * 64 + m * 16 + rsel) * 32 + csel];
        #pragma unroll
        for (int n = 0; n < 4; ++n)
            b[n] = *(const half8*)&Bsb[(wc * 64 + n * 16 + rsel) * 32 + csel];
        #pragma unroll
        for (int m = 0; m < 4; ++m)
            #pragma unroll
            for (int n = 0; n < 4; ++n)
                acc[m][n] = __builtin_amdgcn_mfma_f32_16x16x32_f16(a[m], b[n], acc[m][n], 0, 0, 0);
        __syncthreads();
    }

    int ocol = l & 15, orow = (l >> 4) * 4;
    #pragma unroll
    for (int m = 0; m < 4; ++m)
        #pragma unroll
        for (int n = 0; n < 4; ++n) {
            size_t base = (size_t)(row0 + wr * 64 + m * 16 + orow) * N
                        + col0 + wc * 64 + n * 16 + ocol;
            #pragma unroll
            for (int j = 0; j < 4; ++j) {
                if constexpr (OUT_HALF)
                    ((_Float16*)Cv)[base + (size_t)j * N] = (_Float16)acc[m][n][j];
                else
                    ((float*)Cv)[base + (size_t)j * N] = acc[m][n][j];
            }
        }
}

// ---------------------------------------------------------------------------
// featk: from qkv f16, produce pkT f16 [bnl][384][2048], vT f16 [bnl][64][2048]
// ---------------------------------------------------------------------------
__global__ __launch_bounds__(256) void featk_kernel(const _Float16* __restrict__ qkv,
                                                    _Float16* __restrict__ pkT,
                                                    _Float16* __restrict__ vT,
                                                    int bn0) {
    __shared__ float x2[128][33];
    __shared__ _Float16 vls[64][40];
    int t = threadIdx.x;
    int bnl = blockIdx.x;
    int bn = bn0 + bnl;
    int b = bn >> 4, nh = bn & 15;
    int j0 = blockIdx.y * 32;
    int c = t & 63;
    #pragma unroll
    for (int ii = 0; ii < 8; ++ii) {
        int jl = ii * 4 + (t >> 6);
        const _Float16* row = qkv + (size_t)((j0 + jl) * 2 + b) * 3072 + nh * 64;
        float kd = (float)row[1024 + c];
        vls[c][jl] = row[2048 + c];
        x2[c][jl] = fmaxf(kd, 0.f);
        x2[c + 64][jl] = fmaxf(-kd, 0.f);
    }
    __syncthreads();
    {
        int d = t >> 2, jj0 = (t & 3) * 8;
        half8 o;
        #pragma unroll
        for (int e = 0; e < 8; ++e) o[e] = vls[d][jj0 + e];
        *(half8*)&vT[((size_t)bnl * 64 + d) * 2048 + j0 + jj0] = o;
    }
    int fr = t >> 2, jj0 = (t & 3) * 8;
    #pragma unroll
    for (int fb = 0; fb < 6; ++fb) {
        int f = fb * 64 + fr;
        int fm = f & 127;
        int r = (f >> 7) + 1;
        int fm2 = (fm - r) & 127;
        half8 o;
        #pragma unroll
        for (int e = 0; e < 8; ++e)
            o[e] = (_Float16)(x2[fm][jj0 + e] * x2[fm2][jj0 + e]);
        *(half8*)&pkT[((size_t)bnl * FEAT + f) * 2048 + j0 + jj0] = o;
    }
}

// ---------------------------------------------------------------------------
// kvagg GEMM (16 bn per group, K-split 4)
// ---------------------------------------------------------------------------
__global__ __launch_bounds__(256) void kvagg_gemm(const _Float16* __restrict__ vT,
                                                  const _Float16* __restrict__ pkT,
                                                  float* __restrict__ kvp,
                                                  float* __restrict__ zp) {
    __shared__ _Float16 Asb[64 * 32];
    __shared__ _Float16 Bsb[128 * 32];
    int t = threadIdx.x;
    int w = t >> 6, l = t & 63;
    int wr = w >> 1, wc = w & 1;
    int fblk = blockIdx.x;   // 0..2
    int bnl = blockIdx.y;    // 0..15
    int kseg = blockIdx.z;   // 0..3
    const _Float16* Abase = vT + (size_t)bnl * 64 * 2048;
    const _Float16* Bbase = pkT + ((size_t)bnl * FEAT + fblk * 128) * 2048;

    f32x4 acc[2][4];
    #pragma unroll
    for (int m = 0; m < 2; ++m)
        #pragma unroll
        for (int n = 0; n < 4; ++n)
            acc[m][n] = (f32x4){0.f, 0.f, 0.f, 0.f};
    float zacc[4] = {0.f, 0.f, 0.f, 0.f};

    int srow = l >> 2, scol = (l & 3) * 8;
    int rsel = l & 15, csel = (l >> 4) * 8;

    for (int k0 = kseg * 512; k0 < kseg * 512 + 512; k0 += 32) {
        #pragma unroll
        for (int i = 0; i < 3; ++i) {
            int idx = w * 3 + i;
            if (idx < 4) {
                const _Float16* src = Abase + (size_t)(idx * 16 + srow) * 2048 + k0 + scol;
                __builtin_amdgcn_global_load_lds((const AS1 void*)src,
                                                 (AS3 void*)(Asb + idx * 512), 16, 0, 0);
            } else {
                int cB = idx - 4;
                const _Float16* src = Bbase + (size_t)(cB * 16 + srow) * 2048 + k0 + scol;
                __builtin_amdgcn_global_load_lds((const AS1 void*)src,
                                                 (AS3 void*)(Bsb + cB * 512), 16, 0, 0);
            }
        }
        __syncthreads();
        half8 a[2], bfr[4];
        #pragma unroll
        for (int m = 0; m < 2; ++m)
            a[m] = *(const half8*)&Asb[(wr * 32 + m * 16 + rsel) * 32 + csel];
        #pragma unroll
        for (int n = 0; n < 4; ++n)
            bfr[n] = *(const half8*)&Bsb[(wc * 64 + n * 16 + rsel) * 32 + csel];
        if (wr == 0) {
            #pragma unroll
            for (int n = 0; n < 4; ++n)
                #pragma unroll
                for (int e = 0; e < 8; ++e)
                    zacc[n] += (float)bfr[n][e];
        }
        #pragma unroll
        for (int m = 0; m < 2; ++m)
            #pragma unroll
            for (int n = 0; n < 4; ++n)
                acc[m][n] = __builtin_amdgcn_mfma_f32_16x16x32_f16(a[m], bfr[n], acc[m][n], 0, 0, 0);
        __syncthreads();
    }

    #pragma unroll
    for (int n = 0; n < 4; ++n) {
        float v = zacc[n];
        v += __shfl_xor(v, 16, 64);
        v += __shfl_xor(v, 32, 64);
        if (wr == 0 && l < 16)
            zp[(size_t)(kseg * 16 + bnl) * FEAT + fblk * 128 + wc * 64 + n * 16 + l] = v;
    }
    int orow = (l >> 4) * 4, ocol = l & 15;
    float* outp = kvp + (size_t)(kseg * 16 + bnl) * 64 * FEAT;
    #pragma unroll
    for (int m = 0; m < 2; ++m)
        #pragma unroll
        for (int n = 0; n < 4; ++n) {
            int fcol = fblk * 128 + wc * 64 + n * 16 + ocol;
            #pragma unroll
            for (int j = 0; j < 4; ++j)
                outp[(size_t)(wr * 32 + m * 16 + orow + j) * FEAT + fcol] = acc[m][n][j];
        }
}

// ---------------------------------------------------------------------------
// Reduce 4 k-segments -> kvaggT f16 [bn][64][384], z f32 [bn][384]
// ---------------------------------------------------------------------------
__global__ __launch_bounds__(256) void reduceA(const float* __restrict__ kvp,
                                               const float* __restrict__ zp,
                                               _Float16* __restrict__ kvaggT,
                                               float* __restrict__ z,
                                               int bn0) {
    const int NKV = 16 * 64 * FEAT;  // 393216
    int idx = blockIdx.x * 256 + threadIdx.x;
    if (idx < NKV) {
        float s = 0.f;
        #pragma unroll
        for (int c = 0; c < 4; ++c) s += kvp[(size_t)c * NKV + idx];
        int bnl = idx / (64 * FEAT);
        int rem = idx - bnl * (64 * FEAT);
        kvaggT[(size_t)(bn0 + bnl) * 64 * FEAT + rem] = (_Float16)s;
    } else if (idx < NKV + 16 * FEAT) {
        int e = idx - NKV;
        float s = 0.f;
        #pragma unroll
        for (int c = 0; c < 4; ++c) s += zp[c * 16 * FEAT + e];
        int bnl = e / FEAT;
        z[(size_t)(bn0 + bnl) * FEAT + (e - bnl * FEAT)] = s;
    }
}

// ---------------------------------------------------------------------------
// pq compute helper (static-index, no spill)
// ---------------------------------------------------------------------------
template <int F0>
__device__ __forceinline__ void pq_half(const float (&qr)[64], _Float16* prow) {
    #pragma unroll
    for (int g8 = 0; g8 < 24; ++g8) {
        half8 o;
        #pragma unroll
        for (int e = 0; e < 8; ++e) {
            const int f = F0 + g8 * 8 + e;
            const int fm = f & 127;
            const int r = (f >> 7) + 1;
            const int fm2 = (fm - r) & 127;
            float a = (fm < 64) ? fmaxf(qr[fm], 0.f) : fmaxf(-qr[fm - 64], 0.f);
            float bb = (fm2 < 64) ? fmaxf(qr[fm2], 0.f) : fmaxf(-qr[fm2 - 64], 0.f);
            o[e] = (_Float16)(a * bb);
        }
        *(half8*)&prow[F0 + g8 * 8] = o;
    }
}

// ---------------------------------------------------------------------------
// Fused attn: pq in LDS + barrier-free MFMA K-loop; fused den; f16 out.
// ---------------------------------------------------------------------------
#define PQ_STR 392
__global__ __launch_bounds__(256) void attn_fused(const _Float16* __restrict__ qkv,
                                                  const _Float16* __restrict__ kvaggT,
                                                  const float* __restrict__ z,
                                                  _Float16* __restrict__ av) {
    __shared__ _Float16 pq_lds[128 * PQ_STR];
    __shared__ _Float16 B_lds[64 * PQ_STR];
    __shared__ float z_lds[FEAT];
    __shared__ float den_lds[128];
    int t = threadIdx.x;
    int w = t >> 6, l = t & 63;
    int iblk = blockIdx.x;
    int bn = blockIdx.y;
    int b = bn >> 4, nh = bn & 15;

    {
        const _Float16* Bg = kvaggT + (size_t)bn * 64 * FEAT;
        #pragma unroll
        for (int s = 0; s < 12; ++s) {
            int idx8 = t + 256 * s;
            half8 vv = *(const half8*)&Bg[idx8 * 8];
            int row = idx8 / 48, col8 = idx8 - row * 48;
            *(half8*)&B_lds[row * PQ_STR + col8 * 8] = vv;
        }
    }
    for (int e = t; e < FEAT; e += 256) z_lds[e] = z[(size_t)bn * FEAT + e];

    {
        int il = t & 127;
        int ig = iblk * 128 + il;
        const _Float16* qrow = qkv + ((size_t)ig * 2 + b) * 3072 + nh * 64;
        float qr[64];
        #pragma unroll
        for (int e2 = 0; e2 < 8; ++e2) {
            half8 vv = *(const half8*)&qrow[e2 * 8];
            #pragma unroll
            for (int e = 0; e < 8; ++e) qr[e2 * 8 + e] = (float)vv[e];
        }
        _Float16* prow = &pq_lds[il * PQ_STR];
        if (t < 128) pq_half<0>(qr, prow);
        else         pq_half<192>(qr, prow);
    }
    __syncthreads();

    f32x4 acc[2][4];
    #pragma unroll
    for (int m = 0; m < 2; ++m)
        #pragma unroll
        for (int n = 0; n < 4; ++n)
            acc[m][n] = (f32x4){0.f, 0.f, 0.f, 0.f};
    float denacc[2] = {0.f, 0.f};
    int rsel = l & 15, csel = (l >> 4) * 8;

    #pragma unroll
    for (int k0 = 0; k0 < FEAT; k0 += 32) {
        half8 a[2], bfr[4];
        #pragma unroll
        for (int m = 0; m < 2; ++m)
            a[m] = *(const half8*)&pq_lds[(w * 32 + m * 16 + rsel) * PQ_STR + k0 + csel];
        #pragma unroll
        for (int n = 0; n < 4; ++n)
            bfr[n] = *(const half8*)&B_lds[(n * 16 + rsel) * PQ_STR + k0 + csel];
        #pragma unroll
        for (int m = 0; m < 2; ++m)
            #pragma unroll
            for (int e = 0; e < 8; ++e)
                denacc[m] += (float)a[m][e] * z_lds[k0 + csel + e];
        #pragma unroll
        for (int m = 0; m < 2; ++m)
            #pragma unroll
            for (int n = 0; n < 4; ++n)
                acc[m][n] = __builtin_amdgcn_mfma_f32_16x16x32_f16(a[m], bfr[n], acc[m][n], 0, 0, 0);
    }

    #pragma unroll
    for (int m = 0; m < 2; ++m) {
        float v = denacc[m];
        v += __shfl_xor(v, 16, 64);
        v += __shfl_xor(v, 32, 64);
        if (l < 16) den_lds[w * 32 + m * 16 + l] = v;
    }
    __syncthreads();

    int orow = (l >> 4) * 4, ocol = l & 15;
    #pragma unroll
    for (int m = 0; m < 2; ++m)
        #pragma unroll
        for (int n = 0; n < 4; ++n)
            #pragma unroll
            for (int j = 0; j < 4; ++j) {
                int row = w * 32 + m * 16 + orow + j;
                float den = den_lds[row] * SCALE + EPS;
                float val = acc[m][n][j] * SCALE / den;
                int i = iblk * 128 + row;
                av[((size_t)i * 2 + b) * 1024 + nh * 64 + n * 16 + ocol] = (_Float16)val;
            }
}

// ---------------------------------------------------------------------------
// Residual + LayerNorm, attn_out f16.
// ---------------------------------------------------------------------------
__global__ __launch_bounds__(256) void ln_kernel(const float* __restrict__ h,
                                                 const _Float16* __restrict__ attn_out,
                                                 const float* __restrict__ gamma,
                                                 const float* __restrict__ beta,
                                                 float* __restrict__ out) {
    int r = blockIdx.x;
    int t = threadIdx.x;
    float xs[4];
    float sum = 0.f, sq = 0.f;
    const float* hp = h + (size_t)r * 1024;
    const _Float16* ap = attn_out + (size_t)r * 1024;
    #pragma unroll
    for (int j = 0; j < 4; ++j) {
        int c = t + 256 * j;
        float x = hp[c] + (float)ap[c];
        xs[j] = x;
        sum += x;
        sq += x * x;
    }
    #pragma unroll
    for (int off = 32; off >= 1; off >>= 1) {
        sum += __shfl_xor(sum, off, 64);
        sq += __shfl_xor(sq, off, 64);
    }
    __shared__ float ssum[4], ssq[4];
    int wl = t >> 6, lane = t & 63;
    if (lane == 0) { ssum[wl] = sum; ssq[wl] = sq; }
    __syncthreads();
    sum = ssum[0] + ssum[1] + ssum[2] + ssum[3];
    sq = ssq[0] + ssq[1] + ssq[2] + ssq[3];
    float mu = sum * (1.f / 1024.f);
    float var = sq * (1.f / 1024.f) - mu * mu;
    float rs = rsqrtf(var + 1e-5f);
    float* op = out + (size_t)r * 1024;
    #pragma unroll
    for (int j = 0; j < 4; ++j) {
        int c = t + 256 * j;
        op[c] = (xs[j] - mu) * rs * gamma[c] + beta[c];
    }
}

// ---------------------------------------------------------------------------
extern "C" void kernel_launch(void* const* d_in, const int* in_sizes, int n_in,
                              void* d_out, int out_size, void* d_ws, size_t ws_size,
                              hipStream_t stream) {
    const float* h     = (const float*)d_in[0];
    const float* Wq    = (const float*)d_in[1];
    const float* Wkv   = (const float*)d_in[2];
    const float* Wo    = (const float*)d_in[3];
    const float* gamma = (const float*)d_in[4];
    const float* beta  = (const float*)d_in[5];
    float* out = (float*)d_out;
    _Float16* u = (_Float16*)d_ws;

    // Workspace layout (2-byte units), ~73 MB
    _Float16* h_h    = u;                       // 8 MB; later kvp(f32)/av(f16)
    _Float16* WqkvT  = u + 4194304;             // 6 MB
    _Float16* WoT    = u + 7340032;             // 2 MB
    _Float16* qkv    = u + 8388608;             // 24 MB; later attn_out f16
    _Float16* pkT_g  = u + 20971520;            // 25.2 MB
    _Float16* vT_g   = u + 33554432;            // 4.2 MB
    _Float16* kvaggT = u + 35651584;            // 1.5 MB
    float*    z      = (float*)(u + 36438016);
    float*    zp     = (float*)(u + 36462592);
    float*    kvp        = (float*)h_h;
    _Float16* av         = h_h;
    _Float16* attn_out_h = qkv;

    dim3 blk(256);
    // 0) conversions
    conv_h16<<<dim3(4096), blk, 0, stream>>>(h, h_h, 1048576);
    transpose_h16<<<dim3(96, 32), blk, 0, stream>>>(Wq, Wkv, WqkvT);
    transpose_h16<<<dim3(32, 32), blk, 0, stream>>>(Wo, Wo, WoT);
    // 1) fused qkv projection: 8-phase 256^2 kernel. grid 16*12=192 (%8==0)
    gemm_f16_8ph<<<dim3(192), dim3(512), 0, stream>>>(h_h, WqkvT, qkv, SB, 3072, DM);
    // 2) kv_agg + z in 2 groups of 16 (b,n)
    for (int g = 0; g < 2; ++g) {
        featk_kernel<<<dim3(16, 64), blk, 0, stream>>>(qkv, pkT_g, vT_g, g * 16);
        kvagg_gemm<<<dim3(3, 16, 4), blk, 0, stream>>>(vT_g, pkT_g, kvp, zp);
        reduceA<<<dim3(1560), blk, 0, stream>>>(kvp, zp, kvaggT, z, g * 16);
    }
    // 3) fused featq + attn GEMM (all 32 bn)
    attn_fused<<<dim3(16, 32), blk, 0, stream>>>(qkv, kvaggT, z, av);
    // 4) output projection (f16 out) + LN
    gemm_f16<true><<<dim3(8, 32), blk, 0, stream>>>(av, WoT, attn_out_h, SB, 1024, DM);
    ln_kernel<<<dim3(SB), blk, 0, stream>>>(h, attn_out_h, gamma, beta, out);
}

// Round 7
// 116.859 us; speedup vs baseline: 8.9601x; 1.3209x over previous
//
#include <hip/hip_runtime.h>
#include <math.h>

// Problem constants
#define NH 16
#define DM 1024
#define FEAT 384          // 2*64*3
#define SB 4096           // S*B
#define SEQ 2048

static constexpr float SCALE = 0.125f;  // 1/sqrt(64)
static constexpr float EPS = 1e-5f;

typedef __attribute__((ext_vector_type(8))) _Float16 half8;
typedef __attribute__((ext_vector_type(4))) _Float16 half4;
typedef __attribute__((ext_vector_type(4))) float f32x4;

#define AS1 __attribute__((address_space(1)))
#define AS3 __attribute__((address_space(3)))

// swizzled 16B-cell index into a [rows][64-half] LDS tile (row = 128B = 8 cells)
#define IDX(r, o) ((((r) << 6)) + ((((o) ^ ((r) & 7))) << 3))

// ---------------------------------------------------------------------------
// prep: merged f32->f16 conversion of h + weight transposes.
// grid 8192 x 256: [0,4096) conv; [4096,7168) Wqkv transpose; [7168,8192) Wo.
// ---------------------------------------------------------------------------
__global__ __launch_bounds__(256) void prep_kernel(const float* __restrict__ h,
                                                   const float* __restrict__ Wq,
                                                   const float* __restrict__ Wkv,
                                                   const float* __restrict__ Wo,
                                                   _Float16* __restrict__ h_h,
                                                   _Float16* __restrict__ WqkvT,
                                                   _Float16* __restrict__ WoT) {
    __shared__ _Float16 tile[32][33];
    int bid = blockIdx.x, t = threadIdx.x;
    if (bid < 4096) {
        int i = bid * 256 + t;
        const float4 v = ((const float4*)h)[i];
        half4 o = {(_Float16)v.x, (_Float16)v.y, (_Float16)v.z, (_Float16)v.w};
        ((half4*)h_h)[i] = o;
        return;
    }
    const float* src;
    _Float16* dst;
    int N, col0, n0, k0;
    if (bid < 7168) {
        int b2 = bid - 4096;
        n0 = (b2 % 96) * 32; k0 = (b2 / 96) * 32;
        if (n0 < 1024) { src = Wq; N = 1024; col0 = n0; }
        else           { src = Wkv; N = 2048; col0 = n0 - 1024; }
        dst = WqkvT;
    } else {
        int b3 = bid - 7168;
        n0 = (b3 & 31) * 32; k0 = (b3 >> 5) * 32;
        src = Wo; N = 1024; col0 = n0; dst = WoT;
    }
    int tx = t & 31, ty = t >> 5;
    #pragma unroll
    for (int i = 0; i < 4; ++i)
        tile[ty + i * 8][tx] = (_Float16)src[(size_t)(k0 + ty + i * 8) * N + col0 + tx];
    __syncthreads();
    #pragma unroll
    for (int i = 0; i < 4; ++i)
        dst[(size_t)(n0 + ty + i * 8) * 1024 + k0 + tx] = tile[tx][ty + i * 8];
}

// ---------------------------------------------------------------------------
// 256x256 8-phase f16 MFMA GEMM (T1+T2+T3+T4+T5), C f16.  (qkv projection)
// ---------------------------------------------------------------------------
template <int MH, int NB>
__device__ __forceinline__ void mfma_quad(f32x4 (&acc)[8][4], half8 (&a)[4][2],
                                          half8 (&bv)[4][2]) {
    #pragma unroll
    for (int mf = 0; mf < 4; ++mf)
        #pragma unroll
        for (int nf = 0; nf < 2; ++nf)
            #pragma unroll
            for (int ks = 0; ks < 2; ++ks)
                acc[MH * 4 + mf][NB * 2 + nf] = __builtin_amdgcn_mfma_f32_16x16x32_f16(
                    a[mf][ks], bv[NB * 2 + nf][ks], acc[MH * 4 + mf][NB * 2 + nf], 0, 0, 0);
}

__global__ __launch_bounds__(512) void gemm_f16_8ph(const _Float16* __restrict__ A,
                                                    const _Float16* __restrict__ BT,
                                                    _Float16* __restrict__ C,
                                                    int M, int N, int K) {
    __shared__ _Float16 smem[65536];
    const int t = threadIdx.x;
    const int w = t >> 6, l = t & 63;
    const int wr = w >> 2, wc = w & 3;
    const int NT = K >> 6;
    const int NHT = K >> 4;

    int nwg = gridDim.x;
    int cpx = nwg >> 3;
    int bid = blockIdx.x;
    int swz = (bid & 7) * cpx + (bid >> 3);
    int ntile = N >> 8;
    int row0 = (swz / ntile) << 8;
    int col0 = (swz % ntile) << 8;

    f32x4 acc[8][4];
    #pragma unroll
    for (int m = 0; m < 8; ++m)
        #pragma unroll
        for (int n = 0; n < 4; ++n)
            acc[m][n] = (f32x4){0.f, 0.f, 0.f, 0.f};

    const int lr = l >> 3;
    const int lc8 = ((l & 7) ^ lr) * 8;

    auto STAGE = [&](int s) {
        if (s >= NHT) return;
        int tau = s >> 2, hh = s & 3;
        int kk = tau << 6;
        int hf = hh & 1;
        int ldsbase = ((tau & 1) << 15) + ((hh >= 2) ? 0 : 16384) + (hf << 13)
                    + ((w * 2) << 9);
        const _Float16* gbase = (hh >= 2)
            ? A + (size_t)(row0 + hf * 128) * K
            : BT + (size_t)(col0 + hf * 128) * K;
        #pragma unroll
        for (int i = 0; i < 2; ++i) {
            const _Float16* src = gbase + (size_t)((w * 2 + i) * 8 + lr) * K + kk + lc8;
            __builtin_amdgcn_global_load_lds((const AS1 void*)src,
                                             (AS3 void*)(smem + ldsbase + (i << 9)), 16, 0, 0);
        }
    };

    half8 a[4][2], bv[4][2];
    auto LDA = [&](int mh, int bufb) {
        #pragma unroll
        for (int mf = 0; mf < 4; ++mf) {
            int r = wr * 128 + (mh * 4 + mf) * 16 + (l & 15);
            #pragma unroll
            for (int ks = 0; ks < 2; ++ks) {
                int c16 = (ks * 4 + (l >> 4)) ^ (r & 7);
                a[mf][ks] = *(const half8*)&smem[bufb + r * 64 + c16 * 8];
            }
        }
    };
    auto LDB = [&](int bufb) {
        #pragma unroll
        for (int nf = 0; nf < 4; ++nf) {
            int r = wc * 64 + nf * 16 + (l & 15);
            #pragma unroll
            for (int ks = 0; ks < 2; ++ks) {
                int c16 = (ks * 4 + (l >> 4)) ^ (r & 7);
                bv[nf][ks] = *(const half8*)&smem[bufb + 16384 + r * 64 + c16 * 8];
            }
        }
    };

    #pragma unroll 1
    for (int s = 0; s < 7; ++s) STAGE(s);
    asm volatile("s_waitcnt vmcnt(6)" ::: "memory");
    __builtin_amdgcn_s_barrier();

    #pragma unroll 1
    for (int ti = 0; ti < NT; ++ti) {
        const int bufb = (ti & 1) << 15;
        const int sb = 7 + (ti << 2);
        LDA(0, bufb); LDB(bufb);
        STAGE(sb);
        __builtin_amdgcn_sched_barrier(0);
        __builtin_amdgcn_s_barrier();
        asm volatile("s_waitcnt lgkmcnt(0)" ::: "memory");
        __builtin_amdgcn_sched_barrier(0);
        __builtin_amdgcn_s_setprio(1);
        mfma_quad<0, 0>(acc, a, bv);
        __builtin_amdgcn_s_setprio(0);
        __builtin_amdgcn_sched_barrier(0);
        __builtin_amdgcn_s_barrier();
        STAGE(sb + 1);
        __builtin_amdgcn_sched_barrier(0);
        __builtin_amdgcn_s_barrier();
        __builtin_amdgcn_s_setprio(1);
        mfma_quad<0, 1>(acc, a, bv);
        __builtin_amdgcn_s_setprio(0);
        __builtin_amdgcn_sched_barrier(0);
        __builtin_amdgcn_s_barrier();
        LDA(1, bufb);
        STAGE(sb + 2);
        __builtin_amdgcn_sched_barrier(0);
        __builtin_amdgcn_s_barrier();
        asm volatile("s_waitcnt lgkmcnt(0)" ::: "memory");
        __builtin_amdgcn_sched_barrier(0);
        __builtin_amdgcn_s_setprio(1);
        mfma_quad<1, 0>(acc, a, bv);
        __builtin_amdgcn_s_setprio(0);
        __builtin_amdgcn_sched_barrier(0);
        __builtin_amdgcn_s_barrier();
        STAGE(sb + 3);
        __builtin_amdgcn_sched_barrier(0);
        __builtin_amdgcn_s_barrier();
        __builtin_amdgcn_s_setprio(1);
        mfma_quad<1, 1>(acc, a, bv);
        __builtin_amdgcn_s_setprio(0);
        __builtin_amdgcn_sched_barrier(0);
        if (ti < NT - 2) asm volatile("s_waitcnt vmcnt(6)" ::: "memory");
        else             asm volatile("s_waitcnt vmcnt(0)" ::: "memory");
        __builtin_amdgcn_s_barrier();
    }

    int ocol = l & 15, orow4 = (l >> 4) * 4;
    #pragma unroll
    for (int mf = 0; mf < 8; ++mf)
        #pragma unroll
        for (int nf = 0; nf < 4; ++nf) {
            size_t base = (size_t)(row0 + wr * 128 + mf * 16 + orow4) * N
                        + col0 + wc * 64 + nf * 16 + ocol;
            #pragma unroll
            for (int j = 0; j < 4; ++j)
                C[base + (size_t)j * N] = (_Float16)acc[mf][nf][j];
        }
}

// ---------------------------------------------------------------------------
// f16 MFMA GEMM: 128x128 tile, m97 structure (Wo projection).
// ---------------------------------------------------------------------------
__global__ __launch_bounds__(256) void gemm_f16(const _Float16* __restrict__ A,
                                                const _Float16* __restrict__ BT,
                                                _Float16* __restrict__ C,
                                                int M, int N, int K) {
    __shared__ _Float16 Asb[128 * 32];
    __shared__ _Float16 Bsb[128 * 32];
    int t = threadIdx.x;
    int w = t >> 6, l = t & 63;
    int wr = w >> 1, wc = w & 1;
    int row0 = blockIdx.y * 128, col0 = blockIdx.x * 128;

    f32x4 acc[4][4];
    #pragma unroll
    for (int m = 0; m < 4; ++m)
        #pragma unroll
        for (int n = 0; n < 4; ++n)
            acc[m][n] = (f32x4){0.f, 0.f, 0.f, 0.f};

    int srow = l >> 2;
    int scol = (l & 3) * 8;

    for (int k0 = 0; k0 < K; k0 += 32) {
        #pragma unroll
        for (int i = 0; i < 2; ++i) {
            int chunk = w * 2 + i;
            const _Float16* asrc =
                A + (size_t)(row0 + chunk * 16 + srow) * K + k0 + scol;
            __builtin_amdgcn_global_load_lds((const AS1 void*)asrc,
                                             (AS3 void*)(Asb + chunk * 512), 16, 0, 0);
            const _Float16* bsrc =
                BT + (size_t)(col0 + chunk * 16 + srow) * K + k0 + scol;
            __builtin_amdgcn_global_load_lds((const AS1 void*)bsrc,
                                             (AS3 void*)(Bsb + chunk * 512), 16, 0, 0);
        }
        __syncthreads();
        int rsel = l & 15, csel = (l >> 4) * 8;
        half8 a[4], b[4];
        #pragma unroll
        for (int m = 0; m < 4; ++m)
            a[m] = *(const half8*)&Asb[(wr * 64 + m * 16 + rsel) * 32 + csel];
        #pragma unroll
        for (int n = 0; n < 4; ++n)
            b[n] = *(const half8*)&Bsb[(wc * 64 + n * 16 + rsel) * 32 + csel];
        #pragma unroll
        for (int m = 0; m < 4; ++m)
            #pragma unroll
            for (int n = 0; n < 4; ++n)
                acc[m][n] = __builtin_amdgcn_mfma_f32_16x16x32_f16(a[m], b[n], acc[m][n], 0, 0, 0);
        __syncthreads();
    }

    int ocol = l & 15, orow = (l >> 4) * 4;
    #pragma unroll
    for (int m = 0; m < 4; ++m)
        #pragma unroll
        for (int n = 0; n < 4; ++n) {
            size_t base = (size_t)(row0 + wr * 64 + m * 16 + orow) * N
                        + col0 + wc * 64 + n * 16 + ocol;
            #pragma unroll
            for (int j = 0; j < 4; ++j)
                C[base + (size_t)j * N] = (_Float16)acc[m][n][j];
        }
}

// ---------------------------------------------------------------------------
// kvagg_fused: per (bn, jseg): on-the-fly DPFP(k) + v, MFMA accumulate
//   kvp[jseg][bn][64 d][384 f] = sum_j v[j,d]*pk[j,f]   (256 j's)
//   zp[jseg][bn][f] = sum_j pk[j,f]
// 512 threads (8 waves; wave w owns f-block w*48). LDS 72 KB, swizzled cells.
// ---------------------------------------------------------------------------
__global__ __launch_bounds__(512) void kvagg_fused(const _Float16* __restrict__ qkv,
                                                   float* __restrict__ kvp,
                                                   float* __restrict__ zp) {
    __shared__ _Float16 x2s[128 * 64];    // 16 KB  [fm][j-chunk]
    __shared__ _Float16 vTs[64 * 64];     //  8 KB  [d][j-chunk]
    __shared__ _Float16 pkTs[384 * 64];   // 48 KB  [f][j-chunk]
    const int t = threadIdx.x;
    const int w = t >> 6, l = t & 63;
    const int bn = blockIdx.x;      // 0..31
    const int jseg = blockIdx.y;    // 0..7
    const int b = bn >> 4, nh = bn & 15;

    f32x4 acc[4][3];
    #pragma unroll
    for (int mf = 0; mf < 4; ++mf)
        #pragma unroll
        for (int nf = 0; nf < 3; ++nf)
            acc[mf][nf] = (f32x4){0.f, 0.f, 0.f, 0.f};
    float zacc[3] = {0.f, 0.f, 0.f};

    const int sc = t & 63;    // staging: k/v column (d)
    const int so = t >> 6;    // staging: j-oct

    #pragma unroll 1
    for (int ch = 0; ch < 4; ++ch) {
        int j0 = jseg * 256 + ch * 64;
        // load k,v (scalar, wave-coalesced 128B per j-row)
        _Float16 kx[8], vx[8];
        #pragma unroll
        for (int e = 0; e < 8; ++e) {
            size_t rb = (size_t)((j0 + so * 8 + e) * 2 + b) * 3072 + nh * 64 + sc;
            kx[e] = qkv[rb + 1024];
            vx[e] = qkv[rb + 2048];
        }
        half8 xlo, xhi, vv;
        #pragma unroll
        for (int e = 0; e < 8; ++e) {
            float kf = (float)kx[e];
            xlo[e] = (_Float16)fmaxf(kf, 0.f);
            xhi[e] = (_Float16)fmaxf(-kf, 0.f);
            vv[e] = vx[e];
        }
        if (ch) __syncthreads();   // prev MFMA reads done before overwrite
        *(half8*)&x2s[IDX(sc, so)] = xlo;
        *(half8*)&x2s[IDX(sc + 64, so)] = xhi;
        *(half8*)&vTs[IDX(sc, so)] = vv;
        __syncthreads();
        // pk compute: thread -> (f = it*64 + (t>>3), oct = t&7)
        {
            const int o = t & 7;
            const int fb = t >> 3;   // 0..63
            #pragma unroll
            for (int it = 0; it < 6; ++it) {
                int f = it * 64 + fb;
                int fm = f & 127;
                int r = (f >> 7) + 1;
                int fm2 = (fm - r) & 127;
                half8 pa = *(const half8*)&x2s[IDX(fm, o)];
                half8 pb = *(const half8*)&x2s[IDX(fm2, o)];
                *(half8*)&pkTs[IDX(f, o)] = pa * pb;
            }
        }
        __syncthreads();
        // MFMA: 2 k-steps of 32 j
        #pragma unroll
        for (int ks = 0; ks < 2; ++ks) {
            half8 a[4], bq[3];
            int oo = ks * 4 + (l >> 4);
            #pragma unroll
            for (int mf = 0; mf < 4; ++mf) {
                int dr = mf * 16 + (l & 15);
                a[mf] = *(const half8*)&vTs[IDX(dr, oo)];
            }
            #pragma unroll
            for (int nf = 0; nf < 3; ++nf) {
                int fr = w * 48 + nf * 16 + (l & 15);
                bq[nf] = *(const half8*)&pkTs[IDX(fr, oo)];
                #pragma unroll
                for (int e = 0; e < 8; ++e) zacc[nf] += (float)bq[nf][e];
            }
            #pragma unroll
            for (int mf = 0; mf < 4; ++mf)
                #pragma unroll
                for (int nf = 0; nf < 3; ++nf)
                    acc[mf][nf] = __builtin_amdgcn_mfma_f32_16x16x32_f16(
                        a[mf], bq[nf], acc[mf][nf], 0, 0, 0);
        }
    }

    // z partial write
    #pragma unroll
    for (int nf = 0; nf < 3; ++nf) {
        float v = zacc[nf];
        v += __shfl_xor(v, 16, 64);
        v += __shfl_xor(v, 32, 64);
        if (l < 16)
            zp[(size_t)(jseg * 32 + bn) * FEAT + w * 48 + nf * 16 + l] = v;
    }
    // C partial write
    float* outp = kvp + (size_t)(jseg * 32 + bn) * 64 * FEAT;
    int orow = (l >> 4) * 4, ocol = l & 15;
    #pragma unroll
    for (int mf = 0; mf < 4; ++mf)
        #pragma unroll
        for (int nf = 0; nf < 3; ++nf) {
            int fcol = w * 48 + nf * 16 + ocol;
            #pragma unroll
            for (int j = 0; j < 4; ++j)
                outp[(size_t)(mf * 16 + orow + j) * FEAT + fcol] = acc[mf][nf][j];
        }
}

// ---------------------------------------------------------------------------
// Reduce 8 j-segments -> kvaggT f16 [32][64][384], z f32 [32][384]
// ---------------------------------------------------------------------------
__global__ __launch_bounds__(256) void reduceA(const float* __restrict__ kvp,
                                               const float* __restrict__ zp,
                                               _Float16* __restrict__ kvaggT,
                                               float* __restrict__ z) {
    const int NKV = 32 * 64 * FEAT;  // 786432
    int idx = blockIdx.x * 256 + threadIdx.x;
    if (idx < NKV) {
        float s = 0.f;
        #pragma unroll
        for (int c = 0; c < 8; ++c) s += kvp[(size_t)c * NKV + idx];
        kvaggT[idx] = (_Float16)s;
    } else if (idx < NKV + 32 * FEAT) {
        int e = idx - NKV;
        float s = 0.f;
        #pragma unroll
        for (int c = 0; c < 8; ++c) s += zp[c * 32 * FEAT + e];
        z[e] = s;
    }
}

// ---------------------------------------------------------------------------
// pq compute helper (static-index, no spill)
// ---------------------------------------------------------------------------
template <int F0>
__device__ __forceinline__ void pq_half(const float (&qr)[64], _Float16* prow) {
    #pragma unroll
    for (int g8 = 0; g8 < 24; ++g8) {
        half8 o;
        #pragma unroll
        for (int e = 0; e < 8; ++e) {
            const int f = F0 + g8 * 8 + e;
            const int fm = f & 127;
            const int r = (f >> 7) + 1;
            const int fm2 = (fm - r) & 127;
            float a = (fm < 64) ? fmaxf(qr[fm], 0.f) : fmaxf(-qr[fm - 64], 0.f);
            float bb = (fm2 < 64) ? fmaxf(qr[fm2], 0.f) : fmaxf(-qr[fm2 - 64], 0.f);
            o[e] = (_Float16)(a * bb);
        }
        *(half8*)&prow[F0 + g8 * 8] = o;
    }
}

// ---------------------------------------------------------------------------
// Fused attn: pq in LDS + barrier-free MFMA K-loop; fused den; f16 out.
// ---------------------------------------------------------------------------
#define PQ_STR 392
__global__ __launch_bounds__(256) void attn_fused(const _Float16* __restrict__ qkv,
                                                  const _Float16* __restrict__ kvaggT,
                                                  const float* __restrict__ z,
                                                  _Float16* __restrict__ av) {
    __shared__ _Float16 pq_lds[128 * PQ_STR];
    __shared__ _Float16 B_lds[64 * PQ_STR];
    __shared__ float z_lds[FEAT];
    __shared__ float den_lds[128];
    int t = threadIdx.x;
    int w = t >> 6, l = t & 63;
    int iblk = blockIdx.x;
    int bn = blockIdx.y;
    int b = bn >> 4, nh = bn & 15;

    {
        const _Float16* Bg = kvaggT + (size_t)bn * 64 * FEAT;
        #pragma unroll
        for (int s = 0; s < 12; ++s) {
            int idx8 = t + 256 * s;
            half8 vv = *(const half8*)&Bg[idx8 * 8];
            int row = idx8 / 48, col8 = idx8 - row * 48;
            *(half8*)&B_lds[row * PQ_STR + col8 * 8] = vv;
        }
    }
    for (int e = t; e < FEAT; e += 256) z_lds[e] = z[(size_t)bn * FEAT + e];

    {
        int il = t & 127;
        int ig = iblk * 128 + il;
        const _Float16* qrow = qkv + ((size_t)ig * 2 + b) * 3072 + nh * 64;
        float qr[64];
        #pragma unroll
        for (int e2 = 0; e2 < 8; ++e2) {
            half8 vv = *(const half8*)&qrow[e2 * 8];
            #pragma unroll
            for (int e = 0; e < 8; ++e) qr[e2 * 8 + e] = (float)vv[e];
        }
        _Float16* prow = &pq_lds[il * PQ_STR];
        if (t < 128) pq_half<0>(qr, prow);
        else         pq_half<192>(qr, prow);
    }
    __syncthreads();

    f32x4 acc[2][4];
    #pragma unroll
    for (int m = 0; m < 2; ++m)
        #pragma unroll
        for (int n = 0; n < 4; ++n)
            acc[m][n] = (f32x4){0.f, 0.f, 0.f, 0.f};
    float denacc[2] = {0.f, 0.f};
    int rsel = l & 15, csel = (l >> 4) * 8;

    #pragma unroll
    for (int k0 = 0; k0 < FEAT; k0 += 32) {
        half8 a[2], bfr[4];
        #pragma unroll
        for (int m = 0; m < 2; ++m)
            a[m] = *(const half8*)&pq_lds[(w * 32 + m * 16 + rsel) * PQ_STR + k0 + csel];
        #pragma unroll
        for (int n = 0; n < 4; ++n)
            bfr[n] = *(const half8*)&B_lds[(n * 16 + rsel) * PQ_STR + k0 + csel];
        #pragma unroll
        for (int m = 0; m < 2; ++m)
            #pragma unroll
            for (int e = 0; e < 8; ++e)
                denacc[m] += (float)a[m][e] * z_lds[k0 + csel + e];
        #pragma unroll
        for (int m = 0; m < 2; ++m)
            #pragma unroll
            for (int n = 0; n < 4; ++n)
                acc[m][n] = __builtin_amdgcn_mfma_f32_16x16x32_f16(a[m], bfr[n], acc[m][n], 0, 0, 0);
    }

    #pragma unroll
    for (int m = 0; m < 2; ++m) {
        float v = denacc[m];
        v += __shfl_xor(v, 16, 64);
        v += __shfl_xor(v, 32, 64);
        if (l < 16) den_lds[w * 32 + m * 16 + l] = v;
    }
    __syncthreads();

    int orow = (l >> 4) * 4, ocol = l & 15;
    #pragma unroll
    for (int m = 0; m < 2; ++m)
        #pragma unroll
        for (int n = 0; n < 4; ++n)
            #pragma unroll
            for (int j = 0; j < 4; ++j) {
                int row = w * 32 + m * 16 + orow + j;
                float den = den_lds[row] * SCALE + EPS;
                float val = acc[m][n][j] * SCALE / den;
                int i = iblk * 128 + row;
                av[((size_t)i * 2 + b) * 1024 + nh * 64 + n * 16 + ocol] = (_Float16)val;
            }
}

// ---------------------------------------------------------------------------
// Residual + LayerNorm, vectorized (float4 / half4).
// ---------------------------------------------------------------------------
__global__ __launch_bounds__(256) void ln_kernel(const float* __restrict__ h,
                                                 const _Float16* __restrict__ attn_out,
                                                 const float* __restrict__ gamma,
                                                 const float* __restrict__ beta,
                                                 float* __restrict__ out) {
    int r = blockIdx.x;
    int t = threadIdx.x;
    const float4 hv = ((const float4*)(h + (size_t)r * 1024))[t];
    const half4 a4 = ((const half4*)(attn_out + (size_t)r * 1024))[t];
    float x[4] = {hv.x + (float)a4[0], hv.y + (float)a4[1],
                  hv.z + (float)a4[2], hv.w + (float)a4[3]};
    float sum = x[0] + x[1] + x[2] + x[3];
    float sq = x[0]*x[0] + x[1]*x[1] + x[2]*x[2] + x[3]*x[3];
    #pragma unroll
    for (int off = 32; off >= 1; off >>= 1) {
        sum += __shfl_xor(sum, off, 64);
        sq += __shfl_xor(sq, off, 64);
    }
    __shared__ float ssum[4], ssq[4];
    int wl = t >> 6, lane = t & 63;
    if (lane == 0) { ssum[wl] = sum; ssq[wl] = sq; }
    __syncthreads();
    sum = ssum[0] + ssum[1] + ssum[2] + ssum[3];
    sq = ssq[0] + ssq[1] + ssq[2] + ssq[3];
    float mu = sum * (1.f / 1024.f);
    float var = sq * (1.f / 1024.f) - mu * mu;
    float rs = rsqrtf(var + 1e-5f);
    const float4 g4 = ((const float4*)gamma)[t];
    const float4 b4 = ((const float4*)beta)[t];
    float4 o;
    o.x = (x[0] - mu) * rs * g4.x + b4.x;
    o.y = (x[1] - mu) * rs * g4.y + b4.y;
    o.z = (x[2] - mu) * rs * g4.z + b4.z;
    o.w = (x[3] - mu) * rs * g4.w + b4.w;
    ((float4*)(out + (size_t)r * 1024))[t] = o;
}

// ---------------------------------------------------------------------------
extern "C" void kernel_launch(void* const* d_in, const int* in_sizes, int n_in,
                              void* d_out, int out_size, void* d_ws, size_t ws_size,
                              hipStream_t stream) {
    const float* h     = (const float*)d_in[0];
    const float* Wq    = (const float*)d_in[1];
    const float* Wkv   = (const float*)d_in[2];
    const float* Wo    = (const float*)d_in[3];
    const float* gamma = (const float*)d_in[4];
    const float* beta  = (const float*)d_in[5];
    float* out = (float*)d_out;
    _Float16* u = (_Float16*)d_ws;

    // Workspace (2-byte units), ~69 MB
    _Float16* h_h    = u;                       // 8 MB; later av (f16)
    _Float16* WqkvT  = u + 4194304;             // 6 MB
    _Float16* WoT    = u + 7340032;             // 2 MB
    _Float16* qkv    = u + 8388608;             // 24 MB; later attn_out f16
    float*    kvp    = (float*)(u + 20971520);  // 8x32x64x384 f32 = 25.2 MB
    float*    zp     = (float*)(u + 33554432);  // 8x32x384 f32 = 0.4 MB
    _Float16* kvaggT = u + 33751040;            // 1.5 MB
    float*    z      = (float*)(u + 34537472);  // 48 KB
    _Float16* av         = h_h;
    _Float16* attn_out_h = qkv;

    dim3 blk(256);
    // 0) merged prep: conv h->f16 + weight transposes
    prep_kernel<<<dim3(8192), blk, 0, stream>>>(h, Wq, Wkv, Wo, h_h, WqkvT, WoT);
    // 1) fused qkv projection (8-phase 256^2), grid 16*12=192
    gemm_f16_8ph<<<dim3(192), dim3(512), 0, stream>>>(h_h, WqkvT, qkv, SB, 3072, DM);
    // 2) fused DPFP(k)+kvagg+z partials over (32 bn x 8 jseg)
    kvagg_fused<<<dim3(32, 8), dim3(512), 0, stream>>>(qkv, kvp, zp);
    // 3) reduce partials
    reduceA<<<dim3(3120), blk, 0, stream>>>(kvp, zp, kvaggT, z);
    // 4) fused featq + attn GEMM (all 32 bn)
    attn_fused<<<dim3(16, 32), blk, 0, stream>>>(qkv, kvaggT, z, av);
    // 5) output projection (f16 out)
    gemm_f16<<<dim3(8, 32), blk, 0, stream>>>(av, WoT, attn_out_h, SB, 1024, DM);
    // 6) residual + LayerNorm
    ln_kernel<<<dim3(SB), blk, 0, stream>>>(h, attn_out_h, gamma, beta, out);
}

// Round 8
// 111.571 us; speedup vs baseline: 9.3848x; 1.0474x over previous
//
#include <hip/hip_runtime.h>
#include <math.h>

// Problem constants
#define NH 16
#define DM 1024
#define FEAT 384          // 2*64*3
#define SB 4096           // S*B
#define SEQ 2048

static constexpr float SCALE = 0.125f;  // 1/sqrt(64)
static constexpr float EPS = 1e-5f;

typedef __attribute__((ext_vector_type(8))) _Float16 half8;
typedef __attribute__((ext_vector_type(4))) _Float16 half4;
typedef __attribute__((ext_vector_type(4))) float f32x4;

#define AS1 __attribute__((address_space(1)))
#define AS3 __attribute__((address_space(3)))

// swizzled 16B-cell index into a [rows][64-half] LDS tile (row = 128B = 8 cells)
#define IDX(r, o) ((((r) << 6)) + ((((o) ^ ((r) & 7))) << 3))

// ---------------------------------------------------------------------------
// prep: merged f32->f16 conversion of h + weight transposes.
// grid 8192 x 256: [0,4096) conv; [4096,7168) Wqkv transpose; [7168,8192) Wo.
// ---------------------------------------------------------------------------
__global__ __launch_bounds__(256) void prep_kernel(const float* __restrict__ h,
                                                   const float* __restrict__ Wq,
                                                   const float* __restrict__ Wkv,
                                                   const float* __restrict__ Wo,
                                                   _Float16* __restrict__ h_h,
                                                   _Float16* __restrict__ WqkvT,
                                                   _Float16* __restrict__ WoT) {
    __shared__ _Float16 tile[32][33];
    int bid = blockIdx.x, t = threadIdx.x;
    if (bid < 4096) {
        int i = bid * 256 + t;
        const float4 v = ((const float4*)h)[i];
        half4 o = {(_Float16)v.x, (_Float16)v.y, (_Float16)v.z, (_Float16)v.w};
        ((half4*)h_h)[i] = o;
        return;
    }
    const float* src;
    _Float16* dst;
    int N, col0, n0, k0;
    if (bid < 7168) {
        int b2 = bid - 4096;
        n0 = (b2 % 96) * 32; k0 = (b2 / 96) * 32;
        if (n0 < 1024) { src = Wq; N = 1024; col0 = n0; }
        else           { src = Wkv; N = 2048; col0 = n0 - 1024; }
        dst = WqkvT;
    } else {
        int b3 = bid - 7168;
        n0 = (b3 & 31) * 32; k0 = (b3 >> 5) * 32;
        src = Wo; N = 1024; col0 = n0; dst = WoT;
    }
    int tx = t & 31, ty = t >> 5;
    #pragma unroll
    for (int i = 0; i < 4; ++i)
        tile[ty + i * 8][tx] = (_Float16)src[(size_t)(k0 + ty + i * 8) * N + col0 + tx];
    __syncthreads();
    #pragma unroll
    for (int i = 0; i < 4; ++i)
        dst[(size_t)(n0 + ty + i * 8) * 1024 + k0 + tx] = tile[tx][ty + i * 8];
}

// ---------------------------------------------------------------------------
// 256x192 8-phase f16 MFMA GEMM (T1+T2+T3+T4+T5), C f16. (qkv projection)
// 512 threads = 8 waves (2 M x 4 N), per-wave 128x48, BK=64.
// LDS 112 KiB: 2 buf x (A 256x64 + B 192x64). Stage units per K-tile:
// [B0 rows0-127 (2 ld), B1 rows128-191 (1 ld), A0 rows0-127 (2), A1 rows128-255 (2)]
// = 7 loads/thread/K-tile. Counted waits: vmcnt(5) steady, vmcnt(0) last two.
// Requires: M%256==0, N%192==0, K%64==0, K/64>=3, grid=(M/256)*(N/192), %8==0.
// ---------------------------------------------------------------------------
template <int MH>
__device__ __forceinline__ void mfma_n01(f32x4 (&acc)[8][3], half8 (&a)[4][2],
                                         half8 (&bv)[3][2]) {
    #pragma unroll
    for (int mf = 0; mf < 4; ++mf)
        #pragma unroll
        for (int nf = 0; nf < 2; ++nf)
            #pragma unroll
            for (int ks = 0; ks < 2; ++ks)
                acc[MH * 4 + mf][nf] = __builtin_amdgcn_mfma_f32_16x16x32_f16(
                    a[mf][ks], bv[nf][ks], acc[MH * 4 + mf][nf], 0, 0, 0);
}
template <int MH>
__device__ __forceinline__ void mfma_n2(f32x4 (&acc)[8][3], half8 (&a)[4][2],
                                        half8 (&bv)[3][2]) {
    #pragma unroll
    for (int mf = 0; mf < 4; ++mf)
        #pragma unroll
        for (int ks = 0; ks < 2; ++ks)
            acc[MH * 4 + mf][2] = __builtin_amdgcn_mfma_f32_16x16x32_f16(
                a[mf][ks], bv[2][ks], acc[MH * 4 + mf][2], 0, 0, 0);
}

__global__ __launch_bounds__(512) void gemm_f16_8ph(const _Float16* __restrict__ A,
                                                    const _Float16* __restrict__ BT,
                                                    _Float16* __restrict__ C,
                                                    int M, int N, int K) {
    __shared__ _Float16 smem[57344];   // 2 x 28672 halfs = 112 KiB
    const int t = threadIdx.x;
    const int w = t >> 6, l = t & 63;
    const int wr = w >> 2, wc = w & 3;
    const int NT = K >> 6;
    const int NU = K >> 4;    // stage units = 4*NT

    int nwg = gridDim.x;
    int cpx = nwg >> 3;
    int bid = blockIdx.x;
    int swz = (bid & 7) * cpx + (bid >> 3);
    int ntile = N / 192;
    int row0 = (swz / ntile) << 8;
    int col0 = (swz % ntile) * 192;

    f32x4 acc[8][3];
    #pragma unroll
    for (int m = 0; m < 8; ++m)
        #pragma unroll
        for (int n = 0; n < 3; ++n)
            acc[m][n] = (f32x4){0.f, 0.f, 0.f, 0.f};

    const int lr = l >> 3;
    const int lc8 = ((l & 7) ^ lr) * 8;

    // stage unit s; per-tile order [B0, B1, A0, A1]
    auto STAGE = [&](int s) {
        if (s >= NU) return;
        int tau = s >> 2, u = s & 3;
        int kk = tau << 6;
        int bufo = (tau & 1) * 28672;
        if (u == 0) {          // B rows 0-127 (2 loads)
            #pragma unroll
            for (int i = 0; i < 2; ++i) {
                int chunk = w * 2 + i;
                const _Float16* src = BT + (size_t)(col0 + chunk * 8 + lr) * K + kk + lc8;
                __builtin_amdgcn_global_load_lds((const AS1 void*)src,
                    (AS3 void*)(smem + bufo + 16384 + chunk * 512), 16, 0, 0);
            }
        } else if (u == 1) {   // B rows 128-191 (1 load)
            const _Float16* src = BT + (size_t)(col0 + 128 + w * 8 + lr) * K + kk + lc8;
            __builtin_amdgcn_global_load_lds((const AS1 void*)src,
                (AS3 void*)(smem + bufo + 24576 + w * 512), 16, 0, 0);
        } else {               // u==2: A rows 0-127 ; u==3: A rows 128-255
            int rbase = (u == 3) ? 128 : 0;
            int lbase = (u == 3) ? 8192 : 0;
            #pragma unroll
            for (int i = 0; i < 2; ++i) {
                int chunk = w * 2 + i;
                const _Float16* src = A + (size_t)(row0 + rbase + chunk * 8 + lr) * K + kk + lc8;
                __builtin_amdgcn_global_load_lds((const AS1 void*)src,
                    (AS3 void*)(smem + bufo + lbase + chunk * 512), 16, 0, 0);
            }
        }
    };

    half8 a[4][2], bv[3][2];
    auto LDA = [&](int mh, int bufo) {
        #pragma unroll
        for (int mf = 0; mf < 4; ++mf) {
            int r = wr * 128 + (mh * 4 + mf) * 16 + (l & 15);
            #pragma unroll
            for (int ks = 0; ks < 2; ++ks) {
                int c16 = (ks * 4 + (l >> 4)) ^ (r & 7);
                a[mf][ks] = *(const half8*)&smem[bufo + r * 64 + c16 * 8];
            }
        }
    };
    auto LDB = [&](int bufo) {
        #pragma unroll
        for (int nf = 0; nf < 3; ++nf) {
            int r = wc * 48 + nf * 16 + (l & 15);
            #pragma unroll
            for (int ks = 0; ks < 2; ++ks) {
                int c16 = (ks * 4 + (l >> 4)) ^ (r & 7);
                bv[nf][ks] = *(const half8*)&smem[bufo + 16384 + r * 64 + c16 * 8];
            }
        }
    };

    // Prologue: tile0 all (7 loads) + tile1 B0,B1,A0 (5 loads)
    #pragma unroll 1
    for (int s = 0; s < 7; ++s) STAGE(s);
    asm volatile("s_waitcnt vmcnt(5)" ::: "memory");
    __builtin_amdgcn_s_barrier();

    #pragma unroll 1
    for (int ti = 0; ti < NT; ++ti) {
        const int bufo = (ti & 1) * 28672;
        const int sb = 7 + (ti << 2);
        // ---- phase 0: reads a[mh0]+all b; stage ti+1:A1; MFMA (mh0, n01)
        LDA(0, bufo); LDB(bufo);
        STAGE(sb);
        __builtin_amdgcn_sched_barrier(0);
        __builtin_amdgcn_s_barrier();
        asm volatile("s_waitcnt lgkmcnt(0)" ::: "memory");
        __builtin_amdgcn_sched_barrier(0);
        __builtin_amdgcn_s_setprio(1);
        mfma_n01<0>(acc, a, bv);
        __builtin_amdgcn_s_setprio(0);
        __builtin_amdgcn_sched_barrier(0);
        __builtin_amdgcn_s_barrier();
        // ---- phase 1: stage ti+2:B0; MFMA (mh0, n2)
        STAGE(sb + 1);
        __builtin_amdgcn_sched_barrier(0);
        __builtin_amdgcn_s_barrier();
        __builtin_amdgcn_s_setprio(1);
        mfma_n2<0>(acc, a, bv);
        __builtin_amdgcn_s_setprio(0);
        __builtin_amdgcn_sched_barrier(0);
        __builtin_amdgcn_s_barrier();
        // ---- phase 2: reads a[mh1]; stage ti+2:B1; MFMA (mh1, n01)
        LDA(1, bufo);
        STAGE(sb + 2);
        __builtin_amdgcn_sched_barrier(0);
        __builtin_amdgcn_s_barrier();
        asm volatile("s_waitcnt lgkmcnt(0)" ::: "memory");
        __builtin_amdgcn_sched_barrier(0);
        __builtin_amdgcn_s_setprio(1);
        mfma_n01<1>(acc, a, bv);
        __builtin_amdgcn_s_setprio(0);
        __builtin_amdgcn_sched_barrier(0);
        __builtin_amdgcn_s_barrier();
        // ---- phase 3: stage ti+2:A0; MFMA (mh1, n2); boundary vmcnt
        STAGE(sb + 3);
        __builtin_amdgcn_sched_barrier(0);
        __builtin_amdgcn_s_barrier();
        __builtin_amdgcn_s_setprio(1);
        mfma_n2<1>(acc, a, bv);
        __builtin_amdgcn_s_setprio(0);
        __builtin_amdgcn_sched_barrier(0);
        if (ti < NT - 2) asm volatile("s_waitcnt vmcnt(5)" ::: "memory");
        else             asm volatile("s_waitcnt vmcnt(0)" ::: "memory");
        __builtin_amdgcn_s_barrier();
    }

    // Epilogue: f16 C write
    int ocol = l & 15, orow4 = (l >> 4) * 4;
    #pragma unroll
    for (int mf = 0; mf < 8; ++mf)
        #pragma unroll
        for (int nf = 0; nf < 3; ++nf) {
            size_t base = (size_t)(row0 + wr * 128 + mf * 16 + orow4) * N
                        + col0 + wc * 48 + nf * 16 + ocol;
            #pragma unroll
            for (int j = 0; j < 4; ++j)
                C[base + (size_t)j * N] = (_Float16)acc[mf][nf][j];
        }
}

// ---------------------------------------------------------------------------
// f16 MFMA GEMM: 128x128 tile, m97 structure (Wo projection).
// ---------------------------------------------------------------------------
__global__ __launch_bounds__(256) void gemm_f16(const _Float16* __restrict__ A,
                                                const _Float16* __restrict__ BT,
                                                _Float16* __restrict__ C,
                                                int M, int N, int K) {
    __shared__ _Float16 Asb[128 * 32];
    __shared__ _Float16 Bsb[128 * 32];
    int t = threadIdx.x;
    int w = t >> 6, l = t & 63;
    int wr = w >> 1, wc = w & 1;
    int row0 = blockIdx.y * 128, col0 = blockIdx.x * 128;

    f32x4 acc[4][4];
    #pragma unroll
    for (int m = 0; m < 4; ++m)
        #pragma unroll
        for (int n = 0; n < 4; ++n)
            acc[m][n] = (f32x4){0.f, 0.f, 0.f, 0.f};

    int srow = l >> 2;
    int scol = (l & 3) * 8;

    for (int k0 = 0; k0 < K; k0 += 32) {
        #pragma unroll
        for (int i = 0; i < 2; ++i) {
            int chunk = w * 2 + i;
            const _Float16* asrc =
                A + (size_t)(row0 + chunk * 16 + srow) * K + k0 + scol;
            __builtin_amdgcn_global_load_lds((const AS1 void*)asrc,
                                             (AS3 void*)(Asb + chunk * 512), 16, 0, 0);
            const _Float16* bsrc =
                BT + (size_t)(col0 + chunk * 16 + srow) * K + k0 + scol;
            __builtin_amdgcn_global_load_lds((const AS1 void*)bsrc,
                                             (AS3 void*)(Bsb + chunk * 512), 16, 0, 0);
        }
        __syncthreads();
        int rsel = l & 15, csel = (l >> 4) * 8;
        half8 a[4], b[4];
        #pragma unroll
        for (int m = 0; m < 4; ++m)
            a[m] = *(const half8*)&Asb[(wr * 64 + m * 16 + rsel) * 32 + csel];
        #pragma unroll
        for (int n = 0; n < 4; ++n)
            b[n] = *(const half8*)&Bsb[(wc * 64 + n * 16 + rsel) * 32 + csel];
        #pragma unroll
        for (int m = 0; m < 4; ++m)
            #pragma unroll
            for (int n = 0; n < 4; ++n)
                acc[m][n] = __builtin_amdgcn_mfma_f32_16x16x32_f16(a[m], b[n], acc[m][n], 0, 0, 0);
        __syncthreads();
    }

    int ocol = l & 15, orow = (l >> 4) * 4;
    #pragma unroll
    for (int m = 0; m < 4; ++m)
        #pragma unroll
        for (int n = 0; n < 4; ++n) {
            size_t base = (size_t)(row0 + wr * 64 + m * 16 + orow) * N
                        + col0 + wc * 64 + n * 16 + ocol;
            #pragma unroll
            for (int j = 0; j < 4; ++j)
                C[base + (size_t)j * N] = (_Float16)acc[m][n][j];
        }
}

// ---------------------------------------------------------------------------
// kvagg_fused: per (bn, jseg): on-the-fly DPFP(k) + v, MFMA accumulate
// ---------------------------------------------------------------------------
__global__ __launch_bounds__(512) void kvagg_fused(const _Float16* __restrict__ qkv,
                                                   float* __restrict__ kvp,
                                                   float* __restrict__ zp) {
    __shared__ _Float16 x2s[128 * 64];    // 16 KB
    __shared__ _Float16 vTs[64 * 64];     //  8 KB
    __shared__ _Float16 pkTs[384 * 64];   // 48 KB
    const int t = threadIdx.x;
    const int w = t >> 6, l = t & 63;
    const int bn = blockIdx.x;
    const int jseg = blockIdx.y;
    const int b = bn >> 4, nh = bn & 15;

    f32x4 acc[4][3];
    #pragma unroll
    for (int mf = 0; mf < 4; ++mf)
        #pragma unroll
        for (int nf = 0; nf < 3; ++nf)
            acc[mf][nf] = (f32x4){0.f, 0.f, 0.f, 0.f};
    float zacc[3] = {0.f, 0.f, 0.f};

    const int sc = t & 63;
    const int so = t >> 6;

    #pragma unroll 1
    for (int ch = 0; ch < 4; ++ch) {
        int j0 = jseg * 256 + ch * 64;
        _Float16 kx[8], vx[8];
        #pragma unroll
        for (int e = 0; e < 8; ++e) {
            size_t rb = (size_t)((j0 + so * 8 + e) * 2 + b) * 3072 + nh * 64 + sc;
            kx[e] = qkv[rb + 1024];
            vx[e] = qkv[rb + 2048];
        }
        half8 xlo, xhi, vv;
        #pragma unroll
        for (int e = 0; e < 8; ++e) {
            float kf = (float)kx[e];
            xlo[e] = (_Float16)fmaxf(kf, 0.f);
            xhi[e] = (_Float16)fmaxf(-kf, 0.f);
            vv[e] = vx[e];
        }
        if (ch) __syncthreads();
        *(half8*)&x2s[IDX(sc, so)] = xlo;
        *(half8*)&x2s[IDX(sc + 64, so)] = xhi;
        *(half8*)&vTs[IDX(sc, so)] = vv;
        __syncthreads();
        {
            const int o = t & 7;
            const int fb = t >> 3;
            #pragma unroll
            for (int it = 0; it < 6; ++it) {
                int f = it * 64 + fb;
                int fm = f & 127;
                int r = (f >> 7) + 1;
                int fm2 = (fm - r) & 127;
                half8 pa = *(const half8*)&x2s[IDX(fm, o)];
                half8 pb = *(const half8*)&x2s[IDX(fm2, o)];
                *(half8*)&pkTs[IDX(f, o)] = pa * pb;
            }
        }
        __syncthreads();
        #pragma unroll
        for (int ks = 0; ks < 2; ++ks) {
            half8 a[4], bq[3];
            int oo = ks * 4 + (l >> 4);
            #pragma unroll
            for (int mf = 0; mf < 4; ++mf) {
                int dr = mf * 16 + (l & 15);
                a[mf] = *(const half8*)&vTs[IDX(dr, oo)];
            }
            #pragma unroll
            for (int nf = 0; nf < 3; ++nf) {
                int fr = w * 48 + nf * 16 + (l & 15);
                bq[nf] = *(const half8*)&pkTs[IDX(fr, oo)];
                #pragma unroll
                for (int e = 0; e < 8; ++e) zacc[nf] += (float)bq[nf][e];
            }
            #pragma unroll
            for (int mf = 0; mf < 4; ++mf)
                #pragma unroll
                for (int nf = 0; nf < 3; ++nf)
                    acc[mf][nf] = __builtin_amdgcn_mfma_f32_16x16x32_f16(
                        a[mf], bq[nf], acc[mf][nf], 0, 0, 0);
        }
    }

    #pragma unroll
    for (int nf = 0; nf < 3; ++nf) {
        float v = zacc[nf];
        v += __shfl_xor(v, 16, 64);
        v += __shfl_xor(v, 32, 64);
        if (l < 16)
            zp[(size_t)(jseg * 32 + bn) * FEAT + w * 48 + nf * 16 + l] = v;
    }
    float* outp = kvp + (size_t)(jseg * 32 + bn) * 64 * FEAT;
    int orow = (l >> 4) * 4, ocol = l & 15;
    #pragma unroll
    for (int mf = 0; mf < 4; ++mf)
        #pragma unroll
        for (int nf = 0; nf < 3; ++nf) {
            int fcol = w * 48 + nf * 16 + ocol;
            #pragma unroll
            for (int j = 0; j < 4; ++j)
                outp[(size_t)(mf * 16 + orow + j) * FEAT + fcol] = acc[mf][nf][j];
        }
}

// ---------------------------------------------------------------------------
// Reduce 8 j-segments -> kvaggT f16 [32][64][384], z f32 [32][384]
// ---------------------------------------------------------------------------
__global__ __launch_bounds__(256) void reduceA(const float* __restrict__ kvp,
                                               const float* __restrict__ zp,
                                               _Float16* __restrict__ kvaggT,
                                               float* __restrict__ z) {
    const int NKV = 32 * 64 * FEAT;  // 786432
    int idx = blockIdx.x * 256 + threadIdx.x;
    if (idx < NKV) {
        float s = 0.f;
        #pragma unroll
        for (int c = 0; c < 8; ++c) s += kvp[(size_t)c * NKV + idx];
        kvaggT[idx] = (_Float16)s;
    } else if (idx < NKV + 32 * FEAT) {
        int e = idx - NKV;
        float s = 0.f;
        #pragma unroll
        for (int c = 0; c < 8; ++c) s += zp[c * 32 * FEAT + e];
        z[e] = s;
    }
}

// ---------------------------------------------------------------------------
// pq compute helper (static-index, no spill)
// ---------------------------------------------------------------------------
template <int F0>
__device__ __forceinline__ void pq_half(const float (&qr)[64], _Float16* prow) {
    #pragma unroll
    for (int g8 = 0; g8 < 24; ++g8) {
        half8 o;
        #pragma unroll
        for (int e = 0; e < 8; ++e) {
            const int f = F0 + g8 * 8 + e;
            const int fm = f & 127;
            const int r = (f >> 7) + 1;
            const int fm2 = (fm - r) & 127;
            float a = (fm < 64) ? fmaxf(qr[fm], 0.f) : fmaxf(-qr[fm - 64], 0.f);
            float bb = (fm2 < 64) ? fmaxf(qr[fm2], 0.f) : fmaxf(-qr[fm2 - 64], 0.f);
            o[e] = (_Float16)(a * bb);
        }
        *(half8*)&prow[F0 + g8 * 8] = o;
    }
}

// ---------------------------------------------------------------------------
// Fused attn: pq in LDS + barrier-free MFMA K-loop; fused den; f16 out.
// ---------------------------------------------------------------------------
#define PQ_STR 392
__global__ __launch_bounds__(256) void attn_fused(const _Float16* __restrict__ qkv,
                                                  const _Float16* __restrict__ kvaggT,
                                                  const float* __restrict__ z,
                                                  _Float16* __restrict__ av) {
    __shared__ _Float16 pq_lds[128 * PQ_STR];
    __shared__ _Float16 B_lds[64 * PQ_STR];
    __shared__ float z_lds[FEAT];
    __shared__ float den_lds[128];
    int t = threadIdx.x;
    int w = t >> 6, l = t & 63;
    int iblk = blockIdx.x;
    int bn = blockIdx.y;
    int b = bn >> 4, nh = bn & 15;

    {
        const _Float16* Bg = kvaggT + (size_t)bn * 64 * FEAT;
        #pragma unroll
        for (int s = 0; s < 12; ++s) {
            int idx8 = t + 256 * s;
            half8 vv = *(const half8*)&Bg[idx8 * 8];
            int row = idx8 / 48, col8 = idx8 - row * 48;
            *(half8*)&B_lds[row * PQ_STR + col8 * 8] = vv;
        }
    }
    for (int e = t; e < FEAT; e += 256) z_lds[e] = z[(size_t)bn * FEAT + e];

    {
        int il = t & 127;
        int ig = iblk * 128 + il;
        const _Float16* qrow = qkv + ((size_t)ig * 2 + b) * 3072 + nh * 64;
        float qr[64];
        #pragma unroll
        for (int e2 = 0; e2 < 8; ++e2) {
            half8 vv = *(const half8*)&qrow[e2 * 8];
            #pragma unroll
            for (int e = 0; e < 8; ++e) qr[e2 * 8 + e] = (float)vv[e];
        }
        _Float16* prow = &pq_lds[il * PQ_STR];
        if (t < 128) pq_half<0>(qr, prow);
        else         pq_half<192>(qr, prow);
    }
    __syncthreads();

    f32x4 acc[2][4];
    #pragma unroll
    for (int m = 0; m < 2; ++m)
        #pragma unroll
        for (int n = 0; n < 4; ++n)
            acc[m][n] = (f32x4){0.f, 0.f, 0.f, 0.f};
    float denacc[2] = {0.f, 0.f};
    int rsel = l & 15, csel = (l >> 4) * 8;

    #pragma unroll
    for (int k0 = 0; k0 < FEAT; k0 += 32) {
        half8 a[2], bfr[4];
        #pragma unroll
        for (int m = 0; m < 2; ++m)
            a[m] = *(const half8*)&pq_lds[(w * 32 + m * 16 + rsel) * PQ_STR + k0 + csel];
        #pragma unroll
        for (int n = 0; n < 4; ++n)
            bfr[n] = *(const half8*)&B_lds[(n * 16 + rsel) * PQ_STR + k0 + csel];
        #pragma unroll
        for (int m = 0; m < 2; ++m)
            #pragma unroll
            for (int e = 0; e < 8; ++e)
                denacc[m] += (float)a[m][e] * z_lds[k0 + csel + e];
        #pragma unroll
        for (int m = 0; m < 2; ++m)
            #pragma unroll
            for (int n = 0; n < 4; ++n)
                acc[m][n] = __builtin_amdgcn_mfma_f32_16x16x32_f16(a[m], bfr[n], acc[m][n], 0, 0, 0);
    }

    #pragma unroll
    for (int m = 0; m < 2; ++m) {
        float v = denacc[m];
        v += __shfl_xor(v, 16, 64);
        v += __shfl_xor(v, 32, 64);
        if (l < 16) den_lds[w * 32 + m * 16 + l] = v;
    }
    __syncthreads();

    int orow = (l >> 4) * 4, ocol = l & 15;
    #pragma unroll
    for (int m = 0; m < 2; ++m)
        #pragma unroll
        for (int n = 0; n < 4; ++n)
            #pragma unroll
            for (int j = 0; j < 4; ++j) {
                int row = w * 32 + m * 16 + orow + j;
                float den = den_lds[row] * SCALE + EPS;
                float val = acc[m][n][j] * SCALE / den;
                int i = iblk * 128 + row;
                av[((size_t)i * 2 + b) * 1024 + nh * 64 + n * 16 + ocol] = (_Float16)val;
            }
}

// ---------------------------------------------------------------------------
// Residual + LayerNorm, vectorized (float4 / half4).
// ---------------------------------------------------------------------------
__global__ __launch_bounds__(256) void ln_kernel(const float* __restrict__ h,
                                                 const _Float16* __restrict__ attn_out,
                                                 const float* __restrict__ gamma,
                                                 const float* __restrict__ beta,
                                                 float* __restrict__ out) {
    int r = blockIdx.x;
    int t = threadIdx.x;
    const float4 hv = ((const float4*)(h + (size_t)r * 1024))[t];
    const half4 a4 = ((const half4*)(attn_out + (size_t)r * 1024))[t];
    float x[4] = {hv.x + (float)a4[0], hv.y + (float)a4[1],
                  hv.z + (float)a4[2], hv.w + (float)a4[3]};
    float sum = x[0] + x[1] + x[2] + x[3];
    float sq = x[0]*x[0] + x[1]*x[1] + x[2]*x[2] + x[3]*x[3];
    #pragma unroll
    for (int off = 32; off >= 1; off >>= 1) {
        sum += __shfl_xor(sum, off, 64);
        sq += __shfl_xor(sq, off, 64);
    }
    __shared__ float ssum[4], ssq[4];
    int wl = t >> 6, lane = t & 63;
    if (lane == 0) { ssum[wl] = sum; ssq[wl] = sq; }
    __syncthreads();
    sum = ssum[0] + ssum[1] + ssum[2] + ssum[3];
    sq = ssq[0] + ssq[1] + ssq[2] + ssq[3];
    float mu = sum * (1.f / 1024.f);
    float var = sq * (1.f / 1024.f) - mu * mu;
    float rs = rsqrtf(var + 1e-5f);
    const float4 g4 = ((const float4*)gamma)[t];
    const float4 b4 = ((const float4*)beta)[t];
    float4 o;
    o.x = (x[0] - mu) * rs * g4.x + b4.x;
    o.y = (x[1] - mu) * rs * g4.y + b4.y;
    o.z = (x[2] - mu) * rs * g4.z + b4.z;
    o.w = (x[3] - mu) * rs * g4.w + b4.w;
    ((float4*)(out + (size_t)r * 1024))[t] = o;
}

// ---------------------------------------------------------------------------
extern "C" void kernel_launch(void* const* d_in, const int* in_sizes, int n_in,
                              void* d_out, int out_size, void* d_ws, size_t ws_size,
                              hipStream_t stream) {
    const float* h     = (const float*)d_in[0];
    const float* Wq    = (const float*)d_in[1];
    const float* Wkv   = (const float*)d_in[2];
    const float* Wo    = (const float*)d_in[3];
    const float* gamma = (const float*)d_in[4];
    const float* beta  = (const float*)d_in[5];
    float* out = (float*)d_out;
    _Float16* u = (_Float16*)d_ws;

    // Workspace (2-byte units), ~69 MB
    _Float16* h_h    = u;                       // 8 MB; later av (f16)
    _Float16* WqkvT  = u + 4194304;             // 6 MB
    _Float16* WoT    = u + 7340032;             // 2 MB
    _Float16* qkv    = u + 8388608;             // 24 MB; later attn_out f16
    float*    kvp    = (float*)(u + 20971520);  // 25.2 MB
    float*    zp     = (float*)(u + 33554432);  // 0.4 MB
    _Float16* kvaggT = u + 33751040;            // 1.5 MB
    float*    z      = (float*)(u + 34537472);  // 48 KB
    _Float16* av         = h_h;
    _Float16* attn_out_h = qkv;

    dim3 blk(256);
    // 0) merged prep: conv h->f16 + weight transposes
    prep_kernel<<<dim3(8192), blk, 0, stream>>>(h, Wq, Wkv, Wo, h_h, WqkvT, WoT);
    // 1) fused qkv projection (8-phase 256x192), grid 16*16=256 (%8==0)
    gemm_f16_8ph<<<dim3(256), dim3(512), 0, stream>>>(h_h, WqkvT, qkv, SB, 3072, DM);
    // 2) fused DPFP(k)+kvagg+z partials over (32 bn x 8 jseg)
    kvagg_fused<<<dim3(32, 8), dim3(512), 0, stream>>>(qkv, kvp, zp);
    // 3) reduce partials
    reduceA<<<dim3(3120), blk, 0, stream>>>(kvp, zp, kvaggT, z);
    // 4) fused featq + attn GEMM (all 32 bn)
    attn_fused<<<dim3(16, 32), blk, 0, stream>>>(qkv, kvaggT, z, av);
    // 5) output projection (f16 out)
    gemm_f16<<<dim3(8, 32), blk, 0, stream>>>(av, WoT, attn_out_h, SB, 1024, DM);
    // 6) residual + LayerNorm
    ln_kernel<<<dim3(SB), blk, 0, stream>>>(h, attn_out_h, gamma, beta, out);
}

// Round 9
// 111.400 us; speedup vs baseline: 9.3992x; 1.0015x over previous
//
#include <hip/hip_runtime.h>
#include <math.h>

// Problem constants
#define NH 16
#define DM 1024
#define FEAT 384          // 2*64*3
#define SB 4096           // S*B
#define SEQ 2048

static constexpr float SCALE = 0.125f;  // 1/sqrt(64)
static constexpr float EPS = 1e-5f;

typedef __attribute__((ext_vector_type(8))) _Float16 half8;
typedef __attribute__((ext_vector_type(4))) _Float16 half4;
typedef __attribute__((ext_vector_type(4))) float f32x4;

#define AS1 __attribute__((address_space(1)))
#define AS3 __attribute__((address_space(3)))

// swizzled 16B-cell index into a [rows][64-half] LDS tile (row = 128B = 8 cells)
#define IDX(r, o) ((((r) << 6)) + ((((o) ^ ((r) & 7))) << 3))

// ---------------------------------------------------------------------------
// prep: merged f32->f16 conversion of h + weight transposes.
// ---------------------------------------------------------------------------
__global__ __launch_bounds__(256) void prep_kernel(const float* __restrict__ h,
                                                   const float* __restrict__ Wq,
                                                   const float* __restrict__ Wkv,
                                                   const float* __restrict__ Wo,
                                                   _Float16* __restrict__ h_h,
                                                   _Float16* __restrict__ WqkvT,
                                                   _Float16* __restrict__ WoT) {
    __shared__ _Float16 tile[32][33];
    int bid = blockIdx.x, t = threadIdx.x;
    if (bid < 4096) {
        int i = bid * 256 + t;
        const float4 v = ((const float4*)h)[i];
        half4 o = {(_Float16)v.x, (_Float16)v.y, (_Float16)v.z, (_Float16)v.w};
        ((half4*)h_h)[i] = o;
        return;
    }
    const float* src;
    _Float16* dst;
    int N, col0, n0, k0;
    if (bid < 7168) {
        int b2 = bid - 4096;
        n0 = (b2 % 96) * 32; k0 = (b2 / 96) * 32;
        if (n0 < 1024) { src = Wq; N = 1024; col0 = n0; }
        else           { src = Wkv; N = 2048; col0 = n0 - 1024; }
        dst = WqkvT;
    } else {
        int b3 = bid - 7168;
        n0 = (b3 & 31) * 32; k0 = (b3 >> 5) * 32;
        src = Wo; N = 1024; col0 = n0; dst = WoT;
    }
    int tx = t & 31, ty = t >> 5;
    #pragma unroll
    for (int i = 0; i < 4; ++i)
        tile[ty + i * 8][tx] = (_Float16)src[(size_t)(k0 + ty + i * 8) * N + col0 + tx];
    __syncthreads();
    #pragma unroll
    for (int i = 0; i < 4; ++i)
        dst[(size_t)(n0 + ty + i * 8) * 1024 + k0 + tx] = tile[tx][ty + i * 8];
}

// ---------------------------------------------------------------------------
// 256x192 2-phase f16 MFMA GEMM (T1+T2+T4+T5), C f16. (qkv projection)
// 512 threads = 8 waves (2 M x 4 N), per-wave 128x48, BK=64.
// LDS 112 KiB: 2 buf x (A 256x64 + B 192x64). Stage units per K-tile:
// [B0 (2 ld), B1 (1), A0 (2), A1 (2)] = 7 loads/thread/K-tile.
// Schedule: 2 phases/tile, 4 barriers/tile, 24-MFMA clusters.
//   P0: LDA(mh0)+LDB || stage ti+1:{A0,A1}; bar; lgkm0; MFMA; bar
//   P1: LDA(mh1)     || stage ti+2:{B0,B1}; bar; lgkm0; MFMA; vmcnt(3); bar
// Ledger: B staged 2 tiles ahead, A 1 tile ahead -> at boundary exactly
// ti+2:B (3 loads) in flight; vmcnt(3) proves ti+1 resident. Last two
// boundaries vmcnt(0). Hazards: B ds_reads end in P0 before stage of ti+2:B
// (P1, same buf); A-half reads end before tile-end barrier, stage of ti+1:A
// goes to opposite buf after that barrier.
// ---------------------------------------------------------------------------
template <int MH>
__device__ __forceinline__ void mfma_all(f32x4 (&acc)[8][3], half8 (&a)[4][2],
                                         half8 (&bv)[3][2]) {
    #pragma unroll
    for (int mf = 0; mf < 4; ++mf)
        #pragma unroll
        for (int nf = 0; nf < 3; ++nf)
            #pragma unroll
            for (int ks = 0; ks < 2; ++ks)
                acc[MH * 4 + mf][nf] = __builtin_amdgcn_mfma_f32_16x16x32_f16(
                    a[mf][ks], bv[nf][ks], acc[MH * 4 + mf][nf], 0, 0, 0);
}

__global__ __launch_bounds__(512) void gemm_f16_8ph(const _Float16* __restrict__ A,
                                                    const _Float16* __restrict__ BT,
                                                    _Float16* __restrict__ C,
                                                    int M, int N, int K) {
    __shared__ _Float16 smem[57344];   // 2 x 28672 halfs = 112 KiB
    const int t = threadIdx.x;
    const int w = t >> 6, l = t & 63;
    const int wr = w >> 2, wc = w & 3;
    const int NT = K >> 6;
    const int NU = K >> 4;    // stage units = 4*NT

    int nwg = gridDim.x;
    int cpx = nwg >> 3;
    int bid = blockIdx.x;
    int swz = (bid & 7) * cpx + (bid >> 3);
    int ntile = N / 192;
    int row0 = (swz / ntile) << 8;
    int col0 = (swz % ntile) * 192;

    f32x4 acc[8][3];
    #pragma unroll
    for (int m = 0; m < 8; ++m)
        #pragma unroll
        for (int n = 0; n < 3; ++n)
            acc[m][n] = (f32x4){0.f, 0.f, 0.f, 0.f};

    const int lr = l >> 3;
    const int lc8 = ((l & 7) ^ lr) * 8;

    // stage unit s; per-tile order [B0, B1, A0, A1]
    auto STAGE = [&](int s) {
        if (s >= NU) return;
        int tau = s >> 2, u = s & 3;
        int kk = tau << 6;
        int bufo = (tau & 1) * 28672;
        if (u == 0) {          // B rows 0-127 (2 loads)
            #pragma unroll
            for (int i = 0; i < 2; ++i) {
                int chunk = w * 2 + i;
                const _Float16* src = BT + (size_t)(col0 + chunk * 8 + lr) * K + kk + lc8;
                __builtin_amdgcn_global_load_lds((const AS1 void*)src,
                    (AS3 void*)(smem + bufo + 16384 + chunk * 512), 16, 0, 0);
            }
        } else if (u == 1) {   // B rows 128-191 (1 load)
            const _Float16* src = BT + (size_t)(col0 + 128 + w * 8 + lr) * K + kk + lc8;
            __builtin_amdgcn_global_load_lds((const AS1 void*)src,
                (AS3 void*)(smem + bufo + 24576 + w * 512), 16, 0, 0);
        } else {               // u==2: A rows 0-127 ; u==3: A rows 128-255
            int rbase = (u == 3) ? 128 : 0;
            int lbase = (u == 3) ? 8192 : 0;
            #pragma unroll
            for (int i = 0; i < 2; ++i) {
                int chunk = w * 2 + i;
                const _Float16* src = A + (size_t)(row0 + rbase + chunk * 8 + lr) * K + kk + lc8;
                __builtin_amdgcn_global_load_lds((const AS1 void*)src,
                    (AS3 void*)(smem + bufo + lbase + chunk * 512), 16, 0, 0);
            }
        }
    };

    half8 a[4][2], bv[3][2];
    auto LDA = [&](int mh, int bufo) {
        #pragma unroll
        for (int mf = 0; mf < 4; ++mf) {
            int r = wr * 128 + (mh * 4 + mf) * 16 + (l & 15);
            #pragma unroll
            for (int ks = 0; ks < 2; ++ks) {
                int c16 = (ks * 4 + (l >> 4)) ^ (r & 7);
                a[mf][ks] = *(const half8*)&smem[bufo + r * 64 + c16 * 8];
            }
        }
    };
    auto LDB = [&](int bufo) {
        #pragma unroll
        for (int nf = 0; nf < 3; ++nf) {
            int r = wc * 48 + nf * 16 + (l & 15);
            #pragma unroll
            for (int ks = 0; ks < 2; ++ks) {
                int c16 = (ks * 4 + (l >> 4)) ^ (r & 7);
                bv[nf][ks] = *(const half8*)&smem[bufo + 16384 + r * 64 + c16 * 8];
            }
        }
    };

    // Prologue (issue order = steady state): t0:B0,B1 ; t0:A0,A1 ; t1:B0,B1
    STAGE(0); STAGE(1);            // t0 B  (3 loads)
    STAGE(2); STAGE(3);            // t0 A  (4 loads)
    STAGE(4); STAGE(5);            // t1 B  (3 loads)
    asm volatile("s_waitcnt vmcnt(3)" ::: "memory");   // t0 resident
    __builtin_amdgcn_s_barrier();

    #pragma unroll 1
    for (int ti = 0; ti < NT; ++ti) {
        const int bufo = (ti & 1) * 28672;
        const int sb = (ti + 1) << 2;
        // ---- P0: reads a[mh0] + all b; stage ti+1:{A0,A1}; MFMA mh0 x n012
        LDA(0, bufo); LDB(bufo);
        STAGE(sb + 2); STAGE(sb + 3);
        __builtin_amdgcn_sched_barrier(0);
        __builtin_amdgcn_s_barrier();
        asm volatile("s_waitcnt lgkmcnt(0)" ::: "memory");
        __builtin_amdgcn_sched_barrier(0);
        __builtin_amdgcn_s_setprio(1);
        mfma_all<0>(acc, a, bv);
        __builtin_amdgcn_s_setprio(0);
        __builtin_amdgcn_sched_barrier(0);
        __builtin_amdgcn_s_barrier();
        // ---- P1: reads a[mh1]; stage ti+2:{B0,B1}; MFMA mh1 x n012; boundary
        LDA(1, bufo);
        STAGE(sb + 4); STAGE(sb + 5);
        __builtin_amdgcn_sched_barrier(0);
        __builtin_amdgcn_s_barrier();
        asm volatile("s_waitcnt lgkmcnt(0)" ::: "memory");
        __builtin_amdgcn_sched_barrier(0);
        __builtin_amdgcn_s_setprio(1);
        mfma_all<1>(acc, a, bv);
        __builtin_amdgcn_s_setprio(0);
        __builtin_amdgcn_sched_barrier(0);
        if (ti < NT - 2) asm volatile("s_waitcnt vmcnt(3)" ::: "memory");
        else             asm volatile("s_waitcnt vmcnt(0)" ::: "memory");
        __builtin_amdgcn_s_barrier();
    }

    // Epilogue: f16 C write
    int ocol = l & 15, orow4 = (l >> 4) * 4;
    #pragma unroll
    for (int mf = 0; mf < 8; ++mf)
        #pragma unroll
        for (int nf = 0; nf < 3; ++nf) {
            size_t base = (size_t)(row0 + wr * 128 + mf * 16 + orow4) * N
                        + col0 + wc * 48 + nf * 16 + ocol;
            #pragma unroll
            for (int j = 0; j < 4; ++j)
                C[base + (size_t)j * N] = (_Float16)acc[mf][nf][j];
        }
}

// ---------------------------------------------------------------------------
// f16 MFMA GEMM: 128x128 tile, m97 structure (Wo projection).
// ---------------------------------------------------------------------------
__global__ __launch_bounds__(256) void gemm_f16(const _Float16* __restrict__ A,
                                                const _Float16* __restrict__ BT,
                                                _Float16* __restrict__ C,
                                                int M, int N, int K) {
    __shared__ _Float16 Asb[128 * 32];
    __shared__ _Float16 Bsb[128 * 32];
    int t = threadIdx.x;
    int w = t >> 6, l = t & 63;
    int wr = w >> 1, wc = w & 1;
    int row0 = blockIdx.y * 128, col0 = blockIdx.x * 128;

    f32x4 acc[4][4];
    #pragma unroll
    for (int m = 0; m < 4; ++m)
        #pragma unroll
        for (int n = 0; n < 4; ++n)
            acc[m][n] = (f32x4){0.f, 0.f, 0.f, 0.f};

    int srow = l >> 2;
    int scol = (l & 3) * 8;

    for (int k0 = 0; k0 < K; k0 += 32) {
        #pragma unroll
        for (int i = 0; i < 2; ++i) {
            int chunk = w * 2 + i;
            const _Float16* asrc =
                A + (size_t)(row0 + chunk * 16 + srow) * K + k0 + scol;
            __builtin_amdgcn_global_load_lds((const AS1 void*)asrc,
                                             (AS3 void*)(Asb + chunk * 512), 16, 0, 0);
            const _Float16* bsrc =
                BT + (size_t)(col0 + chunk * 16 + srow) * K + k0 + scol;
            __builtin_amdgcn_global_load_lds((const AS1 void*)bsrc,
                                             (AS3 void*)(Bsb + chunk * 512), 16, 0, 0);
        }
        __syncthreads();
        int rsel = l & 15, csel = (l >> 4) * 8;
        half8 a[4], b[4];
        #pragma unroll
        for (int m = 0; m < 4; ++m)
            a[m] = *(const half8*)&Asb[(wr * 64 + m * 16 + rsel) * 32 + csel];
        #pragma unroll
        for (int n = 0; n < 4; ++n)
            b[n] = *(const half8*)&Bsb[(wc * 64 + n * 16 + rsel) * 32 + csel];
        #pragma unroll
        for (int m = 0; m < 4; ++m)
            #pragma unroll
            for (int n = 0; n < 4; ++n)
                acc[m][n] = __builtin_amdgcn_mfma_f32_16x16x32_f16(a[m], b[n], acc[m][n], 0, 0, 0);
        __syncthreads();
    }

    int ocol = l & 15, orow = (l >> 4) * 4;
    #pragma unroll
    for (int m = 0; m < 4; ++m)
        #pragma unroll
        for (int n = 0; n < 4; ++n) {
            size_t base = (size_t)(row0 + wr * 64 + m * 16 + orow) * N
                        + col0 + wc * 64 + n * 16 + ocol;
            #pragma unroll
            for (int j = 0; j < 4; ++j)
                C[base + (size_t)j * N] = (_Float16)acc[m][n][j];
        }
}

// ---------------------------------------------------------------------------
// kvagg_fused: per (bn, jseg): on-the-fly DPFP(k) + v, MFMA accumulate
// ---------------------------------------------------------------------------
__global__ __launch_bounds__(512) void kvagg_fused(const _Float16* __restrict__ qkv,
                                                   float* __restrict__ kvp,
                                                   float* __restrict__ zp) {
    __shared__ _Float16 x2s[128 * 64];    // 16 KB
    __shared__ _Float16 vTs[64 * 64];     //  8 KB
    __shared__ _Float16 pkTs[384 * 64];   // 48 KB
    const int t = threadIdx.x;
    const int w = t >> 6, l = t & 63;
    const int bn = blockIdx.x;
    const int jseg = blockIdx.y;
    const int b = bn >> 4, nh = bn & 15;

    f32x4 acc[4][3];
    #pragma unroll
    for (int mf = 0; mf < 4; ++mf)
        #pragma unroll
        for (int nf = 0; nf < 3; ++nf)
            acc[mf][nf] = (f32x4){0.f, 0.f, 0.f, 0.f};
    float zacc[3] = {0.f, 0.f, 0.f};

    const int sc = t & 63;
    const int so = t >> 6;

    #pragma unroll 1
    for (int ch = 0; ch < 4; ++ch) {
        int j0 = jseg * 256 + ch * 64;
        _Float16 kx[8], vx[8];
        #pragma unroll
        for (int e = 0; e < 8; ++e) {
            size_t rb = (size_t)((j0 + so * 8 + e) * 2 + b) * 3072 + nh * 64 + sc;
            kx[e] = qkv[rb + 1024];
            vx[e] = qkv[rb + 2048];
        }
        half8 xlo, xhi, vv;
        #pragma unroll
        for (int e = 0; e < 8; ++e) {
            float kf = (float)kx[e];
            xlo[e] = (_Float16)fmaxf(kf, 0.f);
            xhi[e] = (_Float16)fmaxf(-kf, 0.f);
            vv[e] = vx[e];
        }
        if (ch) __syncthreads();
        *(half8*)&x2s[IDX(sc, so)] = xlo;
        *(half8*)&x2s[IDX(sc + 64, so)] = xhi;
        *(half8*)&vTs[IDX(sc, so)] = vv;
        __syncthreads();
        {
            const int o = t & 7;
            const int fb = t >> 3;
            #pragma unroll
            for (int it = 0; it < 6; ++it) {
                int f = it * 64 + fb;
                int fm = f & 127;
                int r = (f >> 7) + 1;
                int fm2 = (fm - r) & 127;
                half8 pa = *(const half8*)&x2s[IDX(fm, o)];
                half8 pb = *(const half8*)&x2s[IDX(fm2, o)];
                *(half8*)&pkTs[IDX(f, o)] = pa * pb;
            }
        }
        __syncthreads();
        #pragma unroll
        for (int ks = 0; ks < 2; ++ks) {
            half8 a[4], bq[3];
            int oo = ks * 4 + (l >> 4);
            #pragma unroll
            for (int mf = 0; mf < 4; ++mf) {
                int dr = mf * 16 + (l & 15);
                a[mf] = *(const half8*)&vTs[IDX(dr, oo)];
            }
            #pragma unroll
            for (int nf = 0; nf < 3; ++nf) {
                int fr = w * 48 + nf * 16 + (l & 15);
                bq[nf] = *(const half8*)&pkTs[IDX(fr, oo)];
                #pragma unroll
                for (int e = 0; e < 8; ++e) zacc[nf] += (float)bq[nf][e];
            }
            #pragma unroll
            for (int mf = 0; mf < 4; ++mf)
                #pragma unroll
                for (int nf = 0; nf < 3; ++nf)
                    acc[mf][nf] = __builtin_amdgcn_mfma_f32_16x16x32_f16(
                        a[mf], bq[nf], acc[mf][nf], 0, 0, 0);
        }
    }

    #pragma unroll
    for (int nf = 0; nf < 3; ++nf) {
        float v = zacc[nf];
        v += __shfl_xor(v, 16, 64);
        v += __shfl_xor(v, 32, 64);
        if (l < 16)
            zp[(size_t)(jseg * 32 + bn) * FEAT + w * 48 + nf * 16 + l] = v;
    }
    float* outp = kvp + (size_t)(jseg * 32 + bn) * 64 * FEAT;
    int orow = (l >> 4) * 4, ocol = l & 15;
    #pragma unroll
    for (int mf = 0; mf < 4; ++mf)
        #pragma unroll
        for (int nf = 0; nf < 3; ++nf) {
            int fcol = w * 48 + nf * 16 + ocol;
            #pragma unroll
            for (int j = 0; j < 4; ++j)
                outp[(size_t)(mf * 16 + orow + j) * FEAT + fcol] = acc[mf][nf][j];
        }
}

// ---------------------------------------------------------------------------
// Reduce 8 j-segments -> kvaggT f16 [32][64][384], z f32 [32][384]
// ---------------------------------------------------------------------------
__global__ __launch_bounds__(256) void reduceA(const float* __restrict__ kvp,
                                               const float* __restrict__ zp,
                                               _Float16* __restrict__ kvaggT,
                                               float* __restrict__ z) {
    const int NKV = 32 * 64 * FEAT;  // 786432
    int idx = blockIdx.x * 256 + threadIdx.x;
    if (idx < NKV) {
        float s = 0.f;
        #pragma unroll
        for (int c = 0; c < 8; ++c) s += kvp[(size_t)c * NKV + idx];
        kvaggT[idx] = (_Float16)s;
    } else if (idx < NKV + 32 * FEAT) {
        int e = idx - NKV;
        float s = 0.f;
        #pragma unroll
        for (int c = 0; c < 8; ++c) s += zp[c * 32 * FEAT + e];
        z[e] = s;
    }
}

// ---------------------------------------------------------------------------
// pq compute helper (static-index, no spill)
// ---------------------------------------------------------------------------
template <int F0>
__device__ __forceinline__ void pq_half(const float (&qr)[64], _Float16* prow) {
    #pragma unroll
    for (int g8 = 0; g8 < 24; ++g8) {
        half8 o;
        #pragma unroll
        for (int e = 0; e < 8; ++e) {
            const int f = F0 + g8 * 8 + e;
            const int fm = f & 127;
            const int r = (f >> 7) + 1;
            const int fm2 = (fm - r) & 127;
            float a = (fm < 64) ? fmaxf(qr[fm], 0.f) : fmaxf(-qr[fm - 64], 0.f);
            float bb = (fm2 < 64) ? fmaxf(qr[fm2], 0.f) : fmaxf(-qr[fm2 - 64], 0.f);
            o[e] = (_Float16)(a * bb);
        }
        *(half8*)&prow[F0 + g8 * 8] = o;
    }
}

// ---------------------------------------------------------------------------
// Fused attn: pq in LDS + barrier-free MFMA K-loop; fused den; f16 out.
// ---------------------------------------------------------------------------
#define PQ_STR 392
__global__ __launch_bounds__(256) void attn_fused(const _Float16* __restrict__ qkv,
                                                  const _Float16* __restrict__ kvaggT,
                                                  const float* __restrict__ z,
                                                  _Float16* __restrict__ av) {
    __shared__ _Float16 pq_lds[128 * PQ_STR];
    __shared__ _Float16 B_lds[64 * PQ_STR];
    __shared__ float z_lds[FEAT];
    __shared__ float den_lds[128];
    int t = threadIdx.x;
    int w = t >> 6, l = t & 63;
    int iblk = blockIdx.x;
    int bn = blockIdx.y;
    int b = bn >> 4, nh = bn & 15;

    {
        const _Float16* Bg = kvaggT + (size_t)bn * 64 * FEAT;
        #pragma unroll
        for (int s = 0; s < 12; ++s) {
            int idx8 = t + 256 * s;
            half8 vv = *(const half8*)&Bg[idx8 * 8];
            int row = idx8 / 48, col8 = idx8 - row * 48;
            *(half8*)&B_lds[row * PQ_STR + col8 * 8] = vv;
        }
    }
    for (int e = t; e < FEAT; e += 256) z_lds[e] = z[(size_t)bn * FEAT + e];

    {
        int il = t & 127;
        int ig = iblk * 128 + il;
        const _Float16* qrow = qkv + ((size_t)ig * 2 + b) * 3072 + nh * 64;
        float qr[64];
        #pragma unroll
        for (int e2 = 0; e2 < 8; ++e2) {
            half8 vv = *(const half8*)&qrow[e2 * 8];
            #pragma unroll
            for (int e = 0; e < 8; ++e) qr[e2 * 8 + e] = (float)vv[e];
        }
        _Float16* prow = &pq_lds[il * PQ_STR];
        if (t < 128) pq_half<0>(qr, prow);
        else         pq_half<192>(qr, prow);
    }
    __syncthreads();

    f32x4 acc[2][4];
    #pragma unroll
    for (int m = 0; m < 2; ++m)
        #pragma unroll
        for (int n = 0; n < 4; ++n)
            acc[m][n] = (f32x4){0.f, 0.f, 0.f, 0.f};
    float denacc[2] = {0.f, 0.f};
    int rsel = l & 15, csel = (l >> 4) * 8;

    #pragma unroll
    for (int k0 = 0; k0 < FEAT; k0 += 32) {
        half8 a[2], bfr[4];
        #pragma unroll
        for (int m = 0; m < 2; ++m)
            a[m] = *(const half8*)&pq_lds[(w * 32 + m * 16 + rsel) * PQ_STR + k0 + csel];
        #pragma unroll
        for (int n = 0; n < 4; ++n)
            bfr[n] = *(const half8*)&B_lds[(n * 16 + rsel) * PQ_STR + k0 + csel];
        #pragma unroll
        for (int m = 0; m < 2; ++m)
            #pragma unroll
            for (int e = 0; e < 8; ++e)
                denacc[m] += (float)a[m][e] * z_lds[k0 + csel + e];
        #pragma unroll
        for (int m = 0; m < 2; ++m)
            #pragma unroll
            for (int n = 0; n < 4; ++n)
                acc[m][n] = __builtin_amdgcn_mfma_f32_16x16x32_f16(a[m], bfr[n], acc[m][n], 0, 0, 0);
    }

    #pragma unroll
    for (int m = 0; m < 2; ++m) {
        float v = denacc[m];
        v += __shfl_xor(v, 16, 64);
        v += __shfl_xor(v, 32, 64);
        if (l < 16) den_lds[w * 32 + m * 16 + l] = v;
    }
    __syncthreads();

    int orow = (l >> 4) * 4, ocol = l & 15;
    #pragma unroll
    for (int m = 0; m < 2; ++m)
        #pragma unroll
        for (int n = 0; n < 4; ++n)
            #pragma unroll
            for (int j = 0; j < 4; ++j) {
                int row = w * 32 + m * 16 + orow + j;
                float den = den_lds[row] * SCALE + EPS;
                float val = acc[m][n][j] * SCALE / den;
                int i = iblk * 128 + row;
                av[((size_t)i * 2 + b) * 1024 + nh * 64 + n * 16 + ocol] = (_Float16)val;
            }
}

// ---------------------------------------------------------------------------
// Residual + LayerNorm, vectorized (float4 / half4).
// ---------------------------------------------------------------------------
__global__ __launch_bounds__(256) void ln_kernel(const float* __restrict__ h,
                                                 const _Float16* __restrict__ attn_out,
                                                 const float* __restrict__ gamma,
                                                 const float* __restrict__ beta,
                                                 float* __restrict__ out) {
    int r = blockIdx.x;
    int t = threadIdx.x;
    const float4 hv = ((const float4*)(h + (size_t)r * 1024))[t];
    const half4 a4 = ((const half4*)(attn_out + (size_t)r * 1024))[t];
    float x[4] = {hv.x + (float)a4[0], hv.y + (float)a4[1],
                  hv.z + (float)a4[2], hv.w + (float)a4[3]};
    float sum = x[0] + x[1] + x[2] + x[3];
    float sq = x[0]*x[0] + x[1]*x[1] + x[2]*x[2] + x[3]*x[3];
    #pragma unroll
    for (int off = 32; off >= 1; off >>= 1) {
        sum += __shfl_xor(sum, off, 64);
        sq += __shfl_xor(sq, off, 64);
    }
    __shared__ float ssum[4], ssq[4];
    int wl = t >> 6, lane = t & 63;
    if (lane == 0) { ssum[wl] = sum; ssq[wl] = sq; }
    __syncthreads();
    sum = ssum[0] + ssum[1] + ssum[2] + ssum[3];
    sq = ssq[0] + ssq[1] + ssq[2] + ssq[3];
    float mu = sum * (1.f / 1024.f);
    float var = sq * (1.f / 1024.f) - mu * mu;
    float rs = rsqrtf(var + 1e-5f);
    const float4 g4 = ((const float4*)gamma)[t];
    const float4 b4 = ((const float4*)beta)[t];
    float4 o;
    o.x = (x[0] - mu) * rs * g4.x + b4.x;
    o.y = (x[1] - mu) * rs * g4.y + b4.y;
    o.z = (x[2] - mu) * rs * g4.z + b4.z;
    o.w = (x[3] - mu) * rs * g4.w + b4.w;
    ((float4*)(out + (size_t)r * 1024))[t] = o;
}

// ---------------------------------------------------------------------------
extern "C" void kernel_launch(void* const* d_in, const int* in_sizes, int n_in,
                              void* d_out, int out_size, void* d_ws, size_t ws_size,
                              hipStream_t stream) {
    const float* h     = (const float*)d_in[0];
    const float* Wq    = (const float*)d_in[1];
    const float* Wkv   = (const float*)d_in[2];
    const float* Wo    = (const float*)d_in[3];
    const float* gamma = (const float*)d_in[4];
    const float* beta  = (const float*)d_in[5];
    float* out = (float*)d_out;
    _Float16* u = (_Float16*)d_ws;

    // Workspace (2-byte units), ~69 MB
    _Float16* h_h    = u;                       // 8 MB; later av (f16)
    _Float16* WqkvT  = u + 4194304;             // 6 MB
    _Float16* WoT    = u + 7340032;             // 2 MB
    _Float16* qkv    = u + 8388608;             // 24 MB; later attn_out f16
    float*    kvp    = (float*)(u + 20971520);  // 25.2 MB
    float*    zp     = (float*)(u + 33554432);  // 0.4 MB
    _Float16* kvaggT = u + 33751040;            // 1.5 MB
    float*    z      = (float*)(u + 34537472);  // 48 KB
    _Float16* av         = h_h;
    _Float16* attn_out_h = qkv;

    dim3 blk(256);
    // 0) merged prep: conv h->f16 + weight transposes
    prep_kernel<<<dim3(8192), blk, 0, stream>>>(h, Wq, Wkv, Wo, h_h, WqkvT, WoT);
    // 1) fused qkv projection (2-phase 256x192), grid 16*16=256 (%8==0)
    gemm_f16_8ph<<<dim3(256), dim3(512), 0, stream>>>(h_h, WqkvT, qkv, SB, 3072, DM);
    // 2) fused DPFP(k)+kvagg+z partials over (32 bn x 8 jseg)
    kvagg_fused<<<dim3(32, 8), dim3(512), 0, stream>>>(qkv, kvp, zp);
    // 3) reduce partials
    reduceA<<<dim3(3120), blk, 0, stream>>>(kvp, zp, kvaggT, z);
    // 4) fused featq + attn GEMM (all 32 bn)
    attn_fused<<<dim3(16, 32), blk, 0, stream>>>(qkv, kvaggT, z, av);
    // 5) output projection (f16 out)
    gemm_f16<<<dim3(8, 32), blk, 0, stream>>>(av, WoT, attn_out_h, SB, 1024, DM);
    // 6) residual + LayerNorm
    ln_kernel<<<dim3(SB), blk, 0, stream>>>(h, attn_out_h, gamma, beta, out);
}

// Round 10
// 108.398 us; speedup vs baseline: 9.6595x; 1.0277x over previous
//
#include <hip/hip_runtime.h>
#include <math.h>

// Problem constants
#define NH 16
#define DM 1024
#define FEAT 384          // 2*64*3
#define SB 4096           // S*B
#define SEQ 2048

static constexpr float SCALE = 0.125f;  // 1/sqrt(64)
static constexpr float EPS = 1e-5f;

typedef __attribute__((ext_vector_type(8))) _Float16 half8;
typedef __attribute__((ext_vector_type(4))) _Float16 half4;
typedef __attribute__((ext_vector_type(4))) float f32x4;

#define AS1 __attribute__((address_space(1)))
#define AS3 __attribute__((address_space(3)))

// swizzled 16B-cell index into a [rows][64-half] LDS tile (row = 128B = 8 cells)
#define IDX(r, o) ((((r) << 6)) + ((((o) ^ ((r) & 7))) << 3))

// ---------------------------------------------------------------------------
// prep: merged f32->f16 conversion of h + weight transposes.
// ---------------------------------------------------------------------------
__global__ __launch_bounds__(256) void prep_kernel(const float* __restrict__ h,
                                                   const float* __restrict__ Wq,
                                                   const float* __restrict__ Wkv,
                                                   const float* __restrict__ Wo,
                                                   _Float16* __restrict__ h_h,
                                                   _Float16* __restrict__ WqkvT,
                                                   _Float16* __restrict__ WoT) {
    __shared__ _Float16 tile[32][33];
    int bid = blockIdx.x, t = threadIdx.x;
    if (bid < 4096) {
        int i = bid * 256 + t;
        const float4 v = ((const float4*)h)[i];
        half4 o = {(_Float16)v.x, (_Float16)v.y, (_Float16)v.z, (_Float16)v.w};
        ((half4*)h_h)[i] = o;
        return;
    }
    const float* src;
    _Float16* dst;
    int N, col0, n0, k0;
    if (bid < 7168) {
        int b2 = bid - 4096;
        n0 = (b2 % 96) * 32; k0 = (b2 / 96) * 32;
        if (n0 < 1024) { src = Wq; N = 1024; col0 = n0; }
        else           { src = Wkv; N = 2048; col0 = n0 - 1024; }
        dst = WqkvT;
    } else {
        int b3 = bid - 7168;
        n0 = (b3 & 31) * 32; k0 = (b3 >> 5) * 32;
        src = Wo; N = 1024; col0 = n0; dst = WoT;
    }
    int tx = t & 31, ty = t >> 5;
    #pragma unroll
    for (int i = 0; i < 4; ++i)
        tile[ty + i * 8][tx] = (_Float16)src[(size_t)(k0 + ty + i * 8) * N + col0 + tx];
    __syncthreads();
    #pragma unroll
    for (int i = 0; i < 4; ++i)
        dst[(size_t)(n0 + ty + i * 8) * 1024 + k0 + tx] = tile[tx][ty + i * 8];
}

// ---------------------------------------------------------------------------
// 256x192 2-phase f16 MFMA GEMM (qkv projection). See R9 ledger comments.
// ---------------------------------------------------------------------------
template <int MH>
__device__ __forceinline__ void mfma_all(f32x4 (&acc)[8][3], half8 (&a)[4][2],
                                         half8 (&bv)[3][2]) {
    #pragma unroll
    for (int mf = 0; mf < 4; ++mf)
        #pragma unroll
        for (int nf = 0; nf < 3; ++nf)
            #pragma unroll
            for (int ks = 0; ks < 2; ++ks)
                acc[MH * 4 + mf][nf] = __builtin_amdgcn_mfma_f32_16x16x32_f16(
                    a[mf][ks], bv[nf][ks], acc[MH * 4 + mf][nf], 0, 0, 0);
}

__global__ __launch_bounds__(512) void gemm_f16_8ph(const _Float16* __restrict__ A,
                                                    const _Float16* __restrict__ BT,
                                                    _Float16* __restrict__ C,
                                                    int M, int N, int K) {
    __shared__ _Float16 smem[57344];   // 2 x 28672 halfs = 112 KiB
    const int t = threadIdx.x;
    const int w = t >> 6, l = t & 63;
    const int wr = w >> 2, wc = w & 3;
    const int NT = K >> 6;
    const int NU = K >> 4;

    int nwg = gridDim.x;
    int cpx = nwg >> 3;
    int bid = blockIdx.x;
    int swz = (bid & 7) * cpx + (bid >> 3);
    int ntile = N / 192;
    int row0 = (swz / ntile) << 8;
    int col0 = (swz % ntile) * 192;

    f32x4 acc[8][3];
    #pragma unroll
    for (int m = 0; m < 8; ++m)
        #pragma unroll
        for (int n = 0; n < 3; ++n)
            acc[m][n] = (f32x4){0.f, 0.f, 0.f, 0.f};

    const int lr = l >> 3;
    const int lc8 = ((l & 7) ^ lr) * 8;

    auto STAGE = [&](int s) {
        if (s >= NU) return;
        int tau = s >> 2, u = s & 3;
        int kk = tau << 6;
        int bufo = (tau & 1) * 28672;
        if (u == 0) {
            #pragma unroll
            for (int i = 0; i < 2; ++i) {
                int chunk = w * 2 + i;
                const _Float16* src = BT + (size_t)(col0 + chunk * 8 + lr) * K + kk + lc8;
                __builtin_amdgcn_global_load_lds((const AS1 void*)src,
                    (AS3 void*)(smem + bufo + 16384 + chunk * 512), 16, 0, 0);
            }
        } else if (u == 1) {
            const _Float16* src = BT + (size_t)(col0 + 128 + w * 8 + lr) * K + kk + lc8;
            __builtin_amdgcn_global_load_lds((const AS1 void*)src,
                (AS3 void*)(smem + bufo + 24576 + w * 512), 16, 0, 0);
        } else {
            int rbase = (u == 3) ? 128 : 0;
            int lbase = (u == 3) ? 8192 : 0;
            #pragma unroll
            for (int i = 0; i < 2; ++i) {
                int chunk = w * 2 + i;
                const _Float16* src = A + (size_t)(row0 + rbase + chunk * 8 + lr) * K + kk + lc8;
                __builtin_amdgcn_global_load_lds((const AS1 void*)src,
                    (AS3 void*)(smem + bufo + lbase + chunk * 512), 16, 0, 0);
            }
        }
    };

    half8 a[4][2], bv[3][2];
    auto LDA = [&](int mh, int bufo) {
        #pragma unroll
        for (int mf = 0; mf < 4; ++mf) {
            int r = wr * 128 + (mh * 4 + mf) * 16 + (l & 15);
            #pragma unroll
            for (int ks = 0; ks < 2; ++ks) {
                int c16 = (ks * 4 + (l >> 4)) ^ (r & 7);
                a[mf][ks] = *(const half8*)&smem[bufo + r * 64 + c16 * 8];
            }
        }
    };
    auto LDB = [&](int bufo) {
        #pragma unroll
        for (int nf = 0; nf < 3; ++nf) {
            int r = wc * 48 + nf * 16 + (l & 15);
            #pragma unroll
            for (int ks = 0; ks < 2; ++ks) {
                int c16 = (ks * 4 + (l >> 4)) ^ (r & 7);
                bv[nf][ks] = *(const half8*)&smem[bufo + 16384 + r * 64 + c16 * 8];
            }
        }
    };

    STAGE(0); STAGE(1);
    STAGE(2); STAGE(3);
    STAGE(4); STAGE(5);
    asm volatile("s_waitcnt vmcnt(3)" ::: "memory");
    __builtin_amdgcn_s_barrier();

    #pragma unroll 1
    for (int ti = 0; ti < NT; ++ti) {
        const int bufo = (ti & 1) * 28672;
        const int sb = (ti + 1) << 2;
        LDA(0, bufo); LDB(bufo);
        STAGE(sb + 2); STAGE(sb + 3);
        __builtin_amdgcn_sched_barrier(0);
        __builtin_amdgcn_s_barrier();
        asm volatile("s_waitcnt lgkmcnt(0)" ::: "memory");
        __builtin_amdgcn_sched_barrier(0);
        __builtin_amdgcn_s_setprio(1);
        mfma_all<0>(acc, a, bv);
        __builtin_amdgcn_s_setprio(0);
        __builtin_amdgcn_sched_barrier(0);
        __builtin_amdgcn_s_barrier();
        LDA(1, bufo);
        STAGE(sb + 4); STAGE(sb + 5);
        __builtin_amdgcn_sched_barrier(0);
        __builtin_amdgcn_s_barrier();
        asm volatile("s_waitcnt lgkmcnt(0)" ::: "memory");
        __builtin_amdgcn_sched_barrier(0);
        __builtin_amdgcn_s_setprio(1);
        mfma_all<1>(acc, a, bv);
        __builtin_amdgcn_s_setprio(0);
        __builtin_amdgcn_sched_barrier(0);
        if (ti < NT - 2) asm volatile("s_waitcnt vmcnt(3)" ::: "memory");
        else             asm volatile("s_waitcnt vmcnt(0)" ::: "memory");
        __builtin_amdgcn_s_barrier();
    }

    int ocol = l & 15, orow4 = (l >> 4) * 4;
    #pragma unroll
    for (int mf = 0; mf < 8; ++mf)
        #pragma unroll
        for (int nf = 0; nf < 3; ++nf) {
            size_t base = (size_t)(row0 + wr * 128 + mf * 16 + orow4) * N
                        + col0 + wc * 48 + nf * 16 + ocol;
            #pragma unroll
            for (int j = 0; j < 4; ++j)
                C[base + (size_t)j * N] = (_Float16)acc[mf][nf][j];
        }
}

// ---------------------------------------------------------------------------
// f16 MFMA GEMM: 128x128 tile, m97 structure (Wo projection).
// ---------------------------------------------------------------------------
__global__ __launch_bounds__(256) void gemm_f16(const _Float16* __restrict__ A,
                                                const _Float16* __restrict__ BT,
                                                _Float16* __restrict__ C,
                                                int M, int N, int K) {
    __shared__ _Float16 Asb[128 * 32];
    __shared__ _Float16 Bsb[128 * 32];
    int t = threadIdx.x;
    int w = t >> 6, l = t & 63;
    int wr = w >> 1, wc = w & 1;
    int row0 = blockIdx.y * 128, col0 = blockIdx.x * 128;

    f32x4 acc[4][4];
    #pragma unroll
    for (int m = 0; m < 4; ++m)
        #pragma unroll
        for (int n = 0; n < 4; ++n)
            acc[m][n] = (f32x4){0.f, 0.f, 0.f, 0.f};

    int srow = l >> 2;
    int scol = (l & 3) * 8;

    for (int k0 = 0; k0 < K; k0 += 32) {
        #pragma unroll
        for (int i = 0; i < 2; ++i) {
            int chunk = w * 2 + i;
            const _Float16* asrc =
                A + (size_t)(row0 + chunk * 16 + srow) * K + k0 + scol;
            __builtin_amdgcn_global_load_lds((const AS1 void*)asrc,
                                             (AS3 void*)(Asb + chunk * 512), 16, 0, 0);
            const _Float16* bsrc =
                BT + (size_t)(col0 + chunk * 16 + srow) * K + k0 + scol;
            __builtin_amdgcn_global_load_lds((const AS1 void*)bsrc,
                                             (AS3 void*)(Bsb + chunk * 512), 16, 0, 0);
        }
        __syncthreads();
        int rsel = l & 15, csel = (l >> 4) * 8;
        half8 a[4], b[4];
        #pragma unroll
        for (int m = 0; m < 4; ++m)
            a[m] = *(const half8*)&Asb[(wr * 64 + m * 16 + rsel) * 32 + csel];
        #pragma unroll
        for (int n = 0; n < 4; ++n)
            b[n] = *(const half8*)&Bsb[(wc * 64 + n * 16 + rsel) * 32 + csel];
        #pragma unroll
        for (int m = 0; m < 4; ++m)
            #pragma unroll
            for (int n = 0; n < 4; ++n)
                acc[m][n] = __builtin_amdgcn_mfma_f32_16x16x32_f16(a[m], b[n], acc[m][n], 0, 0, 0);
        __syncthreads();
    }

    int ocol = l & 15, orow = (l >> 4) * 4;
    #pragma unroll
    for (int m = 0; m < 4; ++m)
        #pragma unroll
        for (int n = 0; n < 4; ++n) {
            size_t base = (size_t)(row0 + wr * 64 + m * 16 + orow) * N
                        + col0 + wc * 64 + n * 16 + ocol;
            #pragma unroll
            for (int j = 0; j < 4; ++j)
                C[base + (size_t)j * N] = (_Float16)acc[m][n][j];
        }
}

// ---------------------------------------------------------------------------
// kvagg_fused: per (bn, jseg): on-the-fly DPFP(k) + v, MFMA accumulate
// ---------------------------------------------------------------------------
__global__ __launch_bounds__(512) void kvagg_fused(const _Float16* __restrict__ qkv,
                                                   float* __restrict__ kvp,
                                                   float* __restrict__ zp) {
    __shared__ _Float16 x2s[128 * 64];    // 16 KB
    __shared__ _Float16 vTs[64 * 64];     //  8 KB
    __shared__ _Float16 pkTs[384 * 64];   // 48 KB
    const int t = threadIdx.x;
    const int w = t >> 6, l = t & 63;
    const int bn = blockIdx.x;
    const int jseg = blockIdx.y;
    const int b = bn >> 4, nh = bn & 15;

    f32x4 acc[4][3];
    #pragma unroll
    for (int mf = 0; mf < 4; ++mf)
        #pragma unroll
        for (int nf = 0; nf < 3; ++nf)
            acc[mf][nf] = (f32x4){0.f, 0.f, 0.f, 0.f};
    float zacc[3] = {0.f, 0.f, 0.f};

    const int sc = t & 63;
    const int so = t >> 6;

    #pragma unroll 1
    for (int ch = 0; ch < 4; ++ch) {
        int j0 = jseg * 256 + ch * 64;
        _Float16 kx[8], vx[8];
        #pragma unroll
        for (int e = 0; e < 8; ++e) {
            size_t rb = (size_t)((j0 + so * 8 + e) * 2 + b) * 3072 + nh * 64 + sc;
            kx[e] = qkv[rb + 1024];
            vx[e] = qkv[rb + 2048];
        }
        half8 xlo, xhi, vv;
        #pragma unroll
        for (int e = 0; e < 8; ++e) {
            float kf = (float)kx[e];
            xlo[e] = (_Float16)fmaxf(kf, 0.f);
            xhi[e] = (_Float16)fmaxf(-kf, 0.f);
            vv[e] = vx[e];
        }
        if (ch) __syncthreads();
        *(half8*)&x2s[IDX(sc, so)] = xlo;
        *(half8*)&x2s[IDX(sc + 64, so)] = xhi;
        *(half8*)&vTs[IDX(sc, so)] = vv;
        __syncthreads();
        {
            const int o = t & 7;
            const int fb = t >> 3;
            #pragma unroll
            for (int it = 0; it < 6; ++it) {
                int f = it * 64 + fb;
                int fm = f & 127;
                int r = (f >> 7) + 1;
                int fm2 = (fm - r) & 127;
                half8 pa = *(const half8*)&x2s[IDX(fm, o)];
                half8 pb = *(const half8*)&x2s[IDX(fm2, o)];
                *(half8*)&pkTs[IDX(f, o)] = pa * pb;
            }
        }
        __syncthreads();
        #pragma unroll
        for (int ks = 0; ks < 2; ++ks) {
            half8 a[4], bq[3];
            int oo = ks * 4 + (l >> 4);
            #pragma unroll
            for (int mf = 0; mf < 4; ++mf) {
                int dr = mf * 16 + (l & 15);
                a[mf] = *(const half8*)&vTs[IDX(dr, oo)];
            }
            #pragma unroll
            for (int nf = 0; nf < 3; ++nf) {
                int fr = w * 48 + nf * 16 + (l & 15);
                bq[nf] = *(const half8*)&pkTs[IDX(fr, oo)];
                #pragma unroll
                for (int e = 0; e < 8; ++e) zacc[nf] += (float)bq[nf][e];
            }
            #pragma unroll
            for (int mf = 0; mf < 4; ++mf)
                #pragma unroll
                for (int nf = 0; nf < 3; ++nf)
                    acc[mf][nf] = __builtin_amdgcn_mfma_f32_16x16x32_f16(
                        a[mf], bq[nf], acc[mf][nf], 0, 0, 0);
        }
    }

    #pragma unroll
    for (int nf = 0; nf < 3; ++nf) {
        float v = zacc[nf];
        v += __shfl_xor(v, 16, 64);
        v += __shfl_xor(v, 32, 64);
        if (l < 16)
            zp[(size_t)(jseg * 32 + bn) * FEAT + w * 48 + nf * 16 + l] = v;
    }
    float* outp = kvp + (size_t)(jseg * 32 + bn) * 64 * FEAT;
    int orow = (l >> 4) * 4, ocol = l & 15;
    #pragma unroll
    for (int mf = 0; mf < 4; ++mf)
        #pragma unroll
        for (int nf = 0; nf < 3; ++nf) {
            int fcol = w * 48 + nf * 16 + ocol;
            #pragma unroll
            for (int j = 0; j < 4; ++j)
                outp[(size_t)(mf * 16 + orow + j) * FEAT + fcol] = acc[mf][nf][j];
        }
}

// ---------------------------------------------------------------------------
// Reduce 8 j-segments -> kvaggT f16 [32][64][384], z f32 [32][384]
// ---------------------------------------------------------------------------
__global__ __launch_bounds__(256) void reduceA(const float* __restrict__ kvp,
                                               const float* __restrict__ zp,
                                               _Float16* __restrict__ kvaggT,
                                               float* __restrict__ z) {
    const int NKV = 32 * 64 * FEAT;  // 786432
    int idx = blockIdx.x * 256 + threadIdx.x;
    if (idx < NKV) {
        float s = 0.f;
        #pragma unroll
        for (int c = 0; c < 8; ++c) s += kvp[(size_t)c * NKV + idx];
        kvaggT[idx] = (_Float16)s;
    } else if (idx < NKV + 32 * FEAT) {
        int e = idx - NKV;
        float s = 0.f;
        #pragma unroll
        for (int c = 0; c < 8; ++c) s += zp[c * 32 * FEAT + e];
        z[e] = s;
    }
}

// ---------------------------------------------------------------------------
// attn_fused v2: 64 rows x 64 d per block, grid (32, 32), 256 threads.
// pq held in REGISTERS via rotated-row trick: lane loads y[j] = x2[(csel+j)&127]
// (16 aligned LDS half8 reads; csel runtime is fine for LDS), then
// pq[f] = y[(ks*32+e)&127] * y[(ks*32+e-r)&127] with r=(ks>>2)+1 — ALL STATIC.
// LDS: x2e 19 KB + B 48 KB (swizzled) + z + den = ~70 KB -> 2 blocks/CU.
// One barrier after staging; 48-MFMA loop barrier-free.
// ---------------------------------------------------------------------------
#define X2STR 152   // 128 + 24 right-extension (max csel=24), halves
__global__ __launch_bounds__(256) void attn_fused(const _Float16* __restrict__ qkv,
                                                  const _Float16* __restrict__ kvaggT,
                                                  const float* __restrict__ z,
                                                  _Float16* __restrict__ av) {
    __shared__ _Float16 x2e[64 * X2STR];   // 19,456 B
    __shared__ _Float16 B_lds[64 * FEAT];  // 49,152 B, 16B-cell swizzle
    __shared__ float z_lds[FEAT];
    __shared__ float den_lds[64];
    const int t = threadIdx.x;
    const int w = t >> 6, l = t & 63;
    const int iblk = blockIdx.x;   // 0..31 (64 rows each)
    const int bn = blockIdx.y;     // 0..31
    const int b = bn >> 4, nh = bn & 15;

    // stage B (64x384) swizzled: 3072 cells, 256 thr x 12
    {
        const _Float16* Bg = kvaggT + (size_t)bn * 64 * FEAT;
        #pragma unroll
        for (int s = 0; s < 12; ++s) {
            int idx8 = t + 256 * s;
            int row = idx8 / 48, c16 = idx8 - row * 48;
            half8 vv = *(const half8*)&Bg[row * FEAT + c16 * 8];
            *(half8*)&B_lds[row * FEAT + ((c16 ^ (row & 7)) << 3)] = vv;
        }
    }
    for (int e = t; e < FEAT; e += 256) z_lds[e] = z[(size_t)bn * FEAT + e];

    // stage x2e: row = t>>2 (64 rows), c0 = (t&3)*16
    {
        int row = t >> 2, c0 = (t & 3) * 16;
        const _Float16* qrow = qkv + (size_t)((iblk * 64 + row) * 2 + b) * 3072 + nh * 64;
        half8 q0 = *(const half8*)&qrow[c0];
        half8 q1 = *(const half8*)&qrow[c0 + 8];
        half8 lo0, lo1, hi0, hi1;
        #pragma unroll
        for (int e = 0; e < 8; ++e) {
            float f0 = (float)q0[e], f1 = (float)q1[e];
            lo0[e] = (_Float16)fmaxf(f0, 0.f);
            lo1[e] = (_Float16)fmaxf(f1, 0.f);
            hi0[e] = (_Float16)fmaxf(-f0, 0.f);
            hi1[e] = (_Float16)fmaxf(-f1, 0.f);
        }
        _Float16* xr = &x2e[row * X2STR];
        *(half8*)&xr[c0] = lo0;
        *(half8*)&xr[c0 + 8] = lo1;
        *(half8*)&xr[64 + c0] = hi0;
        *(half8*)&xr[64 + c0 + 8] = hi1;
        // right-extension: cols 128..151 = x2[0..23] (all in lo part)
        if (c0 == 0) { *(half8*)&xr[128] = lo0; *(half8*)&xr[136] = lo1; }
        if (c0 == 16) { *(half8*)&xr[144] = lo0; }
    }
    __syncthreads();

    // build rotated y (16 aligned LDS reads) then 12 a-frags, all static idx
    const int rloc16 = l & 15;
    const int csel = (l >> 4) * 8;
    const int lrow = w * 16 + rloc16;
    half8 y8[16];
    {
        const _Float16* xr = &x2e[lrow * X2STR + csel];
        #pragma unroll
        for (int j = 0; j < 16; ++j)
            y8[j] = *(const half8*)&xr[j * 8];
    }
    half8 afr[12];
    #pragma unroll
    for (int ks = 0; ks < 12; ++ks) {
        const int r = (ks >> 2) + 1;
        #pragma unroll
        for (int e = 0; e < 8; ++e) {
            const int j1 = ((ks & 3) * 32 + e) & 127;
            const int j2 = ((ks & 3) * 32 + e - r) & 127;
            afr[ks][e] = y8[j1 >> 3][j1 & 7] * y8[j2 >> 3][j2 & 7];
        }
    }

    // MFMA loop (barrier-free) + fused den
    f32x4 acc[4];
    #pragma unroll
    for (int n = 0; n < 4; ++n) acc[n] = (f32x4){0.f, 0.f, 0.f, 0.f};
    float den = 0.f;
    #pragma unroll
    for (int ks = 0; ks < 12; ++ks) {
        #pragma unroll
        for (int e = 0; e < 8; ++e)
            den += (float)afr[ks][e] * z_lds[ks * 32 + csel + e];
        #pragma unroll
        for (int nf = 0; nf < 4; ++nf) {
            int row = nf * 16 + rloc16;
            int c16 = (ks * 4 + (l >> 4)) ^ (row & 7);
            half8 bfr = *(const half8*)&B_lds[row * FEAT + (c16 << 3)];
            acc[nf] = __builtin_amdgcn_mfma_f32_16x16x32_f16(afr[ks], bfr, acc[nf], 0, 0, 0);
        }
    }

    den += __shfl_xor(den, 16, 64);
    den += __shfl_xor(den, 32, 64);
    if (l < 16) den_lds[w * 16 + l] = den;
    __syncthreads();

    #pragma unroll
    for (int nf = 0; nf < 4; ++nf)
        #pragma unroll
        for (int j = 0; j < 4; ++j) {
            int rl = w * 16 + (l >> 4) * 4 + j;
            float dv = den_lds[rl] * SCALE + EPS;
            float val = acc[nf][j] * SCALE / dv;
            int i = iblk * 64 + rl;
            av[((size_t)i * 2 + b) * 1024 + nh * 64 + nf * 16 + (l & 15)] = (_Float16)val;
        }
}

// ---------------------------------------------------------------------------
// Residual + LayerNorm, vectorized (float4 / half4).
// ---------------------------------------------------------------------------
__global__ __launch_bounds__(256) void ln_kernel(const float* __restrict__ h,
                                                 const _Float16* __restrict__ attn_out,
                                                 const float* __restrict__ gamma,
                                                 const float* __restrict__ beta,
                                                 float* __restrict__ out) {
    int r = blockIdx.x;
    int t = threadIdx.x;
    const float4 hv = ((const float4*)(h + (size_t)r * 1024))[t];
    const half4 a4 = ((const half4*)(attn_out + (size_t)r * 1024))[t];
    float x[4] = {hv.x + (float)a4[0], hv.y + (float)a4[1],
                  hv.z + (float)a4[2], hv.w + (float)a4[3]};
    float sum = x[0] + x[1] + x[2] + x[3];
    float sq = x[0]*x[0] + x[1]*x[1] + x[2]*x[2] + x[3]*x[3];
    #pragma unroll
    for (int off = 32; off >= 1; off >>= 1) {
        sum += __shfl_xor(sum, off, 64);
        sq += __shfl_xor(sq, off, 64);
    }
    __shared__ float ssum[4], ssq[4];
    int wl = t >> 6, lane = t & 63;
    if (lane == 0) { ssum[wl] = sum; ssq[wl] = sq; }
    __syncthreads();
    sum = ssum[0] + ssum[1] + ssum[2] + ssum[3];
    sq = ssq[0] + ssq[1] + ssq[2] + ssq[3];
    float mu = sum * (1.f / 1024.f);
    float var = sq * (1.f / 1024.f) - mu * mu;
    float rs = rsqrtf(var + 1e-5f);
    const float4 g4 = ((const float4*)gamma)[t];
    const float4 b4 = ((const float4*)beta)[t];
    float4 o;
    o.x = (x[0] - mu) * rs * g4.x + b4.x;
    o.y = (x[1] - mu) * rs * g4.y + b4.y;
    o.z = (x[2] - mu) * rs * g4.z + b4.z;
    o.w = (x[3] - mu) * rs * g4.w + b4.w;
    ((float4*)(out + (size_t)r * 1024))[t] = o;
}

// ---------------------------------------------------------------------------
extern "C" void kernel_launch(void* const* d_in, const int* in_sizes, int n_in,
                              void* d_out, int out_size, void* d_ws, size_t ws_size,
                              hipStream_t stream) {
    const float* h     = (const float*)d_in[0];
    const float* Wq    = (const float*)d_in[1];
    const float* Wkv   = (const float*)d_in[2];
    const float* Wo    = (const float*)d_in[3];
    const float* gamma = (const float*)d_in[4];
    const float* beta  = (const float*)d_in[5];
    float* out = (float*)d_out;
    _Float16* u = (_Float16*)d_ws;

    // Workspace (2-byte units), ~69 MB
    _Float16* h_h    = u;                       // 8 MB; later av (f16)
    _Float16* WqkvT  = u + 4194304;             // 6 MB
    _Float16* WoT    = u + 7340032;             // 2 MB
    _Float16* qkv    = u + 8388608;             // 24 MB; later attn_out f16
    float*    kvp    = (float*)(u + 20971520);  // 25.2 MB
    float*    zp     = (float*)(u + 33554432);  // 0.4 MB
    _Float16* kvaggT = u + 33751040;            // 1.5 MB
    float*    z      = (float*)(u + 34537472);  // 48 KB
    _Float16* av         = h_h;
    _Float16* attn_out_h = qkv;

    dim3 blk(256);
    // 0) merged prep: conv h->f16 + weight transposes
    prep_kernel<<<dim3(8192), blk, 0, stream>>>(h, Wq, Wkv, Wo, h_h, WqkvT, WoT);
    // 1) fused qkv projection (2-phase 256x192), grid 16*16=256 (%8==0)
    gemm_f16_8ph<<<dim3(256), dim3(512), 0, stream>>>(h_h, WqkvT, qkv, SB, 3072, DM);
    // 2) fused DPFP(k)+kvagg+z partials over (32 bn x 8 jseg)
    kvagg_fused<<<dim3(32, 8), dim3(512), 0, stream>>>(qkv, kvp, zp);
    // 3) reduce partials
    reduceA<<<dim3(3120), blk, 0, stream>>>(kvp, zp, kvaggT, z);
    // 4) fused featq + attn GEMM, pq-in-registers (grid 32 iblk x 32 bn)
    attn_fused<<<dim3(32, 32), blk, 0, stream>>>(qkv, kvaggT, z, av);
    // 5) output projection (f16 out)
    gemm_f16<<<dim3(8, 32), blk, 0, stream>>>(av, WoT, attn_out_h, SB, 1024, DM);
    // 6) residual + LayerNorm
    ln_kernel<<<dim3(SB), blk, 0, stream>>>(h, attn_out_h, gamma, beta, out);
}

// Round 11
// 99.334 us; speedup vs baseline: 10.5409x; 1.0913x over previous
//
#include <hip/hip_runtime.h>
#include <math.h>

// Problem constants
#define NH 16
#define DM 1024
#define FEAT 384          // 2*64*3
#define SB 4096           // S*B
#define SEQ 2048

static constexpr float SCALE = 0.125f;  // 1/sqrt(64)
static constexpr float EPS = 1e-5f;

typedef __attribute__((ext_vector_type(8))) _Float16 half8;
typedef __attribute__((ext_vector_type(4))) _Float16 half4;
typedef __attribute__((ext_vector_type(4))) float f32x4;

#define AS1 __attribute__((address_space(1)))
#define AS3 __attribute__((address_space(3)))

// swizzled 16B-cell index into a [rows][64-half] LDS tile (row = 128B = 8 cells)
#define IDX(r, o) ((((r) << 6)) + ((((o) ^ ((r) & 7))) << 3))

// ---------------------------------------------------------------------------
// prep: merged f32->f16 conversion of h + weight transposes.
// ---------------------------------------------------------------------------
__global__ __launch_bounds__(256) void prep_kernel(const float* __restrict__ h,
                                                   const float* __restrict__ Wq,
                                                   const float* __restrict__ Wkv,
                                                   const float* __restrict__ Wo,
                                                   _Float16* __restrict__ h_h,
                                                   _Float16* __restrict__ WqkvT,
                                                   _Float16* __restrict__ WoT) {
    __shared__ _Float16 tile[32][33];
    int bid = blockIdx.x, t = threadIdx.x;
    if (bid < 4096) {
        int i = bid * 256 + t;
        const float4 v = ((const float4*)h)[i];
        half4 o = {(_Float16)v.x, (_Float16)v.y, (_Float16)v.z, (_Float16)v.w};
        ((half4*)h_h)[i] = o;
        return;
    }
    const float* src;
    _Float16* dst;
    int N, col0, n0, k0;
    if (bid < 7168) {
        int b2 = bid - 4096;
        n0 = (b2 % 96) * 32; k0 = (b2 / 96) * 32;
        if (n0 < 1024) { src = Wq; N = 1024; col0 = n0; }
        else           { src = Wkv; N = 2048; col0 = n0 - 1024; }
        dst = WqkvT;
    } else {
        int b3 = bid - 7168;
        n0 = (b3 & 31) * 32; k0 = (b3 >> 5) * 32;
        src = Wo; N = 1024; col0 = n0; dst = WoT;
    }
    int tx = t & 31, ty = t >> 5;
    #pragma unroll
    for (int i = 0; i < 4; ++i)
        tile[ty + i * 8][tx] = (_Float16)src[(size_t)(k0 + ty + i * 8) * N + col0 + tx];
    __syncthreads();
    #pragma unroll
    for (int i = 0; i < 4; ++i)
        dst[(size_t)(n0 + ty + i * 8) * 1024 + k0 + tx] = tile[tx][ty + i * 8];
}

// ---------------------------------------------------------------------------
// 256x192 2-phase f16 MFMA GEMM (qkv projection). See R9 ledger comments.
// ---------------------------------------------------------------------------
template <int MH>
__device__ __forceinline__ void mfma_all(f32x4 (&acc)[8][3], half8 (&a)[4][2],
                                         half8 (&bv)[3][2]) {
    #pragma unroll
    for (int mf = 0; mf < 4; ++mf)
        #pragma unroll
        for (int nf = 0; nf < 3; ++nf)
            #pragma unroll
            for (int ks = 0; ks < 2; ++ks)
                acc[MH * 4 + mf][nf] = __builtin_amdgcn_mfma_f32_16x16x32_f16(
                    a[mf][ks], bv[nf][ks], acc[MH * 4 + mf][nf], 0, 0, 0);
}

__global__ __launch_bounds__(512) void gemm_f16_8ph(const _Float16* __restrict__ A,
                                                    const _Float16* __restrict__ BT,
                                                    _Float16* __restrict__ C,
                                                    int M, int N, int K) {
    __shared__ _Float16 smem[57344];   // 2 x 28672 halfs = 112 KiB
    const int t = threadIdx.x;
    const int w = t >> 6, l = t & 63;
    const int wr = w >> 2, wc = w & 3;
    const int NT = K >> 6;
    const int NU = K >> 4;

    int nwg = gridDim.x;
    int cpx = nwg >> 3;
    int bid = blockIdx.x;
    int swz = (bid & 7) * cpx + (bid >> 3);
    int ntile = N / 192;
    int row0 = (swz / ntile) << 8;
    int col0 = (swz % ntile) * 192;

    f32x4 acc[8][3];
    #pragma unroll
    for (int m = 0; m < 8; ++m)
        #pragma unroll
        for (int n = 0; n < 3; ++n)
            acc[m][n] = (f32x4){0.f, 0.f, 0.f, 0.f};

    const int lr = l >> 3;
    const int lc8 = ((l & 7) ^ lr) * 8;

    auto STAGE = [&](int s) {
        if (s >= NU) return;
        int tau = s >> 2, u = s & 3;
        int kk = tau << 6;
        int bufo = (tau & 1) * 28672;
        if (u == 0) {
            #pragma unroll
            for (int i = 0; i < 2; ++i) {
                int chunk = w * 2 + i;
                const _Float16* src = BT + (size_t)(col0 + chunk * 8 + lr) * K + kk + lc8;
                __builtin_amdgcn_global_load_lds((const AS1 void*)src,
                    (AS3 void*)(smem + bufo + 16384 + chunk * 512), 16, 0, 0);
            }
        } else if (u == 1) {
            const _Float16* src = BT + (size_t)(col0 + 128 + w * 8 + lr) * K + kk + lc8;
            __builtin_amdgcn_global_load_lds((const AS1 void*)src,
                (AS3 void*)(smem + bufo + 24576 + w * 512), 16, 0, 0);
        } else {
            int rbase = (u == 3) ? 128 : 0;
            int lbase = (u == 3) ? 8192 : 0;
            #pragma unroll
            for (int i = 0; i < 2; ++i) {
                int chunk = w * 2 + i;
                const _Float16* src = A + (size_t)(row0 + rbase + chunk * 8 + lr) * K + kk + lc8;
                __builtin_amdgcn_global_load_lds((const AS1 void*)src,
                    (AS3 void*)(smem + bufo + lbase + chunk * 512), 16, 0, 0);
            }
        }
    };

    half8 a[4][2], bv[3][2];
    auto LDA = [&](int mh, int bufo) {
        #pragma unroll
        for (int mf = 0; mf < 4; ++mf) {
            int r = wr * 128 + (mh * 4 + mf) * 16 + (l & 15);
            #pragma unroll
            for (int ks = 0; ks < 2; ++ks) {
                int c16 = (ks * 4 + (l >> 4)) ^ (r & 7);
                a[mf][ks] = *(const half8*)&smem[bufo + r * 64 + c16 * 8];
            }
        }
    };
    auto LDB = [&](int bufo) {
        #pragma unroll
        for (int nf = 0; nf < 3; ++nf) {
            int r = wc * 48 + nf * 16 + (l & 15);
            #pragma unroll
            for (int ks = 0; ks < 2; ++ks) {
                int c16 = (ks * 4 + (l >> 4)) ^ (r & 7);
                bv[nf][ks] = *(const half8*)&smem[bufo + 16384 + r * 64 + c16 * 8];
            }
        }
    };

    STAGE(0); STAGE(1);
    STAGE(2); STAGE(3);
    STAGE(4); STAGE(5);
    asm volatile("s_waitcnt vmcnt(3)" ::: "memory");
    __builtin_amdgcn_s_barrier();

    #pragma unroll 1
    for (int ti = 0; ti < NT; ++ti) {
        const int bufo = (ti & 1) * 28672;
        const int sb = (ti + 1) << 2;
        LDA(0, bufo); LDB(bufo);
        STAGE(sb + 2); STAGE(sb + 3);
        __builtin_amdgcn_sched_barrier(0);
        __builtin_amdgcn_s_barrier();
        asm volatile("s_waitcnt lgkmcnt(0)" ::: "memory");
        __builtin_amdgcn_sched_barrier(0);
        __builtin_amdgcn_s_setprio(1);
        mfma_all<0>(acc, a, bv);
        __builtin_amdgcn_s_setprio(0);
        __builtin_amdgcn_sched_barrier(0);
        __builtin_amdgcn_s_barrier();
        LDA(1, bufo);
        STAGE(sb + 4); STAGE(sb + 5);
        __builtin_amdgcn_sched_barrier(0);
        __builtin_amdgcn_s_barrier();
        asm volatile("s_waitcnt lgkmcnt(0)" ::: "memory");
        __builtin_amdgcn_sched_barrier(0);
        __builtin_amdgcn_s_setprio(1);
        mfma_all<1>(acc, a, bv);
        __builtin_amdgcn_s_setprio(0);
        __builtin_amdgcn_sched_barrier(0);
        if (ti < NT - 2) asm volatile("s_waitcnt vmcnt(3)" ::: "memory");
        else             asm volatile("s_waitcnt vmcnt(0)" ::: "memory");
        __builtin_amdgcn_s_barrier();
    }

    int ocol = l & 15, orow4 = (l >> 4) * 4;
    #pragma unroll
    for (int mf = 0; mf < 8; ++mf)
        #pragma unroll
        for (int nf = 0; nf < 3; ++nf) {
            size_t base = (size_t)(row0 + wr * 128 + mf * 16 + orow4) * N
                        + col0 + wc * 48 + nf * 16 + ocol;
            #pragma unroll
            for (int j = 0; j < 4; ++j)
                C[base + (size_t)j * N] = (_Float16)acc[mf][nf][j];
        }
}

// ---------------------------------------------------------------------------
// gemm_wo: 128x128 tile, BK=64, 4 waves (2x2), 3-buffer LDS (96 KB),
// single phase per K-tile, counted vmcnt(8). (Wo projection)
// Ledger: stage unit = 8 loads/thread/tile (A4+B4). Prologue stages t0,t1
// (16 in flight) -> vmcnt(8) proves t0. Phase ti: ds_read buf[ti%3],
// STAGE(ti+2)->buf[(ti+2)%3] (never the read buffer), lgkm0, 32 MFMA,
// boundary vmcnt(8) (leaves ti+2's 8 in flight, proves ti+1); last two
// boundaries vmcnt(0). One barrier per K-tile. Requires K/64 >= 3.
// ---------------------------------------------------------------------------
__global__ __launch_bounds__(256) void gemm_wo(const _Float16* __restrict__ A,
                                               const _Float16* __restrict__ BT,
                                               _Float16* __restrict__ C,
                                               int M, int N, int K) {
    __shared__ _Float16 smem[3 * 16384];   // 3 bufs x (A 8K + B 8K halves) = 96 KB
    const int t = threadIdx.x;
    const int w = t >> 6, l = t & 63;
    const int wr = w >> 1, wc = w & 1;
    const int NT = K >> 6;
    int row0 = blockIdx.y * 128, col0 = blockIdx.x * 128;

    f32x4 acc[4][4];
    #pragma unroll
    for (int m = 0; m < 4; ++m)
        #pragma unroll
        for (int n = 0; n < 4; ++n)
            acc[m][n] = (f32x4){0.f, 0.f, 0.f, 0.f};

    const int lr = l >> 3;
    const int lc8 = ((l & 7) ^ lr) * 8;

    auto STAGE = [&](int ti) {
        if (ti >= NT) return;
        int kk = ti << 6;
        int bufo = (ti % 3) * 16384;
        #pragma unroll
        for (int i = 0; i < 4; ++i) {
            int chunk = w * 4 + i;   // 0..15, 8 rows each
            const _Float16* asrc = A + (size_t)(row0 + chunk * 8 + lr) * K + kk + lc8;
            __builtin_amdgcn_global_load_lds((const AS1 void*)asrc,
                (AS3 void*)(smem + bufo + chunk * 512), 16, 0, 0);
            const _Float16* bsrc = BT + (size_t)(col0 + chunk * 8 + lr) * K + kk + lc8;
            __builtin_amdgcn_global_load_lds((const AS1 void*)bsrc,
                (AS3 void*)(smem + bufo + 8192 + chunk * 512), 16, 0, 0);
        }
    };

    STAGE(0); STAGE(1);
    asm volatile("s_waitcnt vmcnt(8)" ::: "memory");
    __builtin_amdgcn_s_barrier();

    #pragma unroll 1
    for (int ti = 0; ti < NT; ++ti) {
        const int bufo = (ti % 3) * 16384;
        half8 a[4][2], bv[4][2];
        #pragma unroll
        for (int mf = 0; mf < 4; ++mf) {
            int r = wr * 64 + mf * 16 + (l & 15);
            #pragma unroll
            for (int ks = 0; ks < 2; ++ks) {
                int c16 = (ks * 4 + (l >> 4)) ^ (r & 7);
                a[mf][ks] = *(const half8*)&smem[bufo + r * 64 + c16 * 8];
            }
        }
        #pragma unroll
        for (int nf = 0; nf < 4; ++nf) {
            int r = wc * 64 + nf * 16 + (l & 15);
            #pragma unroll
            for (int ks = 0; ks < 2; ++ks) {
                int c16 = (ks * 4 + (l >> 4)) ^ (r & 7);
                bv[nf][ks] = *(const half8*)&smem[bufo + 8192 + r * 64 + c16 * 8];
            }
        }
        STAGE(ti + 2);
        __builtin_amdgcn_sched_barrier(0);
        asm volatile("s_waitcnt lgkmcnt(0)" ::: "memory");
        __builtin_amdgcn_sched_barrier(0);
        __builtin_amdgcn_s_setprio(1);
        #pragma unroll
        for (int mf = 0; mf < 4; ++mf)
            #pragma unroll
            for (int nf = 0; nf < 4; ++nf)
                #pragma unroll
                for (int ks = 0; ks < 2; ++ks)
                    acc[mf][nf] = __builtin_amdgcn_mfma_f32_16x16x32_f16(
                        a[mf][ks], bv[nf][ks], acc[mf][nf], 0, 0, 0);
        __builtin_amdgcn_s_setprio(0);
        __builtin_amdgcn_sched_barrier(0);
        if (ti < NT - 2) asm volatile("s_waitcnt vmcnt(8)" ::: "memory");
        else             asm volatile("s_waitcnt vmcnt(0)" ::: "memory");
        __builtin_amdgcn_s_barrier();
    }

    int ocol = l & 15, orow = (l >> 4) * 4;
    #pragma unroll
    for (int mf = 0; mf < 4; ++mf)
        #pragma unroll
        for (int nf = 0; nf < 4; ++nf) {
            size_t base = (size_t)(row0 + wr * 64 + mf * 16 + orow) * N
                        + col0 + wc * 64 + nf * 16 + ocol;
            #pragma unroll
            for (int j = 0; j < 4; ++j)
                C[base + (size_t)j * N] = (_Float16)acc[mf][nf][j];
        }
}

// ---------------------------------------------------------------------------
// kvagg_fused: per (bn, jseg): on-the-fly DPFP(k) + v, MFMA accumulate.
// Partials now written as f16 (halves HBM traffic; values O(1-10)).
// ---------------------------------------------------------------------------
__global__ __launch_bounds__(512) void kvagg_fused(const _Float16* __restrict__ qkv,
                                                   _Float16* __restrict__ kvp,
                                                   float* __restrict__ zp) {
    __shared__ _Float16 x2s[128 * 64];    // 16 KB
    __shared__ _Float16 vTs[64 * 64];     //  8 KB
    __shared__ _Float16 pkTs[384 * 64];   // 48 KB
    const int t = threadIdx.x;
    const int w = t >> 6, l = t & 63;
    const int bn = blockIdx.x;
    const int jseg = blockIdx.y;
    const int b = bn >> 4, nh = bn & 15;

    f32x4 acc[4][3];
    #pragma unroll
    for (int mf = 0; mf < 4; ++mf)
        #pragma unroll
        for (int nf = 0; nf < 3; ++nf)
            acc[mf][nf] = (f32x4){0.f, 0.f, 0.f, 0.f};
    float zacc[3] = {0.f, 0.f, 0.f};

    const int sc = t & 63;
    const int so = t >> 6;

    #pragma unroll 1
    for (int ch = 0; ch < 4; ++ch) {
        int j0 = jseg * 256 + ch * 64;
        _Float16 kx[8], vx[8];
        #pragma unroll
        for (int e = 0; e < 8; ++e) {
            size_t rb = (size_t)((j0 + so * 8 + e) * 2 + b) * 3072 + nh * 64 + sc;
            kx[e] = qkv[rb + 1024];
            vx[e] = qkv[rb + 2048];
        }
        half8 xlo, xhi, vv;
        #pragma unroll
        for (int e = 0; e < 8; ++e) {
            float kf = (float)kx[e];
            xlo[e] = (_Float16)fmaxf(kf, 0.f);
            xhi[e] = (_Float16)fmaxf(-kf, 0.f);
            vv[e] = vx[e];
        }
        if (ch) __syncthreads();
        *(half8*)&x2s[IDX(sc, so)] = xlo;
        *(half8*)&x2s[IDX(sc + 64, so)] = xhi;
        *(half8*)&vTs[IDX(sc, so)] = vv;
        __syncthreads();
        {
            const int o = t & 7;
            const int fb = t >> 3;
            #pragma unroll
            for (int it = 0; it < 6; ++it) {
                int f = it * 64 + fb;
                int fm = f & 127;
                int r = (f >> 7) + 1;
                int fm2 = (fm - r) & 127;
                half8 pa = *(const half8*)&x2s[IDX(fm, o)];
                half8 pb = *(const half8*)&x2s[IDX(fm2, o)];
                *(half8*)&pkTs[IDX(f, o)] = pa * pb;
            }
        }
        __syncthreads();
        #pragma unroll
        for (int ks = 0; ks < 2; ++ks) {
            half8 a[4], bq[3];
            int oo = ks * 4 + (l >> 4);
            #pragma unroll
            for (int mf = 0; mf < 4; ++mf) {
                int dr = mf * 16 + (l & 15);
                a[mf] = *(const half8*)&vTs[IDX(dr, oo)];
            }
            #pragma unroll
            for (int nf = 0; nf < 3; ++nf) {
                int fr = w * 48 + nf * 16 + (l & 15);
                bq[nf] = *(const half8*)&pkTs[IDX(fr, oo)];
                #pragma unroll
                for (int e = 0; e < 8; ++e) zacc[nf] += (float)bq[nf][e];
            }
            #pragma unroll
            for (int mf = 0; mf < 4; ++mf)
                #pragma unroll
                for (int nf = 0; nf < 3; ++nf)
                    acc[mf][nf] = __builtin_amdgcn_mfma_f32_16x16x32_f16(
                        a[mf], bq[nf], acc[mf][nf], 0, 0, 0);
        }
    }

    #pragma unroll
    for (int nf = 0; nf < 3; ++nf) {
        float v = zacc[nf];
        v += __shfl_xor(v, 16, 64);
        v += __shfl_xor(v, 32, 64);
        if (l < 16)
            zp[(size_t)(jseg * 32 + bn) * FEAT + w * 48 + nf * 16 + l] = v;
    }
    _Float16* outp = kvp + (size_t)(jseg * 32 + bn) * 64 * FEAT;
    int orow = (l >> 4) * 4, ocol = l & 15;
    #pragma unroll
    for (int mf = 0; mf < 4; ++mf)
        #pragma unroll
        for (int nf = 0; nf < 3; ++nf) {
            int fcol = w * 48 + nf * 16 + ocol;
            #pragma unroll
            for (int j = 0; j < 4; ++j)
                outp[(size_t)(mf * 16 + orow + j) * FEAT + fcol] = (_Float16)acc[mf][nf][j];
        }
}

// ---------------------------------------------------------------------------
// Reduce 8 j-segments (f16 partials) -> kvaggT f16 [32][64][384], z f32
// ---------------------------------------------------------------------------
__global__ __launch_bounds__(256) void reduceA(const _Float16* __restrict__ kvp,
                                               const float* __restrict__ zp,
                                               _Float16* __restrict__ kvaggT,
                                               float* __restrict__ z) {
    const int NKV = 32 * 64 * FEAT;  // 786432
    int idx = blockIdx.x * 256 + threadIdx.x;
    if (idx < NKV) {
        float s = 0.f;
        #pragma unroll
        for (int c = 0; c < 8; ++c) s += (float)kvp[(size_t)c * NKV + idx];
        kvaggT[idx] = (_Float16)s;
    } else if (idx < NKV + 32 * FEAT) {
        int e = idx - NKV;
        float s = 0.f;
        #pragma unroll
        for (int c = 0; c < 8; ++c) s += zp[c * 32 * FEAT + e];
        z[e] = s;
    }
}

// ---------------------------------------------------------------------------
// attn_fused v2: 64 rows x 64 d per block, grid (32, 32), 256 threads.
// pq in registers via rotated-row trick (see R10 comments).
// ---------------------------------------------------------------------------
#define X2STR 152   // 128 + 24 right-extension (max csel=24), halves
__global__ __launch_bounds__(256) void attn_fused(const _Float16* __restrict__ qkv,
                                                  const _Float16* __restrict__ kvaggT,
                                                  const float* __restrict__ z,
                                                  _Float16* __restrict__ av) {
    __shared__ _Float16 x2e[64 * X2STR];   // 19,456 B
    __shared__ _Float16 B_lds[64 * FEAT];  // 49,152 B, 16B-cell swizzle
    __shared__ float z_lds[FEAT];
    __shared__ float den_lds[64];
    const int t = threadIdx.x;
    const int w = t >> 6, l = t & 63;
    const int iblk = blockIdx.x;
    const int bn = blockIdx.y;
    const int b = bn >> 4, nh = bn & 15;

    {
        const _Float16* Bg = kvaggT + (size_t)bn * 64 * FEAT;
        #pragma unroll
        for (int s = 0; s < 12; ++s) {
            int idx8 = t + 256 * s;
            int row = idx8 / 48, c16 = idx8 - row * 48;
            half8 vv = *(const half8*)&Bg[row * FEAT + c16 * 8];
            *(half8*)&B_lds[row * FEAT + ((c16 ^ (row & 7)) << 3)] = vv;
        }
    }
    for (int e = t; e < FEAT; e += 256) z_lds[e] = z[(size_t)bn * FEAT + e];

    {
        int row = t >> 2, c0 = (t & 3) * 16;
        const _Float16* qrow = qkv + (size_t)((iblk * 64 + row) * 2 + b) * 3072 + nh * 64;
        half8 q0 = *(const half8*)&qrow[c0];
        half8 q1 = *(const half8*)&qrow[c0 + 8];
        half8 lo0, lo1, hi0, hi1;
        #pragma unroll
        for (int e = 0; e < 8; ++e) {
            float f0 = (float)q0[e], f1 = (float)q1[e];
            lo0[e] = (_Float16)fmaxf(f0, 0.f);
            lo1[e] = (_Float16)fmaxf(f1, 0.f);
            hi0[e] = (_Float16)fmaxf(-f0, 0.f);
            hi1[e] = (_Float16)fmaxf(-f1, 0.f);
        }
        _Float16* xr = &x2e[row * X2STR];
        *(half8*)&xr[c0] = lo0;
        *(half8*)&xr[c0 + 8] = lo1;
        *(half8*)&xr[64 + c0] = hi0;
        *(half8*)&xr[64 + c0 + 8] = hi1;
        if (c0 == 0) { *(half8*)&xr[128] = lo0; *(half8*)&xr[136] = lo1; }
        if (c0 == 16) { *(half8*)&xr[144] = lo0; }
    }
    __syncthreads();

    const int rloc16 = l & 15;
    const int csel = (l >> 4) * 8;
    const int lrow = w * 16 + rloc16;
    half8 y8[16];
    {
        const _Float16* xr = &x2e[lrow * X2STR + csel];
        #pragma unroll
        for (int j = 0; j < 16; ++j)
            y8[j] = *(const half8*)&xr[j * 8];
    }
    half8 afr[12];
    #pragma unroll
    for (int ks = 0; ks < 12; ++ks) {
        const int r = (ks >> 2) + 1;
        #pragma unroll
        for (int e = 0; e < 8; ++e) {
            const int j1 = ((ks & 3) * 32 + e) & 127;
            const int j2 = ((ks & 3) * 32 + e - r) & 127;
            afr[ks][e] = y8[j1 >> 3][j1 & 7] * y8[j2 >> 3][j2 & 7];
        }
    }

    f32x4 acc[4];
    #pragma unroll
    for (int n = 0; n < 4; ++n) acc[n] = (f32x4){0.f, 0.f, 0.f, 0.f};
    float den = 0.f;
    #pragma unroll
    for (int ks = 0; ks < 12; ++ks) {
        #pragma unroll
        for (int e = 0; e < 8; ++e)
            den += (float)afr[ks][e] * z_lds[ks * 32 + csel + e];
        #pragma unroll
        for (int nf = 0; nf < 4; ++nf) {
            int row = nf * 16 + rloc16;
            int c16 = (ks * 4 + (l >> 4)) ^ (row & 7);
            half8 bfr = *(const half8*)&B_lds[row * FEAT + (c16 << 3)];
            acc[nf] = __builtin_amdgcn_mfma_f32_16x16x32_f16(afr[ks], bfr, acc[nf], 0, 0, 0);
        }
    }

    den += __shfl_xor(den, 16, 64);
    den += __shfl_xor(den, 32, 64);
    if (l < 16) den_lds[w * 16 + l] = den;
    __syncthreads();

    #pragma unroll
    for (int nf = 0; nf < 4; ++nf)
        #pragma unroll
        for (int j = 0; j < 4; ++j) {
            int rl = w * 16 + (l >> 4) * 4 + j;
            float dv = den_lds[rl] * SCALE + EPS;
            float val = acc[nf][j] * SCALE / dv;
            int i = iblk * 64 + rl;
            av[((size_t)i * 2 + b) * 1024 + nh * 64 + nf * 16 + (l & 15)] = (_Float16)val;
        }
}

// ---------------------------------------------------------------------------
// Residual + LayerNorm, vectorized (float4 / half4).
// ---------------------------------------------------------------------------
__global__ __launch_bounds__(256) void ln_kernel(const float* __restrict__ h,
                                                 const _Float16* __restrict__ attn_out,
                                                 const float* __restrict__ gamma,
                                                 const float* __restrict__ beta,
                                                 float* __restrict__ out) {
    int r = blockIdx.x;
    int t = threadIdx.x;
    const float4 hv = ((const float4*)(h + (size_t)r * 1024))[t];
    const half4 a4 = ((const half4*)(attn_out + (size_t)r * 1024))[t];
    float x[4] = {hv.x + (float)a4[0], hv.y + (float)a4[1],
                  hv.z + (float)a4[2], hv.w + (float)a4[3]};
    float sum = x[0] + x[1] + x[2] + x[3];
    float sq = x[0]*x[0] + x[1]*x[1] + x[2]*x[2] + x[3]*x[3];
    #pragma unroll
    for (int off = 32; off >= 1; off >>= 1) {
        sum += __shfl_xor(sum, off, 64);
        sq += __shfl_xor(sq, off, 64);
    }
    __shared__ float ssum[4], ssq[4];
    int wl = t >> 6, lane = t & 63;
    if (lane == 0) { ssum[wl] = sum; ssq[wl] = sq; }
    __syncthreads();
    sum = ssum[0] + ssum[1] + ssum[2] + ssum[3];
    sq = ssq[0] + ssq[1] + ssq[2] + ssq[3];
    float mu = sum * (1.f / 1024.f);
    float var = sq * (1.f / 1024.f) - mu * mu;
    float rs = rsqrtf(var + 1e-5f);
    const float4 g4 = ((const float4*)gamma)[t];
    const float4 b4 = ((const float4*)beta)[t];
    float4 o;
    o.x = (x[0] - mu) * rs * g4.x + b4.x;
    o.y = (x[1] - mu) * rs * g4.y + b4.y;
    o.z = (x[2] - mu) * rs * g4.z + b4.z;
    o.w = (x[3] - mu) * rs * g4.w + b4.w;
    ((float4*)(out + (size_t)r * 1024))[t] = o;
}

// ---------------------------------------------------------------------------
extern "C" void kernel_launch(void* const* d_in, const int* in_sizes, int n_in,
                              void* d_out, int out_size, void* d_ws, size_t ws_size,
                              hipStream_t stream) {
    const float* h     = (const float*)d_in[0];
    const float* Wq    = (const float*)d_in[1];
    const float* Wkv   = (const float*)d_in[2];
    const float* Wo    = (const float*)d_in[3];
    const float* gamma = (const float*)d_in[4];
    const float* beta  = (const float*)d_in[5];
    float* out = (float*)d_out;
    _Float16* u = (_Float16*)d_ws;

    // Workspace (2-byte units)
    _Float16* h_h    = u;                       // 8 MB; later av (f16)
    _Float16* WqkvT  = u + 4194304;             // 6 MB
    _Float16* WoT    = u + 7340032;             // 2 MB
    _Float16* qkv    = u + 8388608;             // 24 MB; later attn_out f16
    _Float16* kvp    = u + 20971520;            // f16 partials, 12.6 MB
    float*    zp     = (float*)(u + 33554432);  // 0.4 MB
    _Float16* kvaggT = u + 33751040;            // 1.5 MB
    float*    z      = (float*)(u + 34537472);  // 48 KB
    _Float16* av         = h_h;
    _Float16* attn_out_h = qkv;

    dim3 blk(256);
    // 0) merged prep: conv h->f16 + weight transposes
    prep_kernel<<<dim3(8192), blk, 0, stream>>>(h, Wq, Wkv, Wo, h_h, WqkvT, WoT);
    // 1) fused qkv projection (2-phase 256x192), grid 16*16=256 (%8==0)
    gemm_f16_8ph<<<dim3(256), dim3(512), 0, stream>>>(h_h, WqkvT, qkv, SB, 3072, DM);
    // 2) fused DPFP(k)+kvagg+z partials over (32 bn x 8 jseg)
    kvagg_fused<<<dim3(32, 8), dim3(512), 0, stream>>>(qkv, kvp, zp);
    // 3) reduce partials
    reduceA<<<dim3(3120), blk, 0, stream>>>(kvp, zp, kvaggT, z);
    // 4) fused featq + attn GEMM, pq-in-registers (grid 32 iblk x 32 bn)
    attn_fused<<<dim3(32, 32), blk, 0, stream>>>(qkv, kvaggT, z, av);
    // 5) output projection: 3-buffer counted-vmcnt kernel, grid (8, 32)
    gemm_wo<<<dim3(8, 32), blk, 0, stream>>>(av, WoT, attn_out_h, SB, 1024, DM);
    // 6) residual + LayerNorm
    ln_kernel<<<dim3(SB), blk, 0, stream>>>(h, attn_out_h, gamma, beta, out);
}

// Round 12
// 97.955 us; speedup vs baseline: 10.6893x; 1.0141x over previous
//
#include <hip/hip_runtime.h>
#include <math.h>

// Problem constants
#define NH 16
#define DM 1024
#define FEAT 384          // 2*64*3
#define SB 4096           // S*B
#define SEQ 2048

static constexpr float SCALE = 0.125f;  // 1/sqrt(64)
static constexpr float EPS = 1e-5f;

typedef __attribute__((ext_vector_type(8))) _Float16 half8;
typedef __attribute__((ext_vector_type(4))) _Float16 half4;
typedef __attribute__((ext_vector_type(4))) float f32x4;

#define AS1 __attribute__((address_space(1)))
#define AS3 __attribute__((address_space(3)))

// swizzled 16B-cell index into a [rows][64-half] LDS tile (row = 128B = 8 cells)
#define IDX(r, o) ((((r) << 6)) + ((((o) ^ ((r) & 7))) << 3))

// ---------------------------------------------------------------------------
// prep: merged f32->f16 conversion of h + weight transposes.
// ---------------------------------------------------------------------------
__global__ __launch_bounds__(256) void prep_kernel(const float* __restrict__ h,
                                                   const float* __restrict__ Wq,
                                                   const float* __restrict__ Wkv,
                                                   const float* __restrict__ Wo,
                                                   _Float16* __restrict__ h_h,
                                                   _Float16* __restrict__ WqkvT,
                                                   _Float16* __restrict__ WoT) {
    __shared__ _Float16 tile[32][33];
    int bid = blockIdx.x, t = threadIdx.x;
    if (bid < 4096) {
        int i = bid * 256 + t;
        const float4 v = ((const float4*)h)[i];
        half4 o = {(_Float16)v.x, (_Float16)v.y, (_Float16)v.z, (_Float16)v.w};
        ((half4*)h_h)[i] = o;
        return;
    }
    const float* src;
    _Float16* dst;
    int N, col0, n0, k0;
    if (bid < 7168) {
        int b2 = bid - 4096;
        n0 = (b2 % 96) * 32; k0 = (b2 / 96) * 32;
        if (n0 < 1024) { src = Wq; N = 1024; col0 = n0; }
        else           { src = Wkv; N = 2048; col0 = n0 - 1024; }
        dst = WqkvT;
    } else {
        int b3 = bid - 7168;
        n0 = (b3 & 31) * 32; k0 = (b3 >> 5) * 32;
        src = Wo; N = 1024; col0 = n0; dst = WoT;
    }
    int tx = t & 31, ty = t >> 5;
    #pragma unroll
    for (int i = 0; i < 4; ++i)
        tile[ty + i * 8][tx] = (_Float16)src[(size_t)(k0 + ty + i * 8) * N + col0 + tx];
    __syncthreads();
    #pragma unroll
    for (int i = 0; i < 4; ++i)
        dst[(size_t)(n0 + ty + i * 8) * 1024 + k0 + tx] = tile[tx][ty + i * 8];
}

// ---------------------------------------------------------------------------
// qkv GEMM v4: 256x192 tile, BK=64, 512 threads = 8 waves (4M x 2N),
// wave tile 64x96. Single phase / ONE barrier per K-tile, depth-1 prefetch,
// 2-buffer LDS (112 KB). Per tile: issue 7 stage units (ti+1, other buf),
// 20 ds_reads (A 8 + B 12), lgkm0, 48 MFMA, vmcnt(0), barrier.
// Hazards: buf[(ti+1)&1] readers finished before barrier ending ti-1;
// vmcnt(0)+barrier proves ti+1 resident before any wave reads it.
// LDS traffic 160 KB/tile (A-dup 2, B-dup 4) vs 176 in 2x4 arrangement.
// ---------------------------------------------------------------------------
__global__ __launch_bounds__(512) void gemm_qkv(const _Float16* __restrict__ A,
                                                const _Float16* __restrict__ BT,
                                                _Float16* __restrict__ C,
                                                int M, int N, int K) {
    __shared__ _Float16 smem[57344];   // 2 x 28672 halfs = 112 KiB
    const int t = threadIdx.x;
    const int w = t >> 6, l = t & 63;
    const int wr = w >> 1, wc = w & 1;
    const int NT = K >> 6;

    int nwg = gridDim.x;
    int cpx = nwg >> 3;
    int bid = blockIdx.x;
    int swz = (bid & 7) * cpx + (bid >> 3);
    int ntile = N / 192;
    int row0 = (swz / ntile) << 8;
    int col0 = (swz % ntile) * 192;

    f32x4 acc[4][6];
    #pragma unroll
    for (int m = 0; m < 4; ++m)
        #pragma unroll
        for (int n = 0; n < 6; ++n)
            acc[m][n] = (f32x4){0.f, 0.f, 0.f, 0.f};

    const int lr = l >> 3;
    const int lc8 = ((l & 7) ^ lr) * 8;

    // stage entire tile tau (7 units: B 3 + A 4) into buf[tau&1]
    auto STAGE_TILE = [&](int tau) {
        if (tau >= NT) return;
        int kk = tau << 6;
        int bufo = (tau & 1) * 28672;
        #pragma unroll
        for (int i = 0; i < 2; ++i) {
            int chunk = w * 2 + i;
            const _Float16* src = BT + (size_t)(col0 + chunk * 8 + lr) * K + kk + lc8;
            __builtin_amdgcn_global_load_lds((const AS1 void*)src,
                (AS3 void*)(smem + bufo + 16384 + chunk * 512), 16, 0, 0);
        }
        {
            const _Float16* src = BT + (size_t)(col0 + 128 + w * 8 + lr) * K + kk + lc8;
            __builtin_amdgcn_global_load_lds((const AS1 void*)src,
                (AS3 void*)(smem + bufo + 24576 + w * 512), 16, 0, 0);
        }
        #pragma unroll
        for (int i = 0; i < 4; ++i) {
            int chunk = w * 4 + i;   // 0..31, 8 rows each
            const _Float16* src = A + (size_t)(row0 + chunk * 8 + lr) * K + kk + lc8;
            __builtin_amdgcn_global_load_lds((const AS1 void*)src,
                (AS3 void*)(smem + bufo + chunk * 512), 16, 0, 0);
        }
    };

    // Prologue: tile0 resident
    STAGE_TILE(0);
    asm volatile("s_waitcnt vmcnt(0)" ::: "memory");
    __builtin_amdgcn_s_barrier();

    #pragma unroll 1
    for (int ti = 0; ti < NT; ++ti) {
        const int bufo = (ti & 1) * 28672;
        // issue next tile's loads first (other buffer, hazard-free)
        STAGE_TILE(ti + 1);
        // ds_reads: A 8 (wave's 64 rows), B 12 (wave's 96 cols)
        half8 a[4][2], bv[6][2];
        #pragma unroll
        for (int mf = 0; mf < 4; ++mf) {
            int r = wr * 64 + mf * 16 + (l & 15);
            #pragma unroll
            for (int ks = 0; ks < 2; ++ks) {
                int c16 = (ks * 4 + (l >> 4)) ^ (r & 7);
                a[mf][ks] = *(const half8*)&smem[bufo + r * 64 + c16 * 8];
            }
        }
        #pragma unroll
        for (int nf = 0; nf < 6; ++nf) {
            int r = wc * 96 + nf * 16 + (l & 15);
            #pragma unroll
            for (int ks = 0; ks < 2; ++ks) {
                int c16 = (ks * 4 + (l >> 4)) ^ (r & 7);
                bv[nf][ks] = *(const half8*)&smem[bufo + 16384 + r * 64 + c16 * 8];
            }
        }
        __builtin_amdgcn_sched_barrier(0);
        asm volatile("s_waitcnt lgkmcnt(0)" ::: "memory");
        __builtin_amdgcn_sched_barrier(0);
        __builtin_amdgcn_s_setprio(1);
        #pragma unroll
        for (int mf = 0; mf < 4; ++mf)
            #pragma unroll
            for (int nf = 0; nf < 6; ++nf)
                #pragma unroll
                for (int ks = 0; ks < 2; ++ks)
                    acc[mf][nf] = __builtin_amdgcn_mfma_f32_16x16x32_f16(
                        a[mf][ks], bv[nf][ks], acc[mf][nf], 0, 0, 0);
        __builtin_amdgcn_s_setprio(0);
        __builtin_amdgcn_sched_barrier(0);
        asm volatile("s_waitcnt vmcnt(0)" ::: "memory");
        __builtin_amdgcn_s_barrier();
    }

    // Epilogue: f16 C write
    int ocol = l & 15, orow4 = (l >> 4) * 4;
    #pragma unroll
    for (int mf = 0; mf < 4; ++mf)
        #pragma unroll
        for (int nf = 0; nf < 6; ++nf) {
            size_t base = (size_t)(row0 + wr * 64 + mf * 16 + orow4) * N
                        + col0 + wc * 96 + nf * 16 + ocol;
            #pragma unroll
            for (int j = 0; j < 4; ++j)
                C[base + (size_t)j * N] = (_Float16)acc[mf][nf][j];
        }
}

// ---------------------------------------------------------------------------
// gemm_wo: 128x128 tile, BK=64, 4 waves (2x2), 3-buffer LDS (96 KB),
// single phase per K-tile, counted vmcnt(8). (Wo projection)
// ---------------------------------------------------------------------------
__global__ __launch_bounds__(256) void gemm_wo(const _Float16* __restrict__ A,
                                               const _Float16* __restrict__ BT,
                                               _Float16* __restrict__ C,
                                               int M, int N, int K) {
    __shared__ _Float16 smem[3 * 16384];   // 3 bufs x (A 8K + B 8K halves) = 96 KB
    const int t = threadIdx.x;
    const int w = t >> 6, l = t & 63;
    const int wr = w >> 1, wc = w & 1;
    const int NT = K >> 6;
    int row0 = blockIdx.y * 128, col0 = blockIdx.x * 128;

    f32x4 acc[4][4];
    #pragma unroll
    for (int m = 0; m < 4; ++m)
        #pragma unroll
        for (int n = 0; n < 4; ++n)
            acc[m][n] = (f32x4){0.f, 0.f, 0.f, 0.f};

    const int lr = l >> 3;
    const int lc8 = ((l & 7) ^ lr) * 8;

    auto STAGE = [&](int ti) {
        if (ti >= NT) return;
        int kk = ti << 6;
        int bufo = (ti % 3) * 16384;
        #pragma unroll
        for (int i = 0; i < 4; ++i) {
            int chunk = w * 4 + i;   // 0..15, 8 rows each
            const _Float16* asrc = A + (size_t)(row0 + chunk * 8 + lr) * K + kk + lc8;
            __builtin_amdgcn_global_load_lds((const AS1 void*)asrc,
                (AS3 void*)(smem + bufo + chunk * 512), 16, 0, 0);
            const _Float16* bsrc = BT + (size_t)(col0 + chunk * 8 + lr) * K + kk + lc8;
            __builtin_amdgcn_global_load_lds((const AS1 void*)bsrc,
                (AS3 void*)(smem + bufo + 8192 + chunk * 512), 16, 0, 0);
        }
    };

    STAGE(0); STAGE(1);
    asm volatile("s_waitcnt vmcnt(8)" ::: "memory");
    __builtin_amdgcn_s_barrier();

    #pragma unroll 1
    for (int ti = 0; ti < NT; ++ti) {
        const int bufo = (ti % 3) * 16384;
        half8 a[4][2], bv[4][2];
        #pragma unroll
        for (int mf = 0; mf < 4; ++mf) {
            int r = wr * 64 + mf * 16 + (l & 15);
            #pragma unroll
            for (int ks = 0; ks < 2; ++ks) {
                int c16 = (ks * 4 + (l >> 4)) ^ (r & 7);
                a[mf][ks] = *(const half8*)&smem[bufo + r * 64 + c16 * 8];
            }
        }
        #pragma unroll
        for (int nf = 0; nf < 4; ++nf) {
            int r = wc * 64 + nf * 16 + (l & 15);
            #pragma unroll
            for (int ks = 0; ks < 2; ++ks) {
                int c16 = (ks * 4 + (l >> 4)) ^ (r & 7);
                bv[nf][ks] = *(const half8*)&smem[bufo + 8192 + r * 64 + c16 * 8];
            }
        }
        STAGE(ti + 2);
        __builtin_amdgcn_sched_barrier(0);
        asm volatile("s_waitcnt lgkmcnt(0)" ::: "memory");
        __builtin_amdgcn_sched_barrier(0);
        __builtin_amdgcn_s_setprio(1);
        #pragma unroll
        for (int mf = 0; mf < 4; ++mf)
            #pragma unroll
            for (int nf = 0; nf < 4; ++nf)
                #pragma unroll
                for (int ks = 0; ks < 2; ++ks)
                    acc[mf][nf] = __builtin_amdgcn_mfma_f32_16x16x32_f16(
                        a[mf][ks], bv[nf][ks], acc[mf][nf], 0, 0, 0);
        __builtin_amdgcn_s_setprio(0);
        __builtin_amdgcn_sched_barrier(0);
        if (ti < NT - 2) asm volatile("s_waitcnt vmcnt(8)" ::: "memory");
        else             asm volatile("s_waitcnt vmcnt(0)" ::: "memory");
        __builtin_amdgcn_s_barrier();
    }

    int ocol = l & 15, orow = (l >> 4) * 4;
    #pragma unroll
    for (int mf = 0; mf < 4; ++mf)
        #pragma unroll
        for (int nf = 0; nf < 4; ++nf) {
            size_t base = (size_t)(row0 + wr * 64 + mf * 16 + orow) * N
                        + col0 + wc * 64 + nf * 16 + ocol;
            #pragma unroll
            for (int j = 0; j < 4; ++j)
                C[base + (size_t)j * N] = (_Float16)acc[mf][nf][j];
        }
}

// ---------------------------------------------------------------------------
// kvagg_fused: per (bn, jseg): on-the-fly DPFP(k) + v, MFMA accumulate.
// ---------------------------------------------------------------------------
__global__ __launch_bounds__(512) void kvagg_fused(const _Float16* __restrict__ qkv,
                                                   _Float16* __restrict__ kvp,
                                                   float* __restrict__ zp) {
    __shared__ _Float16 x2s[128 * 64];    // 16 KB
    __shared__ _Float16 vTs[64 * 64];     //  8 KB
    __shared__ _Float16 pkTs[384 * 64];   // 48 KB
    const int t = threadIdx.x;
    const int w = t >> 6, l = t & 63;
    const int bn = blockIdx.x;
    const int jseg = blockIdx.y;
    const int b = bn >> 4, nh = bn & 15;

    f32x4 acc[4][3];
    #pragma unroll
    for (int mf = 0; mf < 4; ++mf)
        #pragma unroll
        for (int nf = 0; nf < 3; ++nf)
            acc[mf][nf] = (f32x4){0.f, 0.f, 0.f, 0.f};
    float zacc[3] = {0.f, 0.f, 0.f};

    const int sc = t & 63;
    const int so = t >> 6;

    #pragma unroll 1
    for (int ch = 0; ch < 4; ++ch) {
        int j0 = jseg * 256 + ch * 64;
        _Float16 kx[8], vx[8];
        #pragma unroll
        for (int e = 0; e < 8; ++e) {
            size_t rb = (size_t)((j0 + so * 8 + e) * 2 + b) * 3072 + nh * 64 + sc;
            kx[e] = qkv[rb + 1024];
            vx[e] = qkv[rb + 2048];
        }
        half8 xlo, xhi, vv;
        #pragma unroll
        for (int e = 0; e < 8; ++e) {
            float kf = (float)kx[e];
            xlo[e] = (_Float16)fmaxf(kf, 0.f);
            xhi[e] = (_Float16)fmaxf(-kf, 0.f);
            vv[e] = vx[e];
        }
        if (ch) __syncthreads();
        *(half8*)&x2s[IDX(sc, so)] = xlo;
        *(half8*)&x2s[IDX(sc + 64, so)] = xhi;
        *(half8*)&vTs[IDX(sc, so)] = vv;
        __syncthreads();
        {
            const int o = t & 7;
            const int fb = t >> 3;
            #pragma unroll
            for (int it = 0; it < 6; ++it) {
                int f = it * 64 + fb;
                int fm = f & 127;
                int r = (f >> 7) + 1;
                int fm2 = (fm - r) & 127;
                half8 pa = *(const half8*)&x2s[IDX(fm, o)];
                half8 pb = *(const half8*)&x2s[IDX(fm2, o)];
                *(half8*)&pkTs[IDX(f, o)] = pa * pb;
            }
        }
        __syncthreads();
        #pragma unroll
        for (int ks = 0; ks < 2; ++ks) {
            half8 a[4], bq[3];
            int oo = ks * 4 + (l >> 4);
            #pragma unroll
            for (int mf = 0; mf < 4; ++mf) {
                int dr = mf * 16 + (l & 15);
                a[mf] = *(const half8*)&vTs[IDX(dr, oo)];
            }
            #pragma unroll
            for (int nf = 0; nf < 3; ++nf) {
                int fr = w * 48 + nf * 16 + (l & 15);
                bq[nf] = *(const half8*)&pkTs[IDX(fr, oo)];
                #pragma unroll
                for (int e = 0; e < 8; ++e) zacc[nf] += (float)bq[nf][e];
            }
            #pragma unroll
            for (int mf = 0; mf < 4; ++mf)
                #pragma unroll
                for (int nf = 0; nf < 3; ++nf)
                    acc[mf][nf] = __builtin_amdgcn_mfma_f32_16x16x32_f16(
                        a[mf], bq[nf], acc[mf][nf], 0, 0, 0);
        }
    }

    #pragma unroll
    for (int nf = 0; nf < 3; ++nf) {
        float v = zacc[nf];
        v += __shfl_xor(v, 16, 64);
        v += __shfl_xor(v, 32, 64);
        if (l < 16)
            zp[(size_t)(jseg * 32 + bn) * FEAT + w * 48 + nf * 16 + l] = v;
    }
    _Float16* outp = kvp + (size_t)(jseg * 32 + bn) * 64 * FEAT;
    int orow = (l >> 4) * 4, ocol = l & 15;
    #pragma unroll
    for (int mf = 0; mf < 4; ++mf)
        #pragma unroll
        for (int nf = 0; nf < 3; ++nf) {
            int fcol = w * 48 + nf * 16 + ocol;
            #pragma unroll
            for (int j = 0; j < 4; ++j)
                outp[(size_t)(mf * 16 + orow + j) * FEAT + fcol] = (_Float16)acc[mf][nf][j];
        }
}

// ---------------------------------------------------------------------------
// Reduce 8 j-segments (f16 partials) -> kvaggT f16 [32][64][384], z f32
// ---------------------------------------------------------------------------
__global__ __launch_bounds__(256) void reduceA(const _Float16* __restrict__ kvp,
                                               const float* __restrict__ zp,
                                               _Float16* __restrict__ kvaggT,
                                               float* __restrict__ z) {
    const int NKV = 32 * 64 * FEAT;  // 786432
    int idx = blockIdx.x * 256 + threadIdx.x;
    if (idx < NKV) {
        float s = 0.f;
        #pragma unroll
        for (int c = 0; c < 8; ++c) s += (float)kvp[(size_t)c * NKV + idx];
        kvaggT[idx] = (_Float16)s;
    } else if (idx < NKV + 32 * FEAT) {
        int e = idx - NKV;
        float s = 0.f;
        #pragma unroll
        for (int c = 0; c < 8; ++c) s += zp[c * 32 * FEAT + e];
        z[e] = s;
    }
}

// ---------------------------------------------------------------------------
// attn_fused v2: 64 rows x 64 d per block, grid (32, 32), 256 threads.
// pq in registers via rotated-row trick. z reads vectorized (float4 x2/ks).
// ---------------------------------------------------------------------------
#define X2STR 152   // 128 + 24 right-extension (max csel=24), halves
__global__ __launch_bounds__(256) void attn_fused(const _Float16* __restrict__ qkv,
                                                  const _Float16* __restrict__ kvaggT,
                                                  const float* __restrict__ z,
                                                  _Float16* __restrict__ av) {
    __shared__ _Float16 x2e[64 * X2STR];   // 19,456 B
    __shared__ _Float16 B_lds[64 * FEAT];  // 49,152 B, 16B-cell swizzle
    __shared__ float z_lds[FEAT];
    __shared__ float den_lds[64];
    const int t = threadIdx.x;
    const int w = t >> 6, l = t & 63;
    const int iblk = blockIdx.x;
    const int bn = blockIdx.y;
    const int b = bn >> 4, nh = bn & 15;

    {
        const _Float16* Bg = kvaggT + (size_t)bn * 64 * FEAT;
        #pragma unroll
        for (int s = 0; s < 12; ++s) {
            int idx8 = t + 256 * s;
            int row = idx8 / 48, c16 = idx8 - row * 48;
            half8 vv = *(const half8*)&Bg[row * FEAT + c16 * 8];
            *(half8*)&B_lds[row * FEAT + ((c16 ^ (row & 7)) << 3)] = vv;
        }
    }
    for (int e = t; e < FEAT; e += 256) z_lds[e] = z[(size_t)bn * FEAT + e];

    {
        int row = t >> 2, c0 = (t & 3) * 16;
        const _Float16* qrow = qkv + (size_t)((iblk * 64 + row) * 2 + b) * 3072 + nh * 64;
        half8 q0 = *(const half8*)&qrow[c0];
        half8 q1 = *(const half8*)&qrow[c0 + 8];
        half8 lo0, lo1, hi0, hi1;
        #pragma unroll
        for (int e = 0; e < 8; ++e) {
            float f0 = (float)q0[e], f1 = (float)q1[e];
            lo0[e] = (_Float16)fmaxf(f0, 0.f);
            lo1[e] = (_Float16)fmaxf(f1, 0.f);
            hi0[e] = (_Float16)fmaxf(-f0, 0.f);
            hi1[e] = (_Float16)fmaxf(-f1, 0.f);
        }
        _Float16* xr = &x2e[row * X2STR];
        *(half8*)&xr[c0] = lo0;
        *(half8*)&xr[c0 + 8] = lo1;
        *(half8*)&xr[64 + c0] = hi0;
        *(half8*)&xr[64 + c0 + 8] = hi1;
        if (c0 == 0) { *(half8*)&xr[128] = lo0; *(half8*)&xr[136] = lo1; }
        if (c0 == 16) { *(half8*)&xr[144] = lo0; }
    }
    __syncthreads();

    const int rloc16 = l & 15;
    const int csel = (l >> 4) * 8;
    const int lrow = w * 16 + rloc16;
    half8 y8[16];
    {
        const _Float16* xr = &x2e[lrow * X2STR + csel];
        #pragma unroll
        for (int j = 0; j < 16; ++j)
            y8[j] = *(const half8*)&xr[j * 8];
    }
    half8 afr[12];
    #pragma unroll
    for (int ks = 0; ks < 12; ++ks) {
        const int r = (ks >> 2) + 1;
        #pragma unroll
        for (int e = 0; e < 8; ++e) {
            const int j1 = ((ks & 3) * 32 + e) & 127;
            const int j2 = ((ks & 3) * 32 + e - r) & 127;
            afr[ks][e] = y8[j1 >> 3][j1 & 7] * y8[j2 >> 3][j2 & 7];
        }
    }

    f32x4 acc[4];
    #pragma unroll
    for (int n = 0; n < 4; ++n) acc[n] = (f32x4){0.f, 0.f, 0.f, 0.f};
    float den = 0.f;
    #pragma unroll
    for (int ks = 0; ks < 12; ++ks) {
        const float4 z0 = *(const float4*)&z_lds[ks * 32 + csel];
        const float4 z1 = *(const float4*)&z_lds[ks * 32 + csel + 4];
        den += (float)afr[ks][0] * z0.x + (float)afr[ks][1] * z0.y
             + (float)afr[ks][2] * z0.z + (float)afr[ks][3] * z0.w
             + (float)afr[ks][4] * z1.x + (float)afr[ks][5] * z1.y
             + (float)afr[ks][6] * z1.z + (float)afr[ks][7] * z1.w;
        #pragma unroll
        for (int nf = 0; nf < 4; ++nf) {
            int row = nf * 16 + rloc16;
            int c16 = (ks * 4 + (l >> 4)) ^ (row & 7);
            half8 bfr = *(const half8*)&B_lds[row * FEAT + (c16 << 3)];
            acc[nf] = __builtin_amdgcn_mfma_f32_16x16x32_f16(afr[ks], bfr, acc[nf], 0, 0, 0);
        }
    }

    den += __shfl_xor(den, 16, 64);
    den += __shfl_xor(den, 32, 64);
    if (l < 16) den_lds[w * 16 + l] = den;
    __syncthreads();

    #pragma unroll
    for (int nf = 0; nf < 4; ++nf)
        #pragma unroll
        for (int j = 0; j < 4; ++j) {
            int rl = w * 16 + (l >> 4) * 4 + j;
            float dv = den_lds[rl] * SCALE + EPS;
            float val = acc[nf][j] * SCALE / dv;
            int i = iblk * 64 + rl;
            av[((size_t)i * 2 + b) * 1024 + nh * 64 + nf * 16 + (l & 15)] = (_Float16)val;
        }
}

// ---------------------------------------------------------------------------
// Residual + LayerNorm, vectorized (float4 / half4).
// ---------------------------------------------------------------------------
__global__ __launch_bounds__(256) void ln_kernel(const float* __restrict__ h,
                                                 const _Float16* __restrict__ attn_out,
                                                 const float* __restrict__ gamma,
                                                 const float* __restrict__ beta,
                                                 float* __restrict__ out) {
    int r = blockIdx.x;
    int t = threadIdx.x;
    const float4 hv = ((const float4*)(h + (size_t)r * 1024))[t];
    const half4 a4 = ((const half4*)(attn_out + (size_t)r * 1024))[t];
    float x[4] = {hv.x + (float)a4[0], hv.y + (float)a4[1],
                  hv.z + (float)a4[2], hv.w + (float)a4[3]};
    float sum = x[0] + x[1] + x[2] + x[3];
    float sq = x[0]*x[0] + x[1]*x[1] + x[2]*x[2] + x[3]*x[3];
    #pragma unroll
    for (int off = 32; off >= 1; off >>= 1) {
        sum += __shfl_xor(sum, off, 64);
        sq += __shfl_xor(sq, off, 64);
    }
    __shared__ float ssum[4], ssq[4];
    int wl = t >> 6, lane = t & 63;
    if (lane == 0) { ssum[wl] = sum; ssq[wl] = sq; }
    __syncthreads();
    sum = ssum[0] + ssum[1] + ssum[2] + ssum[3];
    sq = ssq[0] + ssq[1] + ssq[2] + ssq[3];
    float mu = sum * (1.f / 1024.f);
    float var = sq * (1.f / 1024.f) - mu * mu;
    float rs = rsqrtf(var + 1e-5f);
    const float4 g4 = ((const float4*)gamma)[t];
    const float4 b4 = ((const float4*)beta)[t];
    float4 o;
    o.x = (x[0] - mu) * rs * g4.x + b4.x;
    o.y = (x[1] - mu) * rs * g4.y + b4.y;
    o.z = (x[2] - mu) * rs * g4.z + b4.z;
    o.w = (x[3] - mu) * rs * g4.w + b4.w;
    ((float4*)(out + (size_t)r * 1024))[t] = o;
}

// ---------------------------------------------------------------------------
extern "C" void kernel_launch(void* const* d_in, const int* in_sizes, int n_in,
                              void* d_out, int out_size, void* d_ws, size_t ws_size,
                              hipStream_t stream) {
    const float* h     = (const float*)d_in[0];
    const float* Wq    = (const float*)d_in[1];
    const float* Wkv   = (const float*)d_in[2];
    const float* Wo    = (const float*)d_in[3];
    const float* gamma = (const float*)d_in[4];
    const float* beta  = (const float*)d_in[5];
    float* out = (float*)d_out;
    _Float16* u = (_Float16*)d_ws;

    // Workspace (2-byte units)
    _Float16* h_h    = u;                       // 8 MB; later av (f16)
    _Float16* WqkvT  = u + 4194304;             // 6 MB
    _Float16* WoT    = u + 7340032;             // 2 MB
    _Float16* qkv    = u + 8388608;             // 24 MB; later attn_out f16
    _Float16* kvp    = u + 20971520;            // f16 partials, 12.6 MB
    float*    zp     = (float*)(u + 33554432);  // 0.4 MB
    _Float16* kvaggT = u + 33751040;            // 1.5 MB
    float*    z      = (float*)(u + 34537472);  // 48 KB
    _Float16* av         = h_h;
    _Float16* attn_out_h = qkv;

    dim3 blk(256);
    // 0) merged prep: conv h->f16 + weight transposes
    prep_kernel<<<dim3(8192), blk, 0, stream>>>(h, Wq, Wkv, Wo, h_h, WqkvT, WoT);
    // 1) fused qkv projection (single-barrier 256x192), grid 16*16=256
    gemm_qkv<<<dim3(256), dim3(512), 0, stream>>>(h_h, WqkvT, qkv, SB, 3072, DM);
    // 2) fused DPFP(k)+kvagg+z partials over (32 bn x 8 jseg)
    kvagg_fused<<<dim3(32, 8), dim3(512), 0, stream>>>(qkv, kvp, zp);
    // 3) reduce partials
    reduceA<<<dim3(3120), blk, 0, stream>>>(kvp, zp, kvaggT, z);
    // 4) fused featq + attn GEMM, pq-in-registers (grid 32 iblk x 32 bn)
    attn_fused<<<dim3(32, 32), blk, 0, stream>>>(qkv, kvaggT, z, av);
    // 5) output projection: 3-buffer counted-vmcnt kernel, grid (8, 32)
    gemm_wo<<<dim3(8, 32), blk, 0, stream>>>(av, WoT, attn_out_h, SB, 1024, DM);
    // 6) residual + LayerNorm
    ln_kernel<<<dim3(SB), blk, 0, stream>>>(h, attn_out_h, gamma, beta, out);
}